// Round 10
// baseline (2250.754 us; speedup 1.0000x reference)
//
#include <hip/hip_runtime.h>
#include <stdint.h>

#define BB 8
#define NN 4096
#define MM 1024
#define KK 32

__device__ __forceinline__ float bf2f(unsigned short u) {
    union { unsigned int i; float f; } v; v.i = ((unsigned int)u) << 16; return v.f;
}
__device__ __forceinline__ unsigned short f2bf(float f) {
    union { float f; unsigned int i; } v; v.f = f;
    unsigned int x = v.i;
    x += 0x7fffu + ((x >> 16) & 1u);
    return (unsigned short)(x >> 16);
}
__device__ __forceinline__ float swishf(float y) {
    return __fdividef(y, 1.0f + __expf(-y));
}

// out element offsets (dtype-independent)
#define OUT1_OFF 1048576
#define OUT2_OFF 1073152

// params canonical f32 layout (floats)
#define P_W1 0
#define P_B1 4288
#define P_G1 4352
#define P_BE1 4416
#define P_W2 4480
#define P_B2 12672
#define P_G2 12800
#define P_BE2 12928

__device__ __forceinline__ int detect_flag_wave(const unsigned short* f, int lane) {
    unsigned short u = f[lane * 2];
    float x = fabsf(bf2f(u));
    bool ext = (u != 0) && (x > 100.0f || x < 1e-30f);
    unsigned long long m = __ballot(ext);
    return (__popcll(m) >= 16) ? 1 : 0;
}

// ================= launch 1: conversions + sync-var init =================
// blocks 0..511: featT transpose | 512..895: coords cvt | 896..946: params cvt
__global__ __launch_bounds__(256) void k_cvt_all(
    const void* __restrict__ feat, const void* __restrict__ coords,
    float* __restrict__ featT, float* __restrict__ coordsC,
    float* __restrict__ paramsC,
    int* __restrict__ qhead, int* __restrict__ progress,
    const void* W1, const void* b1, const void* g1, const void* be1,
    const void* W2, const void* b2, const void* g2, const void* be2)
{
    __shared__ float tile[64][65];
    __shared__ int sflag;
    int tid = threadIdx.x, blk = blockIdx.x;
    if (tid < 64) {
        int fl0 = detect_flag_wave((const unsigned short*)feat, tid);
        if (tid == 0) sflag = fl0;
    }
    __syncthreads();
    int fl = sflag;
    if (blk == 0) {
        if (tid == 0) *qhead = 0;
        if (tid >= 1 && tid <= 8) progress[tid - 1] = -1;
    }
    if (blk < 512) {
        // featT: [B,64,N] -> f32 [B,N,64]
        int i = blk;
        int b = i >> 6, n0 = (i & 63) * 64;
        int c = tid >> 2, q = tid & 3;
        size_t base = ((size_t)b * 64 + c) * NN + n0 + q * 16;
        if (fl) {
            const float* sp = (const float*)feat + base;
#pragma unroll
            for (int j = 0; j < 16; j++) tile[c][q * 16 + j] = sp[j];
        } else {
            const unsigned short* sp = (const unsigned short*)feat + base;
#pragma unroll
            for (int j = 0; j < 16; j++) tile[c][q * 16 + j] = bf2f(sp[j]);
        }
        __syncthreads();
        int n = tid >> 2;
        float* dp = featT + ((size_t)b * NN + n0 + n) * 64 + q * 16;
#pragma unroll
        for (int j = 0; j < 16; j++) dp[j] = tile[q * 16 + j][n];
    } else if (blk < 896) {
        int idx = (blk - 512) * 256 + tid;
        coordsC[idx] = fl ? ((const float*)coords)[idx]
                          : bf2f(((const unsigned short*)coords)[idx]);
    } else {
        int idx = (blk - 896) * 256 + tid;
        if (idx < 13056) {
            const void* src; int off;
            if (idx < 4288)       { src = W1;  off = idx; }
            else if (idx < 4352)  { src = b1;  off = idx - 4288; }
            else if (idx < 4416)  { src = g1;  off = idx - 4352; }
            else if (idx < 4480)  { src = be1; off = idx - 4416; }
            else if (idx < 12672) { src = W2;  off = idx - 4480; }
            else if (idx < 12800) { src = b2;  off = idx - 12672; }
            else if (idx < 12928) { src = g2;  off = idx - 12800; }
            else                  { src = be2; off = idx - 12928; }
            paramsC[idx] = fl ? ((const float*)src)[off]
                              : bf2f(((const unsigned short*)src)[off]);
        }
    }
}

// ================= launch 2: FPS (blocks 0..7) + persistent kNN workers ====
// 256 blocks total -> always co-resident (no dispatch-order assumption).
// FPS publishes centers in batches of 8 (hist entries >=8 barriers old),
// ordered by agent-scope release store to progress[b]; workers claim centers
// from qhead and acquire-spin on progress[b].
struct PW { double d; int p; int q; };
#define PSM_XS   ((float*)(PSM))
#define PSM_YS   ((float*)(PSM + 16384))
#define PSM_ZS   ((float*)(PSM + 32768))
#define PSM_HIST ((int*)(PSM + 49152))
#define PSM_PWB  ((PW*)(PSM + 53248))
#define PSM_SF   ((int*)(PSM + 53376))

#define RESCAN(G) { \
    double gd = 1.0e300; int ga = (G) * 8; \
    _Pragma("unroll") \
    for (int i = 0; i < 8; i++) { \
        int sl = (G) * 8 + i; \
        unsigned int bit = (sl < 32) ? (elo >> sl) : (ehi >> (sl - 32)); \
        double cd = (bit & 1u) ? 1.0e300 : d[sl]; \
        bool rep = cd < gd; \
        gd = rep ? cd : gd; ga = rep ? sl : ga; \
    } \
    g8[(G)] = gd; a8[(G)] = ga; }

__global__ __launch_bounds__(256) void k_fpsknn(
    const void* __restrict__ coords, const float* __restrict__ coordsC,
    float* __restrict__ centersF, int* __restrict__ nidx,
    const void* __restrict__ temb, const void* __restrict__ feat,
    void* __restrict__ d_out,
    int* __restrict__ qhead, int* __restrict__ progress)
{
    __shared__ __align__(16) char PSM[53392];
    int tid = threadIdx.x;
    int blk = blockIdx.x;
    if (tid < 64) {
        int fl0 = detect_flag_wave((const unsigned short*)feat, tid);
        if (tid == 0) *PSM_SF = fl0;
    }
    __syncthreads();
    int fl = *PSM_SF;

    if (blk < 8) {
        // ---------- FPS in f64 (R7-identical math), 256 thr ----------
        int b = blk;
        if (fl) {
            const float* cb = (const float*)coords + (size_t)b * 3 * NN;
#pragma unroll
            for (int i = 0; i < 16; i++) {
                int p = tid + i * 256;
                PSM_XS[p] = cb[p]; PSM_YS[p] = cb[NN + p]; PSM_ZS[p] = cb[2 * NN + p];
            }
        } else {
            const unsigned short* cb = (const unsigned short*)coords + (size_t)b * 3 * NN;
#pragma unroll
            for (int i = 0; i < 16; i++) {
                int p = tid + i * 256;
                PSM_XS[p] = bf2f(cb[p]); PSM_YS[p] = bf2f(cb[NN + p]); PSM_ZS[p] = bf2f(cb[2 * NN + p]);
            }
        }
        if (tid == 0) PSM_HIST[0] = 0;
        __syncthreads();
        // publish center 0 immediately
        if (tid == 0) {
            *(float4*)(centersF + (size_t)b * MM * 4) =
                make_float4(PSM_XS[0], PSM_YS[0], PSM_ZS[0], 0.f);
            __hip_atomic_store(&progress[b], 0, __ATOMIC_RELEASE, __HIP_MEMORY_SCOPE_AGENT);
        }
        int base = tid * 16;
        double px[16], py[16], pz[16], dist[16];
        double x0 = (double)PSM_XS[0], y0 = (double)PSM_YS[0], z0 = (double)PSM_ZS[0];
        double bd = -1.0; int bp = base;
#pragma unroll
        for (int j = 0; j < 16; j++) {
            px[j] = (double)PSM_XS[base + j]; py[j] = (double)PSM_YS[base + j]; pz[j] = (double)PSM_ZS[base + j];
            double dx = px[j] - x0, dy = py[j] - y0, dz = pz[j] - z0;
            dist[j] = fma(dz, dz, fma(dy, dy, dx * dx));
            bool rep = dist[j] > bd;
            bd = rep ? dist[j] : bd; bp = rep ? base + j : bp;
        }
        int lane = tid & 63, wid = tid >> 6;
#pragma unroll 1
        for (int s = 1; s < MM; s++) {
#pragma unroll
            for (int m = 32; m >= 1; m >>= 1) {
                double od = __shfl_xor(bd, m, 64);
                int op = __shfl_xor(bp, m, 64);
                bool rep = (od > bd) || (od == bd && op < bp);
                bd = rep ? od : bd; bp = rep ? op : bp;
            }
            int par = s & 1;
            if (lane == 0) { PW w; w.d = bd; w.p = bp; w.q = 0; PSM_PWB[par * 4 + wid] = w; }
            __syncthreads();
            PW w0 = PSM_PWB[par * 4 + 0];
            double wd = w0.d; int wp = w0.p;
#pragma unroll
            for (int w = 1; w < 4; w++) {
                PW ww = PSM_PWB[par * 4 + w];
                bool rep = (ww.d > wd) || (ww.d == wd && ww.p < wp);
                wd = rep ? ww.d : wd; wp = rep ? ww.p : wp;
            }
            if (tid == 0) PSM_HIST[s] = wp;
            // progressive publish: batch of 8 centers, >=8 barriers old
            if ((s & 7) == 7 && s >= 15 && wid == ((s >> 3) & 3) && lane == 0) {
                int s0 = s - 15;
#pragma unroll
                for (int t2 = 0; t2 < 8; t2++) {
                    int far = PSM_HIST[s0 + t2];
                    *(float4*)(centersF + ((size_t)b * MM + s0 + t2) * 4) =
                        make_float4(PSM_XS[far], PSM_YS[far], PSM_ZS[far], 0.f);
                }
                __hip_atomic_store(&progress[b], s - 8, __ATOMIC_RELEASE, __HIP_MEMORY_SCOPE_AGENT);
            }
            double fx = (double)PSM_XS[wp], fy = (double)PSM_YS[wp], fz = (double)PSM_ZS[wp];
            bd = -1.0; bp = base;
#pragma unroll
            for (int j = 0; j < 16; j++) {
                double dx = px[j] - fx, dy = py[j] - fy, dz = pz[j] - fz;
                double d = fma(dz, dz, fma(dy, dy, dx * dx));
                dist[j] = fmin(dist[j], d);
                bool rep = dist[j] > bd;
                bd = rep ? dist[j] : bd; bp = rep ? base + j : bp;
            }
        }
        __syncthreads();
        if (tid == 0) {
            for (int t2 = 1016; t2 < 1024; t2++) {
                int far = PSM_HIST[t2];
                *(float4*)(centersF + ((size_t)b * MM + t2) * 4) =
                    make_float4(PSM_XS[far], PSM_YS[far], PSM_ZS[far], 0.f);
            }
            __hip_atomic_store(&progress[b], 1023, __ATOMIC_RELEASE, __HIP_MEMORY_SCOPE_AGENT);
        }
#pragma unroll
        for (int i = 0; i < 4; i++) {
            int m = tid + i * 256;
            int far = PSM_HIST[m];
            float X = PSM_XS[far], Y = PSM_YS[far], Z = PSM_ZS[far];
            if (fl) {
                float* o = (float*)d_out;
                o[OUT1_OFF + (size_t)(b * 3 + 0) * MM + m] = X;
                o[OUT1_OFF + (size_t)(b * 3 + 1) * MM + m] = Y;
                o[OUT1_OFF + (size_t)(b * 3 + 2) * MM + m] = Z;
            } else {
                unsigned short* o = (unsigned short*)d_out;
                o[OUT1_OFF + (size_t)(b * 3 + 0) * MM + m] = f2bf(X);
                o[OUT1_OFF + (size_t)(b * 3 + 1) * MM + m] = f2bf(Y);
                o[OUT1_OFF + (size_t)(b * 3 + 2) * MM + m] = f2bf(Z);
            }
        }
    } else {
        // ---------- persistent kNN + gtemb workers (wave granularity) ----------
        int lane = tid & 63;
        for (;;) {
            int idx = 0;
            if (lane == 0) idx = atomicAdd(qhead, 1);
            idx = __shfl(idx, 0, 64);
            if (idx >= BB * MM) break;
            int b = idx >> 10, m = idx & (MM - 1);
            while (__hip_atomic_load(&progress[b], __ATOMIC_ACQUIRE,
                                     __HIP_MEMORY_SCOPE_AGENT) < m)
                __builtin_amdgcn_s_sleep(4);
            const float* cb = coordsC + (size_t)b * 3 * NN;
            float4 ctr = *(const float4*)(centersF + (size_t)idx * 4);
            double cx = (double)ctr.x, cy = (double)ctr.y, cz = (double)ctr.z;
            double cc = (cx * cx + cy * cy) + cz * cz;
            double d[64];
#pragma unroll 4
            for (int j = 0; j < 64; j++) {
                int p = j * 64 + lane;
                double x = (double)cb[p], y = (double)cb[NN + p], z = (double)cb[2 * NN + p];
                double pp = (x * x + y * y) + z * z;
                double dt = (cx * x + cy * y) + cz * z;
                d[j] = (cc + pp) - 2.0 * dt;
            }
            double g8[8]; int a8[8];
#pragma unroll
            for (int g = 0; g < 8; g++) {
                double gd = d[g * 8]; int ga = g * 8;
#pragma unroll
                for (int i = 1; i < 8; i++) {
                    int sl = g * 8 + i;
                    bool rep = d[sl] < gd;
                    gd = rep ? d[sl] : gd; ga = rep ? sl : ga;
                }
                g8[g] = gd; a8[g] = ga;
            }
            unsigned int elo = 0, ehi = 0;
            int res = 0;
#pragma unroll 1
            for (int it = 0; it < 32; it++) {
                double bd = g8[0]; int ba = a8[0];
#pragma unroll
                for (int g = 1; g < 8; g++) {
                    bool rep = g8[g] < bd;
                    bd = rep ? g8[g] : bd; ba = rep ? a8[g] : ba;
                }
                int bp = ba * 64 + lane;
                double wd = bd; int wp = bp;
#pragma unroll
                for (int s = 32; s >= 1; s >>= 1) {
                    double od = __shfl_xor(wd, s, 64);
                    int op = __shfl_xor(wp, s, 64);
                    bool rep = (od < wd) || (od == wd && op < wp);
                    wd = rep ? od : wd; wp = rep ? op : wp;
                }
                res = (lane == it) ? wp : res;
                if (bp == wp) {
                    int slot = ba;
                    if (slot < 32) elo |= (1u << slot); else ehi |= (1u << (slot - 32));
                    int g = slot >> 3;
                    switch (g) {
                        case 0: RESCAN(0) break;
                        case 1: RESCAN(1) break;
                        case 2: RESCAN(2) break;
                        case 3: RESCAN(3) break;
                        case 4: RESCAN(4) break;
                        case 5: RESCAN(5) break;
                        case 6: RESCAN(6) break;
                        case 7: RESCAN(7) break;
                    }
                }
            }
            if (lane < KK) nidx[(size_t)idx * KK + lane] = res;
            float best = -3.0e38f;
            if (fl) {
                const float* tb = (const float*)temb + ((size_t)b * 64 + lane) * NN;
#pragma unroll 4
                for (int k = 0; k < 32; k++) {
                    int nk = __shfl(res, k, 64);
                    best = fmaxf(best, tb[nk]);
                }
            } else {
                const unsigned short* tb = (const unsigned short*)temb + ((size_t)b * 64 + lane) * NN;
#pragma unroll 4
                for (int k = 0; k < 32; k++) {
                    int nk = __shfl(res, k, 64);
                    best = fmaxf(best, bf2f(tb[nk]));
                }
            }
            size_t off = (size_t)OUT2_OFF + ((size_t)(b * 64 + lane)) * MM + m;
            if (fl) ((float*)d_out)[off] = best;
            else    ((unsigned short*)d_out)[off] = f2bf(best);
        }
    }
}

// ================= fused MLP machinery (featT f32 gathers) =================
#define W1Tm(j,c)     (((float*)SM)[(j)*64+(c)])
#define GBUFm(mi,k,c) (((float*)(SM+17152))[(((mi)*32+(k))*66)+(c)])
#define GCm(mi,j,k)   (((float*)(SM+50944))[(((mi)*3+(j))*32)+(k)])
#define NDm(mi,k)     (((int*)(SM+52480))[((mi)*32)+(k)])
#define W2Tm(j,c)     (((float*)SM)[(j)*128+(c)])
#define ACTm(mi,j,k)  (((float*)(SM+32768))[(((mi)*64+(j))*32)+(k)])

__device__ __forceinline__ void mlp1_compute(
    char* SM, int tid, int lane, int mi, int b, int bm,
    const float* __restrict__ featT, const float* __restrict__ coordsC,
    const float* __restrict__ centersF, const int* __restrict__ nidx,
    const float* __restrict__ P, float acc[8][4])
{
    for (int t = tid; t < 64 * 67; t += 256) {
        int c = t / 67, j = t % 67;
        W1Tm(j, c) = P[P_W1 + t];
    }
    if (lane < 32) NDm(mi, lane) = nidx[(size_t)bm * KK + lane] & (NN - 1);
    __syncthreads();
    const float* fb = featT + (size_t)b * NN * 64;
#pragma unroll 4
    for (int q = 0; q < 32; q++) {
        int n = NDm(mi, q);
        GBUFm(mi, q, lane) = fb[(size_t)n * 64 + lane];
    }
    float4 ctr = *(const float4*)(centersF + (size_t)bm * 4);
    const float* cb = coordsC + (size_t)b * 3 * NN;
    if (lane < 32) {
        int n = NDm(mi, lane);
        GCm(mi, 0, lane) = __fsub_rn(cb[n], ctr.x);
        GCm(mi, 1, lane) = __fsub_rn(cb[NN + n], ctr.y);
        GCm(mi, 2, lane) = __fsub_rn(cb[2 * NN + n], ctr.z);
    }
    __syncthreads();
    int c0 = (lane >> 3) * 8;
    int k0 = (lane & 7) * 4;
#pragma unroll
    for (int i = 0; i < 8; i++)
#pragma unroll
        for (int kk = 0; kk < 4; kk++) acc[i][kk] = 0.f;
#pragma unroll
    for (int j = 0; j < 3; j++) {
        float4 a = *(const float4*)&GCm(mi, j, k0);
        float4 w0 = *(const float4*)&W1Tm(j, c0);
        float4 w1v = *(const float4*)&W1Tm(j, c0 + 4);
        float w[8] = {w0.x, w0.y, w0.z, w0.w, w1v.x, w1v.y, w1v.z, w1v.w};
#pragma unroll
        for (int i = 0; i < 8; i++) {
            acc[i][0] = fmaf(w[i], a.x, acc[i][0]);
            acc[i][1] = fmaf(w[i], a.y, acc[i][1]);
            acc[i][2] = fmaf(w[i], a.z, acc[i][2]);
            acc[i][3] = fmaf(w[i], a.w, acc[i][3]);
        }
    }
#pragma unroll 4
    for (int c = 0; c < 64; c++) {
        float f0 = GBUFm(mi, k0 + 0, c);
        float f1 = GBUFm(mi, k0 + 1, c);
        float f2 = GBUFm(mi, k0 + 2, c);
        float f3 = GBUFm(mi, k0 + 3, c);
        int j = 3 + c;
        float4 w0 = *(const float4*)&W1Tm(j, c0);
        float4 w1v = *(const float4*)&W1Tm(j, c0 + 4);
        float w[8] = {w0.x, w0.y, w0.z, w0.w, w1v.x, w1v.y, w1v.z, w1v.w};
#pragma unroll
        for (int i = 0; i < 8; i++) {
            acc[i][0] = fmaf(w[i], f0, acc[i][0]);
            acc[i][1] = fmaf(w[i], f1, acc[i][1]);
            acc[i][2] = fmaf(w[i], f2, acc[i][2]);
            acc[i][3] = fmaf(w[i], f3, acc[i][3]);
        }
    }
}

__device__ __forceinline__ void mlp2_compute(
    char* SM, int tid, int lane, int mi, int b,
    const float acc1[8][4], const float* __restrict__ coef1,
    const float* __restrict__ P, float acc2[16][4])
{
    __syncthreads();  // phase1 LDS dead
    int c0 = (lane >> 3) * 8;
    int k0 = (lane & 7) * 4;
#pragma unroll
    for (int i = 0; i < 8; i++) {
        int c = c0 + i;
        float sc = coef1[(b * 64 + c) * 2];
        float sh = coef1[(b * 64 + c) * 2 + 1];
        float bb = P[P_B1 + c];
#pragma unroll
        for (int kk = 0; kk < 4; kk++)
            ACTm(mi, c, k0 + kk) = swishf(fmaf(acc1[i][kk] + bb, sc, sh));
    }
    for (int t = tid; t < 128 * 64; t += 256) {
        int c = t >> 6, j = t & 63;
        W2Tm(j, c) = P[P_W2 + t];
    }
    __syncthreads();
    int c02 = (lane >> 3) * 16;
#pragma unroll
    for (int i = 0; i < 16; i++)
#pragma unroll
        for (int kk = 0; kk < 4; kk++) acc2[i][kk] = 0.f;
#pragma unroll 4
    for (int j = 0; j < 64; j++) {
        float4 a = *(const float4*)&ACTm(mi, j, k0);
        float4 w0 = *(const float4*)&W2Tm(j, c02);
        float4 w1v = *(const float4*)&W2Tm(j, c02 + 4);
        float4 w2v = *(const float4*)&W2Tm(j, c02 + 8);
        float4 w3 = *(const float4*)&W2Tm(j, c02 + 12);
        float w[16] = {w0.x, w0.y, w0.z, w0.w, w1v.x, w1v.y, w1v.z, w1v.w,
                       w2v.x, w2v.y, w2v.z, w2v.w, w3.x, w3.y, w3.z, w3.w};
#pragma unroll
        for (int i = 0; i < 16; i++) {
            acc2[i][0] = fmaf(w[i], a.x, acc2[i][0]);
            acc2[i][1] = fmaf(w[i], a.y, acc2[i][1]);
            acc2[i][2] = fmaf(w[i], a.z, acc2[i][2]);
            acc2[i][3] = fmaf(w[i], a.w, acc2[i][3]);
        }
    }
}

// ---------------- MLP1 + GN1 block-partial stats
__global__ __launch_bounds__(256) void k_mlp1s(
    const float* __restrict__ featT, const float* __restrict__ coordsC,
    const float* __restrict__ centersF, const int* __restrict__ nidx,
    const float* __restrict__ P, float* __restrict__ part1)
{
    __shared__ __align__(16) char smem[53248];
    char* SM = smem;
    int tid = threadIdx.x, blk = blockIdx.x;
    int b = blk >> 8, m0 = (blk & 255) * 4;
    int mi = tid >> 6, lane = tid & 63;
    int bm = b * MM + m0 + mi;
    float acc[8][4];
    mlp1_compute(SM, tid, lane, mi, b, bm, featT, coordsC, centersF, nidx, P, acc);
    int c0 = (lane >> 3) * 8;
    float s = 0.f, s2 = 0.f;
#pragma unroll
    for (int i = 0; i < 8; i++) {
        float bb = P[P_B1 + c0 + i];
#pragma unroll
        for (int kk = 0; kk < 4; kk++) {
            float v = acc[i][kk] + bb;
            s += v; s2 = fmaf(v, v, s2);
        }
    }
    s += __shfl_xor(s, 1, 64); s += __shfl_xor(s, 2, 64); s += __shfl_xor(s, 4, 64);
    s2 += __shfl_xor(s2, 1, 64); s2 += __shfl_xor(s2, 2, 64); s2 += __shfl_xor(s2, 4, 64);
    float* sred = (float*)(SM + 52992);
    __syncthreads();
    if ((lane & 7) == 0) {
        int g = lane >> 3;
        sred[(mi * 8 + g) * 2] = s;
        sred[(mi * 8 + g) * 2 + 1] = s2;
    }
    __syncthreads();
    if (tid < 16) {
        int g = tid >> 1, w = tid & 1;
        float t = sred[(0 * 8 + g) * 2 + w] + sred[(1 * 8 + g) * 2 + w]
                + sred[(2 * 8 + g) * 2 + w] + sred[(3 * 8 + g) * 2 + w];
        part1[blk * 16 + g * 2 + w] = t;
    }
}

// ---------------- parallel coef reductions (512 thr, tree)
__global__ __launch_bounds__(512) void k_coef1(
    const float* __restrict__ part1, const float* __restrict__ P,
    float* __restrict__ coef1)
{
    __shared__ float red[512];
    int tid = threadIdx.x;
    int out = tid >> 2, sub = tid & 3;
    int b = out >> 4, gw = out & 15;
    const float* p = part1 + (size_t)(b * 256 + sub * 64) * 16 + gw;
    float s = 0.f;
#pragma unroll 8
    for (int r = 0; r < 64; r++) s += p[r * 16];
    red[out * 4 + sub] = s;
    __syncthreads();
    if (tid < 64) {
        int bb = tid >> 3, g = tid & 7;
        int o1 = (bb * 16 + g * 2) * 4, o2 = o1 + 4;
        float S = red[o1] + red[o1 + 1] + red[o1 + 2] + red[o1 + 3];
        float Q = red[o2] + red[o2 + 1] + red[o2 + 2] + red[o2 + 3];
        float inv_n = 1.0f / 262144.0f;
        float mean = S * inv_n;
        float var = Q * inv_n - mean * mean;
        float inv = rsqrtf(var + 1e-5f);
        for (int i = 0; i < 8; i++) {
            int c = g * 8 + i;
            float sc = P[P_G1 + c] * inv;
            coef1[(bb * 64 + c) * 2] = sc;
            coef1[(bb * 64 + c) * 2 + 1] = P[P_BE1 + c] - mean * sc;
        }
    }
}

// ---------------- MLP1+act+MLP2 + GN2 block-partial stats
__global__ __launch_bounds__(256) void k_mlp2s(
    const float* __restrict__ featT, const float* __restrict__ coordsC,
    const float* __restrict__ centersF, const int* __restrict__ nidx,
    const float* __restrict__ P, const float* __restrict__ coef1,
    float* __restrict__ part2)
{
    __shared__ __align__(16) char smem[65536];
    char* SM = smem;
    int tid = threadIdx.x, blk = blockIdx.x;
    int b = blk >> 8, m0 = (blk & 255) * 4;
    int mi = tid >> 6, lane = tid & 63;
    int bm = b * MM + m0 + mi;
    float acc1[8][4];
    mlp1_compute(SM, tid, lane, mi, b, bm, featT, coordsC, centersF, nidx, P, acc1);
    float acc2[16][4];
    mlp2_compute(SM, tid, lane, mi, b, acc1, coef1, P, acc2);
    int c02 = (lane >> 3) * 16;
    float s = 0.f, s2 = 0.f;
#pragma unroll
    for (int i = 0; i < 16; i++) {
        float bb = P[P_B2 + c02 + i];
#pragma unroll
        for (int kk = 0; kk < 4; kk++) {
            float v = acc2[i][kk] + bb;
            s += v; s2 = fmaf(v, v, s2);
        }
    }
    s += __shfl_xor(s, 1, 64); s += __shfl_xor(s, 2, 64); s += __shfl_xor(s, 4, 64);
    s2 += __shfl_xor(s2, 1, 64); s2 += __shfl_xor(s2, 2, 64); s2 += __shfl_xor(s2, 4, 64);
    __syncthreads();
    float* sred = (float*)SM;
    if ((lane & 7) == 0) {
        int g = lane >> 3;
        sred[(mi * 8 + g) * 2] = s;
        sred[(mi * 8 + g) * 2 + 1] = s2;
    }
    __syncthreads();
    if (tid < 16) {
        int g = tid >> 1, w = tid & 1;
        float t = sred[(0 * 8 + g) * 2 + w] + sred[(1 * 8 + g) * 2 + w]
                + sred[(2 * 8 + g) * 2 + w] + sred[(3 * 8 + g) * 2 + w];
        part2[blk * 16 + g * 2 + w] = t;
    }
}

__global__ __launch_bounds__(512) void k_coef2(
    const float* __restrict__ part2, const float* __restrict__ P,
    float* __restrict__ coef2)
{
    __shared__ float red[512];
    int tid = threadIdx.x;
    int out = tid >> 2, sub = tid & 3;
    int b = out >> 4, gw = out & 15;
    const float* p = part2 + (size_t)(b * 256 + sub * 64) * 16 + gw;
    float s = 0.f;
#pragma unroll 8
    for (int r = 0; r < 64; r++) s += p[r * 16];
    red[out * 4 + sub] = s;
    __syncthreads();
    if (tid < 64) {
        int bb = tid >> 3, g = tid & 7;
        int o1 = (bb * 16 + g * 2) * 4, o2 = o1 + 4;
        float S = red[o1] + red[o1 + 1] + red[o1 + 2] + red[o1 + 3];
        float Q = red[o2] + red[o2 + 1] + red[o2 + 2] + red[o2 + 3];
        float inv_n = 1.0f / 524288.0f;
        float mean = S * inv_n;
        float var = Q * inv_n - mean * mean;
        float inv = rsqrtf(var + 1e-5f);
        for (int i = 0; i < 16; i++) {
            int c = g * 16 + i;
            float sc = P[P_G2 + c] * inv;
            coef2[(bb * 128 + c) * 2] = sc;
            coef2[(bb * 128 + c) * 2 + 1] = P[P_BE2 + c] - mean * sc;
        }
    }
}

// ---------------- final: recompute, swish(GN2), max over K -> out0
__global__ __launch_bounds__(256) void k_final(
    const float* __restrict__ featT, const float* __restrict__ coordsC,
    const float* __restrict__ centersF, const int* __restrict__ nidx,
    const float* __restrict__ P, const float* __restrict__ coef1,
    const float* __restrict__ coef2,
    void* __restrict__ d_out, const void* __restrict__ feat)
{
    __shared__ __align__(16) char smem[65536];
    char* SM = smem;
    int tid = threadIdx.x, blk = blockIdx.x;
    if (tid < 64) {
        int fl0 = detect_flag_wave((const unsigned short*)feat, tid);
        if (tid == 0) *(int*)(SM + 53248) = fl0;
    }
    __syncthreads();
    int fl = *(int*)(SM + 53248);
    int b = blk >> 8, m0 = (blk & 255) * 4;
    int mi = tid >> 6, lane = tid & 63;
    int bm = b * MM + m0 + mi;
    float acc1[8][4];
    mlp1_compute(SM, tid, lane, mi, b, bm, featT, coordsC, centersF, nidx, P, acc1);
    float acc2[16][4];
    mlp2_compute(SM, tid, lane, mi, b, acc1, coef1, P, acc2);
    int c02 = (lane >> 3) * 16;
    float mx[16];
#pragma unroll
    for (int i = 0; i < 16; i++) {
        int c = c02 + i;
        float sc = coef2[(b * 128 + c) * 2];
        float sh = coef2[(b * 128 + c) * 2 + 1];
        float bb = P[P_B2 + c];
        float v = -3.0e38f;
#pragma unroll
        for (int kk = 0; kk < 4; kk++)
            v = fmaxf(v, swishf(fmaf(acc2[i][kk] + bb, sc, sh)));
        v = fmaxf(v, __shfl_xor(v, 1, 64));
        v = fmaxf(v, __shfl_xor(v, 2, 64));
        v = fmaxf(v, __shfl_xor(v, 4, 64));
        mx[i] = v;
    }
    if ((lane & 7) == 0) {
        int m = m0 + mi;
#pragma unroll
        for (int i = 0; i < 16; i++) {
            size_t off = (size_t)(b * 128 + c02 + i) * MM + m;
            if (fl) ((float*)d_out)[off] = mx[i];
            else    ((unsigned short*)d_out)[off] = f2bf(mx[i]);
        }
    }
}

extern "C" void kernel_launch(void* const* d_in, const int* in_sizes, int n_in,
                              void* d_out, int out_size, void* d_ws, size_t ws_size,
                              hipStream_t stream) {
    (void)in_sizes; (void)n_in; (void)out_size; (void)ws_size;
    const void* feat = d_in[0];
    const void* coords = d_in[1];
    const void* temb = d_in[2];

    // workspace: 10,288,192 bytes total
    char* ws = (char*)d_ws;
    int* qhead = (int*)ws;                                 // @0
    int* progress = (int*)(ws + 16);                       // 8 ints
    float* coordsC = (float*)(ws + 64);                    // 393,216
    float* paramsC = (float*)(ws + 393280);                // 52,224
    float* centersF = (float*)(ws + 445504);               // 131,072
    int* nidx = (int*)(ws + 576576);                       // 1,048,576
    float* part1 = (float*)(ws + 1625152);                 // 131,072
    float* part2 = (float*)(ws + 1756224);                 // 131,072
    float* coef1 = (float*)(ws + 1887296);                 // 4,096
    float* coef2 = (float*)(ws + 1891392);                 // 8,192
    float* featT = (float*)(ws + 1899584);                 // 8,388,608

    k_cvt_all<<<947, 256, 0, stream>>>(feat, coords, featT, coordsC, paramsC,
                                       qhead, progress,
                                       d_in[3], d_in[4], d_in[5], d_in[6],
                                       d_in[7], d_in[8], d_in[9], d_in[10]);
    k_fpsknn<<<256, 256, 0, stream>>>(coords, coordsC, centersF, nidx, temb,
                                      feat, d_out, qhead, progress);
    k_mlp1s<<<2048, 256, 0, stream>>>(featT, coordsC, centersF, nidx, paramsC, part1);
    k_coef1<<<1, 512, 0, stream>>>(part1, paramsC, coef1);
    k_mlp2s<<<2048, 256, 0, stream>>>(featT, coordsC, centersF, nidx, paramsC, coef1, part2);
    k_coef2<<<1, 512, 0, stream>>>(part2, paramsC, coef2);
    k_final<<<2048, 256, 0, stream>>>(featT, coordsC, centersF, nidx, paramsC, coef1, coef2, d_out, feat);
}

// Round 11
// 1650.385 us; speedup vs baseline: 1.3638x; 1.3638x over previous
//
#include <hip/hip_runtime.h>
#include <stdint.h>

#define BB 8
#define NN 4096
#define MM 1024
#define KK 32

__device__ __forceinline__ float bf2f(unsigned short u) {
    union { unsigned int i; float f; } v; v.i = ((unsigned int)u) << 16; return v.f;
}
__device__ __forceinline__ unsigned short f2bf(float f) {
    union { float f; unsigned int i; } v; v.f = f;
    unsigned int x = v.i;
    x += 0x7fffu + ((x >> 16) & 1u);
    return (unsigned short)(x >> 16);
}
__device__ __forceinline__ float swishf(float y) {
    return __fdividef(y, 1.0f + __expf(-y));
}

// out element offsets (dtype-independent)
#define OUT1_OFF 1048576
#define OUT2_OFF 1073152

// params canonical f32 layout (floats)
#define P_W1 0
#define P_B1 4288
#define P_G1 4352
#define P_BE1 4416
#define P_W2 4480
#define P_B2 12672
#define P_G2 12800
#define P_BE2 12928

__device__ __forceinline__ int detect_flag_wave(const unsigned short* f, int lane) {
    unsigned short u = f[lane * 2];
    float x = fabsf(bf2f(u));
    bool ext = (u != 0) && (x > 100.0f || x < 1e-30f);
    unsigned long long m = __ballot(ext);
    return (__popcll(m) >= 16) ? 1 : 0;
}

// ================= launch 1: conversions + sync-var init =================
__global__ __launch_bounds__(256) void k_cvt_all(
    const void* __restrict__ feat, const void* __restrict__ coords,
    float* __restrict__ featT, float* __restrict__ coordsC,
    float* __restrict__ paramsC,
    int* __restrict__ qhead, int* __restrict__ progress,
    const void* W1, const void* b1, const void* g1, const void* be1,
    const void* W2, const void* b2, const void* g2, const void* be2)
{
    __shared__ float tile[64][65];
    __shared__ int sflag;
    int tid = threadIdx.x, blk = blockIdx.x;
    if (tid < 64) {
        int fl0 = detect_flag_wave((const unsigned short*)feat, tid);
        if (tid == 0) sflag = fl0;
    }
    __syncthreads();
    int fl = sflag;
    if (blk == 0) {
        if (tid == 0) *qhead = 0;
        if (tid >= 1 && tid <= 8) progress[(tid - 1) * 16] = -1;  // 64B-strided
    }
    if (blk < 512) {
        int i = blk;
        int b = i >> 6, n0 = (i & 63) * 64;
        int c = tid >> 2, q = tid & 3;
        size_t base = ((size_t)b * 64 + c) * NN + n0 + q * 16;
        if (fl) {
            const float* sp = (const float*)feat + base;
#pragma unroll
            for (int j = 0; j < 16; j++) tile[c][q * 16 + j] = sp[j];
        } else {
            const unsigned short* sp = (const unsigned short*)feat + base;
#pragma unroll
            for (int j = 0; j < 16; j++) tile[c][q * 16 + j] = bf2f(sp[j]);
        }
        __syncthreads();
        int n = tid >> 2;
        float* dp = featT + ((size_t)b * NN + n0 + n) * 64 + q * 16;
#pragma unroll
        for (int j = 0; j < 16; j++) dp[j] = tile[q * 16 + j][n];
    } else if (blk < 896) {
        int idx = (blk - 512) * 256 + tid;
        coordsC[idx] = fl ? ((const float*)coords)[idx]
                          : bf2f(((const unsigned short*)coords)[idx]);
    } else {
        int idx = (blk - 896) * 256 + tid;
        if (idx < 13056) {
            const void* src; int off;
            if (idx < 4288)       { src = W1;  off = idx; }
            else if (idx < 4352)  { src = b1;  off = idx - 4288; }
            else if (idx < 4416)  { src = g1;  off = idx - 4352; }
            else if (idx < 4480)  { src = be1; off = idx - 4416; }
            else if (idx < 12672) { src = W2;  off = idx - 4480; }
            else if (idx < 12800) { src = b2;  off = idx - 12672; }
            else if (idx < 12928) { src = g2;  off = idx - 12800; }
            else                  { src = be2; off = idx - 12928; }
            paramsC[idx] = fl ? ((const float*)src)[off]
                              : bf2f(((const unsigned short*)src)[off]);
        }
    }
}

// ================= launch 2: FPS (blocks 0..7) + persistent kNN workers ====
// 256 blocks, LDS padded to 55296 B -> max 2 blocks/CU -> capacity 512 >=
// grid 256: all blocks resident, no dispatch-order assumption.
// Workers poll progress[b*16] (own 64B line) with s_sleep(64) throttle
// (~1.7us/poll) -- R10's unthrottled polls saturated the fabric (185MB
// FETCH) and slowed FPS 1.05->1.75 us/step.
struct PW { double d; int p; int q; };
#define PSM_XS   ((float*)(PSM))
#define PSM_YS   ((float*)(PSM + 16384))
#define PSM_ZS   ((float*)(PSM + 32768))
#define PSM_HIST ((int*)(PSM + 49152))
#define PSM_PWB  ((PW*)(PSM + 53248))
#define PSM_SF   ((int*)(PSM + 53376))

#define RESCAN(G) { \
    double gd = 1.0e300; int ga = (G) * 8; \
    _Pragma("unroll") \
    for (int i = 0; i < 8; i++) { \
        int sl = (G) * 8 + i; \
        unsigned int bit = (sl < 32) ? (elo >> sl) : (ehi >> (sl - 32)); \
        double cd = (bit & 1u) ? 1.0e300 : d[sl]; \
        bool rep = cd < gd; \
        gd = rep ? cd : gd; ga = rep ? sl : ga; \
    } \
    g8[(G)] = gd; a8[(G)] = ga; }

__global__ __launch_bounds__(256) void k_fpsknn(
    const void* __restrict__ coords, const float* __restrict__ coordsC,
    float* __restrict__ centersF, int* __restrict__ nidx,
    const void* __restrict__ temb, const void* __restrict__ feat,
    void* __restrict__ d_out,
    int* __restrict__ qhead, int* __restrict__ progress)
{
    __shared__ __align__(16) char PSM[55296];   // pad: max 2 blocks/CU
    int tid = threadIdx.x;
    int blk = blockIdx.x;
    if (tid < 64) {
        int fl0 = detect_flag_wave((const unsigned short*)feat, tid);
        if (tid == 0) *PSM_SF = fl0;
    }
    __syncthreads();
    int fl = *PSM_SF;

    if (blk < 8) {
        // ---------- FPS in f64 (R7-identical math), 256 thr ----------
        int b = blk;
        if (fl) {
            const float* cb = (const float*)coords + (size_t)b * 3 * NN;
#pragma unroll
            for (int i = 0; i < 16; i++) {
                int p = tid + i * 256;
                PSM_XS[p] = cb[p]; PSM_YS[p] = cb[NN + p]; PSM_ZS[p] = cb[2 * NN + p];
            }
        } else {
            const unsigned short* cb = (const unsigned short*)coords + (size_t)b * 3 * NN;
#pragma unroll
            for (int i = 0; i < 16; i++) {
                int p = tid + i * 256;
                PSM_XS[p] = bf2f(cb[p]); PSM_YS[p] = bf2f(cb[NN + p]); PSM_ZS[p] = bf2f(cb[2 * NN + p]);
            }
        }
        if (tid == 0) PSM_HIST[0] = 0;
        __syncthreads();
        if (tid == 0) {
            *(float4*)(centersF + (size_t)b * MM * 4) =
                make_float4(PSM_XS[0], PSM_YS[0], PSM_ZS[0], 0.f);
            __hip_atomic_store(&progress[b * 16], 0, __ATOMIC_RELEASE, __HIP_MEMORY_SCOPE_AGENT);
        }
        int base = tid * 16;
        double px[16], py[16], pz[16], dist[16];
        double x0 = (double)PSM_XS[0], y0 = (double)PSM_YS[0], z0 = (double)PSM_ZS[0];
        double bd = -1.0; int bp = base;
#pragma unroll
        for (int j = 0; j < 16; j++) {
            px[j] = (double)PSM_XS[base + j]; py[j] = (double)PSM_YS[base + j]; pz[j] = (double)PSM_ZS[base + j];
            double dx = px[j] - x0, dy = py[j] - y0, dz = pz[j] - z0;
            dist[j] = fma(dz, dz, fma(dy, dy, dx * dx));
            bool rep = dist[j] > bd;
            bd = rep ? dist[j] : bd; bp = rep ? base + j : bp;
        }
        int lane = tid & 63, wid = tid >> 6;
#pragma unroll 1
        for (int s = 1; s < MM; s++) {
#pragma unroll
            for (int m = 32; m >= 1; m >>= 1) {
                double od = __shfl_xor(bd, m, 64);
                int op = __shfl_xor(bp, m, 64);
                bool rep = (od > bd) || (od == bd && op < bp);
                bd = rep ? od : bd; bp = rep ? op : bp;
            }
            int par = s & 1;
            if (lane == 0) { PW w; w.d = bd; w.p = bp; w.q = 0; PSM_PWB[par * 4 + wid] = w; }
            __syncthreads();
            PW w0 = PSM_PWB[par * 4 + 0];
            double wd = w0.d; int wp = w0.p;
#pragma unroll
            for (int w = 1; w < 4; w++) {
                PW ww = PSM_PWB[par * 4 + w];
                bool rep = (ww.d > wd) || (ww.d == wd && ww.p < wp);
                wd = rep ? ww.d : wd; wp = rep ? ww.p : wp;
            }
            if (tid == 0) PSM_HIST[s] = wp;
            // progressive publish: 32 centers every 32 steps, entries >=32
            // barriers old; stores spread over 32 lanes of one wave, then
            // release by lane 0 (wave-level vmcnt orders all lanes' stores)
            if ((s & 31) == 31 && s >= 63 && wid == ((s >> 5) & 3)) {
                int s0 = s - 63;
                if (lane < 32) {
                    int far = PSM_HIST[s0 + lane];
                    *(float4*)(centersF + ((size_t)b * MM + s0 + lane) * 4) =
                        make_float4(PSM_XS[far], PSM_YS[far], PSM_ZS[far], 0.f);
                }
                if (lane == 0)
                    __hip_atomic_store(&progress[b * 16], s0 + 31,
                                       __ATOMIC_RELEASE, __HIP_MEMORY_SCOPE_AGENT);
            }
            double fx = (double)PSM_XS[wp], fy = (double)PSM_YS[wp], fz = (double)PSM_ZS[wp];
            bd = -1.0; bp = base;
#pragma unroll
            for (int j = 0; j < 16; j++) {
                double dx = px[j] - fx, dy = py[j] - fy, dz = pz[j] - fz;
                double d = fma(dz, dz, fma(dy, dy, dx * dx));
                dist[j] = fmin(dist[j], d);
                bool rep = dist[j] > bd;
                bd = rep ? dist[j] : bd; bp = rep ? base + j : bp;
            }
        }
        __syncthreads();
        if (tid < 32) {
            int far = PSM_HIST[992 + tid];
            *(float4*)(centersF + ((size_t)b * MM + 992 + tid) * 4) =
                make_float4(PSM_XS[far], PSM_YS[far], PSM_ZS[far], 0.f);
        }
        if (tid == 0)
            __hip_atomic_store(&progress[b * 16], 1023,
                               __ATOMIC_RELEASE, __HIP_MEMORY_SCOPE_AGENT);
#pragma unroll
        for (int i = 0; i < 4; i++) {
            int m = tid + i * 256;
            int far = PSM_HIST[m];
            float X = PSM_XS[far], Y = PSM_YS[far], Z = PSM_ZS[far];
            if (fl) {
                float* o = (float*)d_out;
                o[OUT1_OFF + (size_t)(b * 3 + 0) * MM + m] = X;
                o[OUT1_OFF + (size_t)(b * 3 + 1) * MM + m] = Y;
                o[OUT1_OFF + (size_t)(b * 3 + 2) * MM + m] = Z;
            } else {
                unsigned short* o = (unsigned short*)d_out;
                o[OUT1_OFF + (size_t)(b * 3 + 0) * MM + m] = f2bf(X);
                o[OUT1_OFF + (size_t)(b * 3 + 1) * MM + m] = f2bf(Y);
                o[OUT1_OFF + (size_t)(b * 3 + 2) * MM + m] = f2bf(Z);
            }
        }
    } else {
        // ---------- persistent kNN + gtemb workers (wave granularity) ----------
        // m-major claim order: freshest available work across all 8 producers
        int lane = tid & 63;
        for (;;) {
            int id = 0;
            if (lane == 0) id = atomicAdd(qhead, 1);
            id = __shfl(id, 0, 64);
            if (id >= BB * MM) break;
            int b = id & 7, m = id >> 3;
            while (__hip_atomic_load(&progress[b * 16], __ATOMIC_ACQUIRE,
                                     __HIP_MEMORY_SCOPE_AGENT) < m)
                __builtin_amdgcn_s_sleep(64);   // ~1.7us; unthrottled polls killed R10
            int bm = b * MM + m;
            const float* cb = coordsC + (size_t)b * 3 * NN;
            float4 ctr = *(const float4*)(centersF + (size_t)bm * 4);
            double cx = (double)ctr.x, cy = (double)ctr.y, cz = (double)ctr.z;
            double cc = (cx * cx + cy * cy) + cz * cz;
            double d[64];
#pragma unroll 4
            for (int j = 0; j < 64; j++) {
                int p = j * 64 + lane;
                double x = (double)cb[p], y = (double)cb[NN + p], z = (double)cb[2 * NN + p];
                double pp = (x * x + y * y) + z * z;
                double dt = (cx * x + cy * y) + cz * z;
                d[j] = (cc + pp) - 2.0 * dt;
            }
            double g8[8]; int a8[8];
#pragma unroll
            for (int g = 0; g < 8; g++) {
                double gd = d[g * 8]; int ga = g * 8;
#pragma unroll
                for (int i = 1; i < 8; i++) {
                    int sl = g * 8 + i;
                    bool rep = d[sl] < gd;
                    gd = rep ? d[sl] : gd; ga = rep ? sl : ga;
                }
                g8[g] = gd; a8[g] = ga;
            }
            unsigned int elo = 0, ehi = 0;
            int res = 0;
#pragma unroll 1
            for (int it = 0; it < 32; it++) {
                double bd = g8[0]; int ba = a8[0];
#pragma unroll
                for (int g = 1; g < 8; g++) {
                    bool rep = g8[g] < bd;
                    bd = rep ? g8[g] : bd; ba = rep ? a8[g] : ba;
                }
                int bp = ba * 64 + lane;
                double wd = bd; int wp = bp;
#pragma unroll
                for (int s = 32; s >= 1; s >>= 1) {
                    double od = __shfl_xor(wd, s, 64);
                    int op = __shfl_xor(wp, s, 64);
                    bool rep = (od < wd) || (od == wd && op < wp);
                    wd = rep ? od : wd; wp = rep ? op : wp;
                }
                res = (lane == it) ? wp : res;
                if (bp == wp) {
                    int slot = ba;
                    if (slot < 32) elo |= (1u << slot); else ehi |= (1u << (slot - 32));
                    int g = slot >> 3;
                    switch (g) {
                        case 0: RESCAN(0) break;
                        case 1: RESCAN(1) break;
                        case 2: RESCAN(2) break;
                        case 3: RESCAN(3) break;
                        case 4: RESCAN(4) break;
                        case 5: RESCAN(5) break;
                        case 6: RESCAN(6) break;
                        case 7: RESCAN(7) break;
                    }
                }
            }
            if (lane < KK) nidx[(size_t)bm * KK + lane] = res;
            float best = -3.0e38f;
            if (fl) {
                const float* tb = (const float*)temb + ((size_t)b * 64 + lane) * NN;
#pragma unroll 4
                for (int k = 0; k < 32; k++) {
                    int nk = __shfl(res, k, 64);
                    best = fmaxf(best, tb[nk]);
                }
            } else {
                const unsigned short* tb = (const unsigned short*)temb + ((size_t)b * 64 + lane) * NN;
#pragma unroll 4
                for (int k = 0; k < 32; k++) {
                    int nk = __shfl(res, k, 64);
                    best = fmaxf(best, bf2f(tb[nk]));
                }
            }
            size_t off = (size_t)OUT2_OFF + ((size_t)(b * 64 + lane)) * MM + m;
            if (fl) ((float*)d_out)[off] = best;
            else    ((unsigned short*)d_out)[off] = f2bf(best);
        }
    }
}

// ================= fused MLP machinery (featT f32 gathers) =================
#define W1Tm(j,c)     (((float*)SM)[(j)*64+(c)])
#define GBUFm(mi,k,c) (((float*)(SM+17152))[(((mi)*32+(k))*66)+(c)])
#define GCm(mi,j,k)   (((float*)(SM+50944))[(((mi)*3+(j))*32)+(k)])
#define NDm(mi,k)     (((int*)(SM+52480))[((mi)*32)+(k)])
#define W2Tm(j,c)     (((float*)SM)[(j)*128+(c)])
#define ACTm(mi,j,k)  (((float*)(SM+32768))[(((mi)*64+(j))*32)+(k)])

__device__ __forceinline__ void mlp1_compute(
    char* SM, int tid, int lane, int mi, int b, int bm,
    const float* __restrict__ featT, const float* __restrict__ coordsC,
    const float* __restrict__ centersF, const int* __restrict__ nidx,
    const float* __restrict__ P, float acc[8][4])
{
    for (int t = tid; t < 64 * 67; t += 256) {
        int c = t / 67, j = t % 67;
        W1Tm(j, c) = P[P_W1 + t];
    }
    if (lane < 32) NDm(mi, lane) = nidx[(size_t)bm * KK + lane] & (NN - 1);
    __syncthreads();
    const float* fb = featT + (size_t)b * NN * 64;
#pragma unroll 4
    for (int q = 0; q < 32; q++) {
        int n = NDm(mi, q);
        GBUFm(mi, q, lane) = fb[(size_t)n * 64 + lane];
    }
    float4 ctr = *(const float4*)(centersF + (size_t)bm * 4);
    const float* cb = coordsC + (size_t)b * 3 * NN;
    if (lane < 32) {
        int n = NDm(mi, lane);
        GCm(mi, 0, lane) = __fsub_rn(cb[n], ctr.x);
        GCm(mi, 1, lane) = __fsub_rn(cb[NN + n], ctr.y);
        GCm(mi, 2, lane) = __fsub_rn(cb[2 * NN + n], ctr.z);
    }
    __syncthreads();
    int c0 = (lane >> 3) * 8;
    int k0 = (lane & 7) * 4;
#pragma unroll
    for (int i = 0; i < 8; i++)
#pragma unroll
        for (int kk = 0; kk < 4; kk++) acc[i][kk] = 0.f;
#pragma unroll
    for (int j = 0; j < 3; j++) {
        float4 a = *(const float4*)&GCm(mi, j, k0);
        float4 w0 = *(const float4*)&W1Tm(j, c0);
        float4 w1v = *(const float4*)&W1Tm(j, c0 + 4);
        float w[8] = {w0.x, w0.y, w0.z, w0.w, w1v.x, w1v.y, w1v.z, w1v.w};
#pragma unroll
        for (int i = 0; i < 8; i++) {
            acc[i][0] = fmaf(w[i], a.x, acc[i][0]);
            acc[i][1] = fmaf(w[i], a.y, acc[i][1]);
            acc[i][2] = fmaf(w[i], a.z, acc[i][2]);
            acc[i][3] = fmaf(w[i], a.w, acc[i][3]);
        }
    }
#pragma unroll 4
    for (int c = 0; c < 64; c++) {
        float f0 = GBUFm(mi, k0 + 0, c);
        float f1 = GBUFm(mi, k0 + 1, c);
        float f2 = GBUFm(mi, k0 + 2, c);
        float f3 = GBUFm(mi, k0 + 3, c);
        int j = 3 + c;
        float4 w0 = *(const float4*)&W1Tm(j, c0);
        float4 w1v = *(const float4*)&W1Tm(j, c0 + 4);
        float w[8] = {w0.x, w0.y, w0.z, w0.w, w1v.x, w1v.y, w1v.z, w1v.w};
#pragma unroll
        for (int i = 0; i < 8; i++) {
            acc[i][0] = fmaf(w[i], f0, acc[i][0]);
            acc[i][1] = fmaf(w[i], f1, acc[i][1]);
            acc[i][2] = fmaf(w[i], f2, acc[i][2]);
            acc[i][3] = fmaf(w[i], f3, acc[i][3]);
        }
    }
}

__device__ __forceinline__ void mlp2_compute(
    char* SM, int tid, int lane, int mi, int b,
    const float acc1[8][4], const float* __restrict__ coef1,
    const float* __restrict__ P, float acc2[16][4])
{
    __syncthreads();
    int c0 = (lane >> 3) * 8;
    int k0 = (lane & 7) * 4;
#pragma unroll
    for (int i = 0; i < 8; i++) {
        int c = c0 + i;
        float sc = coef1[(b * 64 + c) * 2];
        float sh = coef1[(b * 64 + c) * 2 + 1];
        float bb = P[P_B1 + c];
#pragma unroll
        for (int kk = 0; kk < 4; kk++)
            ACTm(mi, c, k0 + kk) = swishf(fmaf(acc1[i][kk] + bb, sc, sh));
    }
    for (int t = tid; t < 128 * 64; t += 256) {
        int c = t >> 6, j = t & 63;
        W2Tm(j, c) = P[P_W2 + t];
    }
    __syncthreads();
    int c02 = (lane >> 3) * 16;
#pragma unroll
    for (int i = 0; i < 16; i++)
#pragma unroll
        for (int kk = 0; kk < 4; kk++) acc2[i][kk] = 0.f;
#pragma unroll 4
    for (int j = 0; j < 64; j++) {
        float4 a = *(const float4*)&ACTm(mi, j, k0);
        float4 w0 = *(const float4*)&W2Tm(j, c02);
        float4 w1v = *(const float4*)&W2Tm(j, c02 + 4);
        float4 w2v = *(const float4*)&W2Tm(j, c02 + 8);
        float4 w3 = *(const float4*)&W2Tm(j, c02 + 12);
        float w[16] = {w0.x, w0.y, w0.z, w0.w, w1v.x, w1v.y, w1v.z, w1v.w,
                       w2v.x, w2v.y, w2v.z, w2v.w, w3.x, w3.y, w3.z, w3.w};
#pragma unroll
        for (int i = 0; i < 16; i++) {
            acc2[i][0] = fmaf(w[i], a.x, acc2[i][0]);
            acc2[i][1] = fmaf(w[i], a.y, acc2[i][1]);
            acc2[i][2] = fmaf(w[i], a.z, acc2[i][2]);
            acc2[i][3] = fmaf(w[i], a.w, acc2[i][3]);
        }
    }
}

// ---------------- MLP1 + GN1 block-partial stats
__global__ __launch_bounds__(256) void k_mlp1s(
    const float* __restrict__ featT, const float* __restrict__ coordsC,
    const float* __restrict__ centersF, const int* __restrict__ nidx,
    const float* __restrict__ P, float* __restrict__ part1)
{
    __shared__ __align__(16) char smem[53248];
    char* SM = smem;
    int tid = threadIdx.x, blk = blockIdx.x;
    int b = blk >> 8, m0 = (blk & 255) * 4;
    int mi = tid >> 6, lane = tid & 63;
    int bm = b * MM + m0 + mi;
    float acc[8][4];
    mlp1_compute(SM, tid, lane, mi, b, bm, featT, coordsC, centersF, nidx, P, acc);
    int c0 = (lane >> 3) * 8;
    float s = 0.f, s2 = 0.f;
#pragma unroll
    for (int i = 0; i < 8; i++) {
        float bb = P[P_B1 + c0 + i];
#pragma unroll
        for (int kk = 0; kk < 4; kk++) {
            float v = acc[i][kk] + bb;
            s += v; s2 = fmaf(v, v, s2);
        }
    }
    s += __shfl_xor(s, 1, 64); s += __shfl_xor(s, 2, 64); s += __shfl_xor(s, 4, 64);
    s2 += __shfl_xor(s2, 1, 64); s2 += __shfl_xor(s2, 2, 64); s2 += __shfl_xor(s2, 4, 64);
    float* sred = (float*)(SM + 52992);
    __syncthreads();
    if ((lane & 7) == 0) {
        int g = lane >> 3;
        sred[(mi * 8 + g) * 2] = s;
        sred[(mi * 8 + g) * 2 + 1] = s2;
    }
    __syncthreads();
    if (tid < 16) {
        int g = tid >> 1, w = tid & 1;
        float t = sred[(0 * 8 + g) * 2 + w] + sred[(1 * 8 + g) * 2 + w]
                + sred[(2 * 8 + g) * 2 + w] + sred[(3 * 8 + g) * 2 + w];
        part1[blk * 16 + g * 2 + w] = t;
    }
}

__global__ __launch_bounds__(512) void k_coef1(
    const float* __restrict__ part1, const float* __restrict__ P,
    float* __restrict__ coef1)
{
    __shared__ float red[512];
    int tid = threadIdx.x;
    int out = tid >> 2, sub = tid & 3;
    int b = out >> 4, gw = out & 15;
    const float* p = part1 + (size_t)(b * 256 + sub * 64) * 16 + gw;
    float s = 0.f;
#pragma unroll 8
    for (int r = 0; r < 64; r++) s += p[r * 16];
    red[out * 4 + sub] = s;
    __syncthreads();
    if (tid < 64) {
        int bb = tid >> 3, g = tid & 7;
        int o1 = (bb * 16 + g * 2) * 4, o2 = o1 + 4;
        float S = red[o1] + red[o1 + 1] + red[o1 + 2] + red[o1 + 3];
        float Q = red[o2] + red[o2 + 1] + red[o2 + 2] + red[o2 + 3];
        float inv_n = 1.0f / 262144.0f;
        float mean = S * inv_n;
        float var = Q * inv_n - mean * mean;
        float inv = rsqrtf(var + 1e-5f);
        for (int i = 0; i < 8; i++) {
            int c = g * 8 + i;
            float sc = P[P_G1 + c] * inv;
            coef1[(bb * 64 + c) * 2] = sc;
            coef1[(bb * 64 + c) * 2 + 1] = P[P_BE1 + c] - mean * sc;
        }
    }
}

__global__ __launch_bounds__(256) void k_mlp2s(
    const float* __restrict__ featT, const float* __restrict__ coordsC,
    const float* __restrict__ centersF, const int* __restrict__ nidx,
    const float* __restrict__ P, const float* __restrict__ coef1,
    float* __restrict__ part2)
{
    __shared__ __align__(16) char smem[65536];
    char* SM = smem;
    int tid = threadIdx.x, blk = blockIdx.x;
    int b = blk >> 8, m0 = (blk & 255) * 4;
    int mi = tid >> 6, lane = tid & 63;
    int bm = b * MM + m0 + mi;
    float acc1[8][4];
    mlp1_compute(SM, tid, lane, mi, b, bm, featT, coordsC, centersF, nidx, P, acc1);
    float acc2[16][4];
    mlp2_compute(SM, tid, lane, mi, b, acc1, coef1, P, acc2);
    int c02 = (lane >> 3) * 16;
    float s = 0.f, s2 = 0.f;
#pragma unroll
    for (int i = 0; i < 16; i++) {
        float bb = P[P_B2 + c02 + i];
#pragma unroll
        for (int kk = 0; kk < 4; kk++) {
            float v = acc2[i][kk] + bb;
            s += v; s2 = fmaf(v, v, s2);
        }
    }
    s += __shfl_xor(s, 1, 64); s += __shfl_xor(s, 2, 64); s += __shfl_xor(s, 4, 64);
    s2 += __shfl_xor(s2, 1, 64); s2 += __shfl_xor(s2, 2, 64); s2 += __shfl_xor(s2, 4, 64);
    __syncthreads();
    float* sred = (float*)SM;
    if ((lane & 7) == 0) {
        int g = lane >> 3;
        sred[(mi * 8 + g) * 2] = s;
        sred[(mi * 8 + g) * 2 + 1] = s2;
    }
    __syncthreads();
    if (tid < 16) {
        int g = tid >> 1, w = tid & 1;
        float t = sred[(0 * 8 + g) * 2 + w] + sred[(1 * 8 + g) * 2 + w]
                + sred[(2 * 8 + g) * 2 + w] + sred[(3 * 8 + g) * 2 + w];
        part2[blk * 16 + g * 2 + w] = t;
    }
}

__global__ __launch_bounds__(512) void k_coef2(
    const float* __restrict__ part2, const float* __restrict__ P,
    float* __restrict__ coef2)
{
    __shared__ float red[512];
    int tid = threadIdx.x;
    int out = tid >> 2, sub = tid & 3;
    int b = out >> 4, gw = out & 15;
    const float* p = part2 + (size_t)(b * 256 + sub * 64) * 16 + gw;
    float s = 0.f;
#pragma unroll 8
    for (int r = 0; r < 64; r++) s += p[r * 16];
    red[out * 4 + sub] = s;
    __syncthreads();
    if (tid < 64) {
        int bb = tid >> 3, g = tid & 7;
        int o1 = (bb * 16 + g * 2) * 4, o2 = o1 + 4;
        float S = red[o1] + red[o1 + 1] + red[o1 + 2] + red[o1 + 3];
        float Q = red[o2] + red[o2 + 1] + red[o2 + 2] + red[o2 + 3];
        float inv_n = 1.0f / 524288.0f;
        float mean = S * inv_n;
        float var = Q * inv_n - mean * mean;
        float inv = rsqrtf(var + 1e-5f);
        for (int i = 0; i < 16; i++) {
            int c = g * 16 + i;
            float sc = P[P_G2 + c] * inv;
            coef2[(bb * 128 + c) * 2] = sc;
            coef2[(bb * 128 + c) * 2 + 1] = P[P_BE2 + c] - mean * sc;
        }
    }
}

__global__ __launch_bounds__(256) void k_final(
    const float* __restrict__ featT, const float* __restrict__ coordsC,
    const float* __restrict__ centersF, const int* __restrict__ nidx,
    const float* __restrict__ P, const float* __restrict__ coef1,
    const float* __restrict__ coef2,
    void* __restrict__ d_out, const void* __restrict__ feat)
{
    __shared__ __align__(16) char smem[65536];
    char* SM = smem;
    int tid = threadIdx.x, blk = blockIdx.x;
    if (tid < 64) {
        int fl0 = detect_flag_wave((const unsigned short*)feat, tid);
        if (tid == 0) *(int*)(SM + 53248) = fl0;
    }
    __syncthreads();
    int fl = *(int*)(SM + 53248);
    int b = blk >> 8, m0 = (blk & 255) * 4;
    int mi = tid >> 6, lane = tid & 63;
    int bm = b * MM + m0 + mi;
    float acc1[8][4];
    mlp1_compute(SM, tid, lane, mi, b, bm, featT, coordsC, centersF, nidx, P, acc1);
    float acc2[16][4];
    mlp2_compute(SM, tid, lane, mi, b, acc1, coef1, P, acc2);
    int c02 = (lane >> 3) * 16;
    float mx[16];
#pragma unroll
    for (int i = 0; i < 16; i++) {
        int c = c02 + i;
        float sc = coef2[(b * 128 + c) * 2];
        float sh = coef2[(b * 128 + c) * 2 + 1];
        float bb = P[P_B2 + c];
        float v = -3.0e38f;
#pragma unroll
        for (int kk = 0; kk < 4; kk++)
            v = fmaxf(v, swishf(fmaf(acc2[i][kk] + bb, sc, sh)));
        v = fmaxf(v, __shfl_xor(v, 1, 64));
        v = fmaxf(v, __shfl_xor(v, 2, 64));
        v = fmaxf(v, __shfl_xor(v, 4, 64));
        mx[i] = v;
    }
    if ((lane & 7) == 0) {
        int m = m0 + mi;
#pragma unroll
        for (int i = 0; i < 16; i++) {
            size_t off = (size_t)(b * 128 + c02 + i) * MM + m;
            if (fl) ((float*)d_out)[off] = mx[i];
            else    ((unsigned short*)d_out)[off] = f2bf(mx[i]);
        }
    }
}

extern "C" void kernel_launch(void* const* d_in, const int* in_sizes, int n_in,
                              void* d_out, int out_size, void* d_ws, size_t ws_size,
                              hipStream_t stream) {
    (void)in_sizes; (void)n_in; (void)out_size; (void)ws_size;
    const void* feat = d_in[0];
    const void* coords = d_in[1];
    const void* temb = d_in[2];

    // workspace: 10,288,192 bytes total
    char* ws = (char*)d_ws;
    int* qhead = (int*)ws;                                 // @0
    int* progress = (int*)(ws + 512);                      // 8 x 64B-strided ints
    float* coordsC = (float*)(ws + 1088);                  // 393,216
    float* paramsC = (float*)(ws + 394304);                // 52,224
    float* centersF = (float*)(ws + 446528);               // 131,072
    int* nidx = (int*)(ws + 577600);                       // 1,048,576
    float* part1 = (float*)(ws + 1626176);                 // 131,072
    float* part2 = (float*)(ws + 1757248);                 // 131,072
    float* coef1 = (float*)(ws + 1888320);                 // 4,096
    float* coef2 = (float*)(ws + 1892416);                 // 8,192
    float* featT = (float*)(ws + 1900608);                 // 8,388,608 -> 10,289,216

    k_cvt_all<<<947, 256, 0, stream>>>(feat, coords, featT, coordsC, paramsC,
                                       qhead, progress,
                                       d_in[3], d_in[4], d_in[5], d_in[6],
                                       d_in[7], d_in[8], d_in[9], d_in[10]);
    k_fpsknn<<<256, 256, 0, stream>>>(coords, coordsC, centersF, nidx, temb,
                                      feat, d_out, qhead, progress);
    k_mlp1s<<<2048, 256, 0, stream>>>(featT, coordsC, centersF, nidx, paramsC, part1);
    k_coef1<<<1, 512, 0, stream>>>(part1, paramsC, coef1);
    k_mlp2s<<<2048, 256, 0, stream>>>(featT, coordsC, centersF, nidx, paramsC, coef1, part2);
    k_coef2<<<1, 512, 0, stream>>>(part2, paramsC, coef2);
    k_final<<<2048, 256, 0, stream>>>(featT, coordsC, centersF, nidx, paramsC, coef1, coef2, d_out, feat);
}

// Round 12
// 1540.343 us; speedup vs baseline: 1.4612x; 1.0714x over previous
//
#include <hip/hip_runtime.h>
#include <stdint.h>

#define BB 8
#define NN 4096
#define MM 1024
#define KK 32

__device__ __forceinline__ float bf2f(unsigned short u) {
    union { unsigned int i; float f; } v; v.i = ((unsigned int)u) << 16; return v.f;
}
__device__ __forceinline__ unsigned short f2bf(float f) {
    union { float f; unsigned int i; } v; v.f = f;
    unsigned int x = v.i;
    x += 0x7fffu + ((x >> 16) & 1u);
    return (unsigned short)(x >> 16);
}
__device__ __forceinline__ float swishf(float y) {
    return __fdividef(y, 1.0f + __expf(-y));
}

// out element offsets (dtype-independent)
#define OUT1_OFF 1048576
#define OUT2_OFF 1073152

// params canonical f32 layout (floats)
#define P_W1 0
#define P_B1 4288
#define P_G1 4352
#define P_BE1 4416
#define P_W2 4480
#define P_B2 12672
#define P_G2 12800
#define P_BE2 12928

__device__ __forceinline__ int detect_flag_wave(const unsigned short* f, int lane) {
    unsigned short u = f[lane * 2];
    float x = fabsf(bf2f(u));
    bool ext = (u != 0) && (x > 100.0f || x < 1e-30f);
    unsigned long long m = __ballot(ext);
    return (__popcll(m) >= 16) ? 1 : 0;
}

// ================= launch 1: conversions + sync/stat init =================
__global__ __launch_bounds__(256) void k_cvt_all(
    const void* __restrict__ feat, const void* __restrict__ coords,
    float* __restrict__ featT, float* __restrict__ coordsC,
    float* __restrict__ paramsC,
    int* __restrict__ qhead, int* __restrict__ progress,
    float* __restrict__ stats1,   // 256 f32 (stats1) + 256 f32 (stats2) contiguous
    const void* W1, const void* b1, const void* g1, const void* be1,
    const void* W2, const void* b2, const void* g2, const void* be2)
{
    __shared__ float tile[64][65];
    __shared__ int sflag;
    int tid = threadIdx.x, blk = blockIdx.x;
    if (tid < 64) {
        int fl0 = detect_flag_wave((const unsigned short*)feat, tid);
        if (tid == 0) sflag = fl0;
    }
    __syncthreads();
    int fl = sflag;
    if (blk == 0) {
        if (tid == 0) *qhead = 0;
        if (tid < 8) progress[tid * 16] = -1;   // 64B-strided lines
        stats1[tid] = 0.f;                      // stats1[0..255] + stats2[256..511]
        stats1[tid + 256] = 0.f;
    }
    if (blk < 512) {
        int i = blk;
        int b = i >> 6, n0 = (i & 63) * 64;
        int c = tid >> 2, q = tid & 3;
        size_t base = ((size_t)b * 64 + c) * NN + n0 + q * 16;
        if (fl) {
            const float* sp = (const float*)feat + base;
#pragma unroll
            for (int j = 0; j < 16; j++) tile[c][q * 16 + j] = sp[j];
        } else {
            const unsigned short* sp = (const unsigned short*)feat + base;
#pragma unroll
            for (int j = 0; j < 16; j++) tile[c][q * 16 + j] = bf2f(sp[j]);
        }
        __syncthreads();
        int n = tid >> 2;
        float* dp = featT + ((size_t)b * NN + n0 + n) * 64 + q * 16;
#pragma unroll
        for (int j = 0; j < 16; j++) dp[j] = tile[q * 16 + j][n];
    } else if (blk < 896) {
        int idx = (blk - 512) * 256 + tid;
        coordsC[idx] = fl ? ((const float*)coords)[idx]
                          : bf2f(((const unsigned short*)coords)[idx]);
    } else {
        int idx = (blk - 896) * 256 + tid;
        if (idx < 13056) {
            const void* src; int off;
            if (idx < 4288)       { src = W1;  off = idx; }
            else if (idx < 4352)  { src = b1;  off = idx - 4288; }
            else if (idx < 4416)  { src = g1;  off = idx - 4352; }
            else if (idx < 4480)  { src = be1; off = idx - 4416; }
            else if (idx < 12672) { src = W2;  off = idx - 4480; }
            else if (idx < 12800) { src = b2;  off = idx - 12672; }
            else if (idx < 12928) { src = g2;  off = idx - 12800; }
            else                  { src = be2; off = idx - 12928; }
            paramsC[idx] = fl ? ((const float*)src)[off]
                              : bf2f(((const unsigned short*)src)[off]);
        }
    }
}

// ====== shared LDS macros (worker blocks + MLP kernels use same layout) ====
#define W1Tm(j,c)     (((float*)SM)[(j)*64+(c)])
#define GBUFm(mi,k,c) (((float*)(SM+17152))[(((mi)*32+(k))*66)+(c)])
#define GCm(mi,j,k)   (((float*)(SM+50944))[(((mi)*3+(j))*32)+(k)])
#define NDm(mi,k)     (((int*)(SM+52480))[((mi)*32)+(k)])
#define W2Tm(j,c)     (((float*)SM)[(j)*128+(c)])
#define ACTm(mi,j,k)  (((float*)(SM+32768))[(((mi)*64+(j))*32)+(k)])

// ================= launch 2: FPS (blocks 0..7) + persistent workers =======
// Workers: kNN + gtemb + MLP1/GN1-stat accumulation per claimed center.
// 256 blocks, 55296B LDS -> max 2 blocks/CU, capacity 512 >= 256: all
// resident. Relaxed spin + ONE acquire load per task (R11's per-poll
// acquire invalidated L1/L2 -> 770MB FETCH).
struct PW { double d; int p; int q; };
#define PSM_XS   ((float*)(SM))
#define PSM_YS   ((float*)(SM + 16384))
#define PSM_ZS   ((float*)(SM + 32768))
#define PSM_HIST ((int*)(SM + 49152))
#define PSM_PWB  ((PW*)(SM + 53248))
#define PSM_SF   ((int*)(SM + 53376))

#define RESCAN(G) { \
    double gd = 1.0e300; int ga = (G) * 8; \
    _Pragma("unroll") \
    for (int i = 0; i < 8; i++) { \
        int sl = (G) * 8 + i; \
        unsigned int bit = (sl < 32) ? (elo >> sl) : (ehi >> (sl - 32)); \
        double cd = (bit & 1u) ? 1.0e300 : d[sl]; \
        bool rep = cd < gd; \
        gd = rep ? cd : gd; ga = rep ? sl : ga; \
    } \
    g8[(G)] = gd; a8[(G)] = ga; }

__global__ __launch_bounds__(256) void k_fpsknn(
    const void* __restrict__ coords, const float* __restrict__ coordsC,
    float* __restrict__ centersF, int* __restrict__ nidx,
    const void* __restrict__ temb, const void* __restrict__ feat,
    const float* __restrict__ featT, const float* __restrict__ paramsC,
    float* __restrict__ stats1,
    void* __restrict__ d_out,
    int* __restrict__ qhead, int* __restrict__ progress)
{
    __shared__ __align__(16) char SM[55296];
    int tid = threadIdx.x;
    int blk = blockIdx.x;
    if (tid < 64) {
        int fl0 = detect_flag_wave((const unsigned short*)feat, tid);
        if (tid == 0) *PSM_SF = fl0;
    }
    __syncthreads();
    int fl = *PSM_SF;

    if (blk < 8) {
        // ---------- FPS in f64 (R7-identical math), 256 thr ----------
        int b = blk;
        if (fl) {
            const float* cb = (const float*)coords + (size_t)b * 3 * NN;
#pragma unroll
            for (int i = 0; i < 16; i++) {
                int p = tid + i * 256;
                PSM_XS[p] = cb[p]; PSM_YS[p] = cb[NN + p]; PSM_ZS[p] = cb[2 * NN + p];
            }
        } else {
            const unsigned short* cb = (const unsigned short*)coords + (size_t)b * 3 * NN;
#pragma unroll
            for (int i = 0; i < 16; i++) {
                int p = tid + i * 256;
                PSM_XS[p] = bf2f(cb[p]); PSM_YS[p] = bf2f(cb[NN + p]); PSM_ZS[p] = bf2f(cb[2 * NN + p]);
            }
        }
        if (tid == 0) PSM_HIST[0] = 0;
        __syncthreads();
        if (tid == 0) {
            *(float4*)(centersF + (size_t)b * MM * 4) =
                make_float4(PSM_XS[0], PSM_YS[0], PSM_ZS[0], 0.f);
            __hip_atomic_store(&progress[b * 16], 0, __ATOMIC_RELEASE, __HIP_MEMORY_SCOPE_AGENT);
        }
        int base = tid * 16;
        double px[16], py[16], pz[16], dist[16];
        double x0 = (double)PSM_XS[0], y0 = (double)PSM_YS[0], z0 = (double)PSM_ZS[0];
        double bd = -1.0; int bp = base;
#pragma unroll
        for (int j = 0; j < 16; j++) {
            px[j] = (double)PSM_XS[base + j]; py[j] = (double)PSM_YS[base + j]; pz[j] = (double)PSM_ZS[base + j];
            double dx = px[j] - x0, dy = py[j] - y0, dz = pz[j] - z0;
            dist[j] = fma(dz, dz, fma(dy, dy, dx * dx));
            bool rep = dist[j] > bd;
            bd = rep ? dist[j] : bd; bp = rep ? base + j : bp;
        }
        int lane = tid & 63, wid = tid >> 6;
#pragma unroll 1
        for (int s = 1; s < MM; s++) {
#pragma unroll
            for (int m = 32; m >= 1; m >>= 1) {
                double od = __shfl_xor(bd, m, 64);
                int op = __shfl_xor(bp, m, 64);
                bool rep = (od > bd) || (od == bd && op < bp);
                bd = rep ? od : bd; bp = rep ? op : bp;
            }
            int par = s & 1;
            if (lane == 0) { PW w; w.d = bd; w.p = bp; w.q = 0; PSM_PWB[par * 4 + wid] = w; }
            __syncthreads();
            PW w0 = PSM_PWB[par * 4 + 0];
            double wd = w0.d; int wp = w0.p;
#pragma unroll
            for (int w = 1; w < 4; w++) {
                PW ww = PSM_PWB[par * 4 + w];
                bool rep = (ww.d > wd) || (ww.d == wd && ww.p < wp);
                wd = rep ? ww.d : wd; wp = rep ? ww.p : wp;
            }
            if (tid == 0) PSM_HIST[s] = wp;
            // progressive publish: 32 centers every 32 steps (>=32 barriers old)
            if ((s & 31) == 31 && s >= 63 && wid == ((s >> 5) & 3)) {
                int s0 = s - 63;
                if (lane < 32) {
                    int far = PSM_HIST[s0 + lane];
                    *(float4*)(centersF + ((size_t)b * MM + s0 + lane) * 4) =
                        make_float4(PSM_XS[far], PSM_YS[far], PSM_ZS[far], 0.f);
                }
                if (lane == 0)
                    __hip_atomic_store(&progress[b * 16], s0 + 31,
                                       __ATOMIC_RELEASE, __HIP_MEMORY_SCOPE_AGENT);
            }
            double fx = (double)PSM_XS[wp], fy = (double)PSM_YS[wp], fz = (double)PSM_ZS[wp];
            bd = -1.0; bp = base;
#pragma unroll
            for (int j = 0; j < 16; j++) {
                double dx = px[j] - fx, dy = py[j] - fy, dz = pz[j] - fz;
                double d = fma(dz, dz, fma(dy, dy, dx * dx));
                dist[j] = fmin(dist[j], d);
                bool rep = dist[j] > bd;
                bd = rep ? dist[j] : bd; bp = rep ? base + j : bp;
            }
        }
        __syncthreads();
        if (tid < 32) {
            int far = PSM_HIST[992 + tid];
            *(float4*)(centersF + ((size_t)b * MM + 992 + tid) * 4) =
                make_float4(PSM_XS[far], PSM_YS[far], PSM_ZS[far], 0.f);
        }
        if (tid == 0)
            __hip_atomic_store(&progress[b * 16], 1023,
                               __ATOMIC_RELEASE, __HIP_MEMORY_SCOPE_AGENT);
#pragma unroll
        for (int i = 0; i < 4; i++) {
            int m = tid + i * 256;
            int far = PSM_HIST[m];
            float X = PSM_XS[far], Y = PSM_YS[far], Z = PSM_ZS[far];
            if (fl) {
                float* o = (float*)d_out;
                o[OUT1_OFF + (size_t)(b * 3 + 0) * MM + m] = X;
                o[OUT1_OFF + (size_t)(b * 3 + 1) * MM + m] = Y;
                o[OUT1_OFF + (size_t)(b * 3 + 2) * MM + m] = Z;
            } else {
                unsigned short* o = (unsigned short*)d_out;
                o[OUT1_OFF + (size_t)(b * 3 + 0) * MM + m] = f2bf(X);
                o[OUT1_OFF + (size_t)(b * 3 + 1) * MM + m] = f2bf(Y);
                o[OUT1_OFF + (size_t)(b * 3 + 2) * MM + m] = f2bf(Z);
            }
        }
    } else {
        // ---------- persistent workers: kNN + gtemb + MLP1/GN1 stats ----------
        int lane = tid & 63, wid = tid >> 6;
        // stage W1 once per block
        for (int t = tid; t < 64 * 67; t += 256) {
            int c = t / 67, j = t % 67;
            W1Tm(j, c) = paramsC[P_W1 + t];
        }
        __syncthreads();
        for (;;) {
            int id = 0;
            if (lane == 0) id = atomicAdd(qhead, 1);
            id = __shfl(id, 0, 64);
            if (id >= BB * MM) break;
            int b = id & 7, m = id >> 3;
            // relaxed spin (no cache invalidation), then ONE acquire
            while (__hip_atomic_load(&progress[b * 16], __ATOMIC_RELAXED,
                                     __HIP_MEMORY_SCOPE_AGENT) < m)
                __builtin_amdgcn_s_sleep(64);
            (void)__hip_atomic_load(&progress[b * 16], __ATOMIC_ACQUIRE,
                                    __HIP_MEMORY_SCOPE_AGENT);
            int bm = b * MM + m;
            const float* cb = coordsC + (size_t)b * 3 * NN;
            float4 ctr = *(const float4*)(centersF + (size_t)bm * 4);
            double cx = (double)ctr.x, cy = (double)ctr.y, cz = (double)ctr.z;
            double cc = (cx * cx + cy * cy) + cz * cz;
            double d[64];
#pragma unroll 4
            for (int j = 0; j < 64; j++) {
                int p = j * 64 + lane;
                double x = (double)cb[p], y = (double)cb[NN + p], z = (double)cb[2 * NN + p];
                double pp = (x * x + y * y) + z * z;
                double dt = (cx * x + cy * y) + cz * z;
                d[j] = (cc + pp) - 2.0 * dt;
            }
            double g8[8]; int a8[8];
#pragma unroll
            for (int g = 0; g < 8; g++) {
                double gd = d[g * 8]; int ga = g * 8;
#pragma unroll
                for (int i = 1; i < 8; i++) {
                    int sl = g * 8 + i;
                    bool rep = d[sl] < gd;
                    gd = rep ? d[sl] : gd; ga = rep ? sl : ga;
                }
                g8[g] = gd; a8[g] = ga;
            }
            unsigned int elo = 0, ehi = 0;
            int res = 0;
#pragma unroll 1
            for (int it = 0; it < 32; it++) {
                double bd = g8[0]; int ba = a8[0];
#pragma unroll
                for (int g = 1; g < 8; g++) {
                    bool rep = g8[g] < bd;
                    bd = rep ? g8[g] : bd; ba = rep ? a8[g] : ba;
                }
                int bp = ba * 64 + lane;
                double wd = bd; int wp = bp;
#pragma unroll
                for (int s = 32; s >= 1; s >>= 1) {
                    double od = __shfl_xor(wd, s, 64);
                    int op = __shfl_xor(wp, s, 64);
                    bool rep = (od < wd) || (od == wd && op < wp);
                    wd = rep ? od : wd; wp = rep ? op : wp;
                }
                res = (lane == it) ? wp : res;
                if (bp == wp) {
                    int slot = ba;
                    if (slot < 32) elo |= (1u << slot); else ehi |= (1u << (slot - 32));
                    int g = slot >> 3;
                    switch (g) {
                        case 0: RESCAN(0) break;
                        case 1: RESCAN(1) break;
                        case 2: RESCAN(2) break;
                        case 3: RESCAN(3) break;
                        case 4: RESCAN(4) break;
                        case 5: RESCAN(5) break;
                        case 6: RESCAN(6) break;
                        case 7: RESCAN(7) break;
                    }
                }
            }
            if (lane < KK) nidx[(size_t)bm * KK + lane] = res;
            // gtemb
            float best = -3.0e38f;
            if (fl) {
                const float* tb = (const float*)temb + ((size_t)b * 64 + lane) * NN;
#pragma unroll 4
                for (int k = 0; k < 32; k++) {
                    int nk = __shfl(res, k, 64);
                    best = fmaxf(best, tb[nk]);
                }
            } else {
                const unsigned short* tb = (const unsigned short*)temb + ((size_t)b * 64 + lane) * NN;
#pragma unroll 4
                for (int k = 0; k < 32; k++) {
                    int nk = __shfl(res, k, 64);
                    best = fmaxf(best, bf2f(tb[nk]));
                }
            }
            size_t off = (size_t)OUT2_OFF + ((size_t)(b * 64 + lane)) * MM + m;
            if (fl) ((float*)d_out)[off] = best;
            else    ((unsigned short*)d_out)[off] = f2bf(best);
            // ---- MLP1 for this center (same math/layout as old k_mlp1s) ----
            if (lane < 32) NDm(wid, lane) = res & (NN - 1);
            const float* fb = featT + (size_t)b * NN * 64;
#pragma unroll 4
            for (int q = 0; q < 32; q++) {
                int n = NDm(wid, q);
                GBUFm(wid, q, lane) = fb[(size_t)n * 64 + lane];
            }
            if (lane < 32) {
                int n = NDm(wid, lane);
                GCm(wid, 0, lane) = __fsub_rn(cb[n], ctr.x);
                GCm(wid, 1, lane) = __fsub_rn(cb[NN + n], ctr.y);
                GCm(wid, 2, lane) = __fsub_rn(cb[2 * NN + n], ctr.z);
            }
            int c0 = (lane >> 3) * 8;
            int k0 = (lane & 7) * 4;
            float acc[8][4];
#pragma unroll
            for (int i = 0; i < 8; i++)
#pragma unroll
                for (int kk = 0; kk < 4; kk++) acc[i][kk] = 0.f;
#pragma unroll
            for (int j = 0; j < 3; j++) {
                float4 a = *(const float4*)&GCm(wid, j, k0);
                float4 w0 = *(const float4*)&W1Tm(j, c0);
                float4 w1v = *(const float4*)&W1Tm(j, c0 + 4);
                float w[8] = {w0.x, w0.y, w0.z, w0.w, w1v.x, w1v.y, w1v.z, w1v.w};
#pragma unroll
                for (int i = 0; i < 8; i++) {
                    acc[i][0] = fmaf(w[i], a.x, acc[i][0]);
                    acc[i][1] = fmaf(w[i], a.y, acc[i][1]);
                    acc[i][2] = fmaf(w[i], a.z, acc[i][2]);
                    acc[i][3] = fmaf(w[i], a.w, acc[i][3]);
                }
            }
#pragma unroll 4
            for (int c = 0; c < 64; c++) {
                float f0 = GBUFm(wid, k0 + 0, c);
                float f1 = GBUFm(wid, k0 + 1, c);
                float f2 = GBUFm(wid, k0 + 2, c);
                float f3 = GBUFm(wid, k0 + 3, c);
                int j = 3 + c;
                float4 w0 = *(const float4*)&W1Tm(j, c0);
                float4 w1v = *(const float4*)&W1Tm(j, c0 + 4);
                float w[8] = {w0.x, w0.y, w0.z, w0.w, w1v.x, w1v.y, w1v.z, w1v.w};
#pragma unroll
                for (int i = 0; i < 8; i++) {
                    acc[i][0] = fmaf(w[i], f0, acc[i][0]);
                    acc[i][1] = fmaf(w[i], f1, acc[i][1]);
                    acc[i][2] = fmaf(w[i], f2, acc[i][2]);
                    acc[i][3] = fmaf(w[i], f3, acc[i][3]);
                }
            }
            float s = 0.f, s2 = 0.f;
#pragma unroll
            for (int i = 0; i < 8; i++) {
                float bb = paramsC[P_B1 + c0 + i];
#pragma unroll
                for (int kk = 0; kk < 4; kk++) {
                    float v = acc[i][kk] + bb;
                    s += v; s2 = fmaf(v, v, s2);
                }
            }
            s += __shfl_xor(s, 1, 64); s += __shfl_xor(s, 2, 64); s += __shfl_xor(s, 4, 64);
            s2 += __shfl_xor(s2, 1, 64); s2 += __shfl_xor(s2, 2, 64); s2 += __shfl_xor(s2, 4, 64);
            if ((lane & 7) == 0) {
                int g = lane >> 3;
                atomicAdd(&stats1[(b * 8 + g) * 2], s);
                atomicAdd(&stats1[(b * 8 + g) * 2 + 1], s2);
            }
        }
    }
}

// ================= fused MLP machinery (featT f32 gathers) =================
__device__ __forceinline__ void mlp1_compute(
    char* SM, int tid, int lane, int mi, int b, int bm,
    const float* __restrict__ featT, const float* __restrict__ coordsC,
    const float* __restrict__ centersF, const int* __restrict__ nidx,
    const float* __restrict__ P, float acc[8][4])
{
    for (int t = tid; t < 64 * 67; t += 256) {
        int c = t / 67, j = t % 67;
        W1Tm(j, c) = P[P_W1 + t];
    }
    if (lane < 32) NDm(mi, lane) = nidx[(size_t)bm * KK + lane] & (NN - 1);
    __syncthreads();
    const float* fb = featT + (size_t)b * NN * 64;
#pragma unroll 4
    for (int q = 0; q < 32; q++) {
        int n = NDm(mi, q);
        GBUFm(mi, q, lane) = fb[(size_t)n * 64 + lane];
    }
    float4 ctr = *(const float4*)(centersF + (size_t)bm * 4);
    const float* cb = coordsC + (size_t)b * 3 * NN;
    if (lane < 32) {
        int n = NDm(mi, lane);
        GCm(mi, 0, lane) = __fsub_rn(cb[n], ctr.x);
        GCm(mi, 1, lane) = __fsub_rn(cb[NN + n], ctr.y);
        GCm(mi, 2, lane) = __fsub_rn(cb[2 * NN + n], ctr.z);
    }
    __syncthreads();
    int c0 = (lane >> 3) * 8;
    int k0 = (lane & 7) * 4;
#pragma unroll
    for (int i = 0; i < 8; i++)
#pragma unroll
        for (int kk = 0; kk < 4; kk++) acc[i][kk] = 0.f;
#pragma unroll
    for (int j = 0; j < 3; j++) {
        float4 a = *(const float4*)&GCm(mi, j, k0);
        float4 w0 = *(const float4*)&W1Tm(j, c0);
        float4 w1v = *(const float4*)&W1Tm(j, c0 + 4);
        float w[8] = {w0.x, w0.y, w0.z, w0.w, w1v.x, w1v.y, w1v.z, w1v.w};
#pragma unroll
        for (int i = 0; i < 8; i++) {
            acc[i][0] = fmaf(w[i], a.x, acc[i][0]);
            acc[i][1] = fmaf(w[i], a.y, acc[i][1]);
            acc[i][2] = fmaf(w[i], a.z, acc[i][2]);
            acc[i][3] = fmaf(w[i], a.w, acc[i][3]);
        }
    }
#pragma unroll 4
    for (int c = 0; c < 64; c++) {
        float f0 = GBUFm(mi, k0 + 0, c);
        float f1 = GBUFm(mi, k0 + 1, c);
        float f2 = GBUFm(mi, k0 + 2, c);
        float f3 = GBUFm(mi, k0 + 3, c);
        int j = 3 + c;
        float4 w0 = *(const float4*)&W1Tm(j, c0);
        float4 w1v = *(const float4*)&W1Tm(j, c0 + 4);
        float w[8] = {w0.x, w0.y, w0.z, w0.w, w1v.x, w1v.y, w1v.z, w1v.w};
#pragma unroll
        for (int i = 0; i < 8; i++) {
            acc[i][0] = fmaf(w[i], f0, acc[i][0]);
            acc[i][1] = fmaf(w[i], f1, acc[i][1]);
            acc[i][2] = fmaf(w[i], f2, acc[i][2]);
            acc[i][3] = fmaf(w[i], f3, acc[i][3]);
        }
    }
}

// GN1 coefs computed inline from stats1 (one group per lane)
__device__ __forceinline__ void mlp2_compute(
    char* SM, int tid, int lane, int mi, int b,
    const float acc1[8][4], const float* __restrict__ S1,
    const float* __restrict__ P, float acc2[16][4])
{
    __syncthreads();
    int c0 = (lane >> 3) * 8;
    int k0 = (lane & 7) * 4;
    int g = c0 >> 3;
    float S = S1[(b * 8 + g) * 2], Q = S1[(b * 8 + g) * 2 + 1];
    float mean = S * (1.0f / 262144.0f);
    float var = Q * (1.0f / 262144.0f) - mean * mean;
    float inv = rsqrtf(var + 1e-5f);
#pragma unroll
    for (int i = 0; i < 8; i++) {
        int c = c0 + i;
        float sc = P[P_G1 + c] * inv;
        float sh = P[P_BE1 + c] - mean * sc;
        float bb = P[P_B1 + c];
#pragma unroll
        for (int kk = 0; kk < 4; kk++)
            ACTm(mi, c, k0 + kk) = swishf(fmaf(acc1[i][kk] + bb, sc, sh));
    }
    for (int t = tid; t < 128 * 64; t += 256) {
        int c = t >> 6, j = t & 63;
        W2Tm(j, c) = P[P_W2 + t];
    }
    __syncthreads();
    int c02 = (lane >> 3) * 16;
#pragma unroll
    for (int i = 0; i < 16; i++)
#pragma unroll
        for (int kk = 0; kk < 4; kk++) acc2[i][kk] = 0.f;
#pragma unroll 4
    for (int j = 0; j < 64; j++) {
        float4 a = *(const float4*)&ACTm(mi, j, k0);
        float4 w0 = *(const float4*)&W2Tm(j, c02);
        float4 w1v = *(const float4*)&W2Tm(j, c02 + 4);
        float4 w2v = *(const float4*)&W2Tm(j, c02 + 8);
        float4 w3 = *(const float4*)&W2Tm(j, c02 + 12);
        float w[16] = {w0.x, w0.y, w0.z, w0.w, w1v.x, w1v.y, w1v.z, w1v.w,
                       w2v.x, w2v.y, w2v.z, w2v.w, w3.x, w3.y, w3.z, w3.w};
#pragma unroll
        for (int i = 0; i < 16; i++) {
            acc2[i][0] = fmaf(w[i], a.x, acc2[i][0]);
            acc2[i][1] = fmaf(w[i], a.y, acc2[i][1]);
            acc2[i][2] = fmaf(w[i], a.z, acc2[i][2]);
            acc2[i][3] = fmaf(w[i], a.w, acc2[i][3]);
        }
    }
}

// ---------------- MLP1(recompute)+MLP2 + GN2 stats via atomics
__global__ __launch_bounds__(256) void k_mlp2s(
    const float* __restrict__ featT, const float* __restrict__ coordsC,
    const float* __restrict__ centersF, const int* __restrict__ nidx,
    const float* __restrict__ P, const float* __restrict__ stats1,
    float* __restrict__ stats2)
{
    __shared__ __align__(16) char smem[65536];
    char* SM = smem;
    int tid = threadIdx.x, blk = blockIdx.x;
    int b = blk >> 8, m0 = (blk & 255) * 4;
    int mi = tid >> 6, lane = tid & 63;
    int bm = b * MM + m0 + mi;
    float acc1[8][4];
    mlp1_compute(SM, tid, lane, mi, b, bm, featT, coordsC, centersF, nidx, P, acc1);
    float acc2[16][4];
    mlp2_compute(SM, tid, lane, mi, b, acc1, stats1, P, acc2);
    int c02 = (lane >> 3) * 16;
    float s = 0.f, s2 = 0.f;
#pragma unroll
    for (int i = 0; i < 16; i++) {
        float bb = P[P_B2 + c02 + i];
#pragma unroll
        for (int kk = 0; kk < 4; kk++) {
            float v = acc2[i][kk] + bb;
            s += v; s2 = fmaf(v, v, s2);
        }
    }
    s += __shfl_xor(s, 1, 64); s += __shfl_xor(s, 2, 64); s += __shfl_xor(s, 4, 64);
    s2 += __shfl_xor(s2, 1, 64); s2 += __shfl_xor(s2, 2, 64); s2 += __shfl_xor(s2, 4, 64);
    __syncthreads();
    float* sred = (float*)SM;
    if ((lane & 7) == 0) {
        int g = lane >> 3;
        sred[(mi * 8 + g) * 2] = s;
        sred[(mi * 8 + g) * 2 + 1] = s2;
    }
    __syncthreads();
    if (tid < 16) {
        int g = tid >> 1, w = tid & 1;
        float t = sred[(0 * 8 + g) * 2 + w] + sred[(1 * 8 + g) * 2 + w]
                + sred[(2 * 8 + g) * 2 + w] + sred[(3 * 8 + g) * 2 + w];
        atomicAdd(&stats2[(b * 8 + g) * 2 + w], t);
    }
}

// ---------------- final: recompute, swish(GN2 inline), max over K -> out0
__global__ __launch_bounds__(256) void k_final(
    const float* __restrict__ featT, const float* __restrict__ coordsC,
    const float* __restrict__ centersF, const int* __restrict__ nidx,
    const float* __restrict__ P, const float* __restrict__ stats1,
    const float* __restrict__ stats2,
    void* __restrict__ d_out, const void* __restrict__ feat)
{
    __shared__ __align__(16) char smem[65536];
    char* SM = smem;
    int tid = threadIdx.x, blk = blockIdx.x;
    if (tid < 64) {
        int fl0 = detect_flag_wave((const unsigned short*)feat, tid);
        if (tid == 0) *(int*)(SM + 53248) = fl0;
    }
    __syncthreads();
    int fl = *(int*)(SM + 53248);
    int b = blk >> 8, m0 = (blk & 255) * 4;
    int mi = tid >> 6, lane = tid & 63;
    int bm = b * MM + m0 + mi;
    float acc1[8][4];
    mlp1_compute(SM, tid, lane, mi, b, bm, featT, coordsC, centersF, nidx, P, acc1);
    float acc2[16][4];
    mlp2_compute(SM, tid, lane, mi, b, acc1, stats1, P, acc2);
    int c02 = (lane >> 3) * 16;
    int g2 = c02 >> 4;
    float S = stats2[(b * 8 + g2) * 2], Q = stats2[(b * 8 + g2) * 2 + 1];
    float mean = S * (1.0f / 524288.0f);
    float var = Q * (1.0f / 524288.0f) - mean * mean;
    float inv = rsqrtf(var + 1e-5f);
    float mx[16];
#pragma unroll
    for (int i = 0; i < 16; i++) {
        int c = c02 + i;
        float sc = P[P_G2 + c] * inv;
        float sh = P[P_BE2 + c] - mean * sc;
        float bb = P[P_B2 + c];
        float v = -3.0e38f;
#pragma unroll
        for (int kk = 0; kk < 4; kk++)
            v = fmaxf(v, swishf(fmaf(acc2[i][kk] + bb, sc, sh)));
        v = fmaxf(v, __shfl_xor(v, 1, 64));
        v = fmaxf(v, __shfl_xor(v, 2, 64));
        v = fmaxf(v, __shfl_xor(v, 4, 64));
        mx[i] = v;
    }
    if ((lane & 7) == 0) {
        int m = m0 + mi;
#pragma unroll
        for (int i = 0; i < 16; i++) {
            size_t off = (size_t)(b * 128 + c02 + i) * MM + m;
            if (fl) ((float*)d_out)[off] = mx[i];
            else    ((unsigned short*)d_out)[off] = f2bf(mx[i]);
        }
    }
}

extern "C" void kernel_launch(void* const* d_in, const int* in_sizes, int n_in,
                              void* d_out, int out_size, void* d_ws, size_t ws_size,
                              hipStream_t stream) {
    (void)in_sizes; (void)n_in; (void)out_size; (void)ws_size;
    const void* feat = d_in[0];
    const void* coords = d_in[1];
    const void* temb = d_in[2];

    // workspace: ~10.0 MB
    char* ws = (char*)d_ws;
    int* qhead = (int*)ws;                                 // @0
    int* progress = (int*)(ws + 512);                      // 8 x 64B-strided ints
    float* stats1 = (float*)(ws + 1024);                   // 256 f32 (GN1)
    float* stats2 = (float*)(ws + 2048);                   // 256 f32 (GN2)
    float* coordsC = (float*)(ws + 3072);                  // 393,216
    float* paramsC = (float*)(ws + 396288);                // 52,224
    float* centersF = (float*)(ws + 448512);               // 131,072
    int* nidx = (int*)(ws + 579584);                       // 1,048,576
    float* featT = (float*)(ws + 1628160);                 // 8,388,608 -> 10,016,768

    k_cvt_all<<<947, 256, 0, stream>>>(feat, coords, featT, coordsC, paramsC,
                                       qhead, progress, stats1,
                                       d_in[3], d_in[4], d_in[5], d_in[6],
                                       d_in[7], d_in[8], d_in[9], d_in[10]);
    k_fpsknn<<<256, 256, 0, stream>>>(coords, coordsC, centersF, nidx, temb,
                                      feat, featT, paramsC, stats1, d_out,
                                      qhead, progress);
    k_mlp2s<<<2048, 256, 0, stream>>>(featT, coordsC, centersF, nidx, paramsC,
                                      stats1, stats2);
    k_final<<<2048, 256, 0, stream>>>(featT, coordsC, centersF, nidx, paramsC,
                                      stats1, stats2, d_out, feat);
}

// Round 13
// 1501.130 us; speedup vs baseline: 1.4994x; 1.0261x over previous
//
#include <hip/hip_runtime.h>
#include <stdint.h>

#define BB 8
#define NN 4096
#define MM 1024
#define KK 32

__device__ __forceinline__ float bf2f(unsigned short u) {
    union { unsigned int i; float f; } v; v.i = ((unsigned int)u) << 16; return v.f;
}
__device__ __forceinline__ unsigned short f2bf(float f) {
    union { float f; unsigned int i; } v; v.f = f;
    unsigned int x = v.i;
    x += 0x7fffu + ((x >> 16) & 1u);
    return (unsigned short)(x >> 16);
}
__device__ __forceinline__ float swishf(float y) {
    return __fdividef(y, 1.0f + __expf(-y));
}

// out element offsets (dtype-independent)
#define OUT1_OFF 1048576
#define OUT2_OFF 1073152

// params canonical f32 layout (floats)
#define P_W1 0
#define P_B1 4288
#define P_G1 4352
#define P_BE1 4416
#define P_W2 4480
#define P_B2 12672
#define P_G2 12800
#define P_BE2 12928

__device__ __forceinline__ int detect_flag_wave(const unsigned short* f, int lane) {
    unsigned short u = f[lane * 2];
    float x = fabsf(bf2f(u));
    bool ext = (u != 0) && (x > 100.0f || x < 1e-30f);
    unsigned long long m = __ballot(ext);
    return (__popcll(m) >= 16) ? 1 : 0;
}

// ---- DPP-accelerated 64-lane lex-max (d desc, idx asc) reduction ----
// Stages 1,2,4,8 as VALU DPP (xor-involutions within 16-lane rows:
// quad_perm[1,0,3,2]=0xB1 (xor1), quad_perm[2,3,0,1]=0x4E (xor2),
// row_half_mirror=0x141 (xor7), row_mirror=0x140 (xor15) -- lex-max is
// assoc/comm/idempotent so coverage reaches all 16 row lanes), then
// stages 16/32 via __shfl_xor (LDS). Replaces 6 serial ds_swizzle f64
// stages (~1400 cyc) with 4 VALU + 2 LDS (~500 cyc).
#define DPP_STAGE(CTRL) { \
    union { double d; unsigned int u[2]; } s_, r_; \
    s_.d = bd; \
    r_.u[0] = (unsigned)__builtin_amdgcn_update_dpp(0, (int)s_.u[0], CTRL, 0xF, 0xF, true); \
    r_.u[1] = (unsigned)__builtin_amdgcn_update_dpp(0, (int)s_.u[1], CTRL, 0xF, 0xF, true); \
    int op_ = __builtin_amdgcn_update_dpp(0, bp, CTRL, 0xF, 0xF, true); \
    double od_ = r_.d; \
    bool rep_ = (od_ > bd) || (od_ == bd && op_ < bp); \
    bd = rep_ ? od_ : bd; bp = rep_ ? op_ : bp; }

__device__ __forceinline__ void redmax64(double& bd, int& bp) {
    DPP_STAGE(0xB1)
    DPP_STAGE(0x4E)
    DPP_STAGE(0x141)
    DPP_STAGE(0x140)
#pragma unroll
    for (int m = 32; m >= 16; m >>= 1) {
        double od = __shfl_xor(bd, m, 64);
        int op = __shfl_xor(bp, m, 64);
        bool rep = (od > bd) || (od == bd && op < bp);
        bd = rep ? od : bd; bp = rep ? op : bp;
    }
}

// ================= launch 1: conversions + sync/stat init =================
__global__ __launch_bounds__(256) void k_cvt_all(
    const void* __restrict__ feat, const void* __restrict__ coords,
    float* __restrict__ featT, float* __restrict__ coordsC,
    float* __restrict__ paramsC,
    int* __restrict__ qhead, int* __restrict__ progress,
    float* __restrict__ stats1,
    const void* W1, const void* b1, const void* g1, const void* be1,
    const void* W2, const void* b2, const void* g2, const void* be2)
{
    __shared__ float tile[64][65];
    __shared__ int sflag;
    int tid = threadIdx.x, blk = blockIdx.x;
    if (tid < 64) {
        int fl0 = detect_flag_wave((const unsigned short*)feat, tid);
        if (tid == 0) sflag = fl0;
    }
    __syncthreads();
    int fl = sflag;
    if (blk == 0) {
        if (tid == 0) *qhead = 0;
        if (tid < 8) progress[tid * 16] = -1;
        stats1[tid] = 0.f;
        stats1[tid + 256] = 0.f;
    }
    if (blk < 512) {
        int i = blk;
        int b = i >> 6, n0 = (i & 63) * 64;
        int c = tid >> 2, q = tid & 3;
        size_t base = ((size_t)b * 64 + c) * NN + n0 + q * 16;
        if (fl) {
            const float* sp = (const float*)feat + base;
#pragma unroll
            for (int j = 0; j < 16; j++) tile[c][q * 16 + j] = sp[j];
        } else {
            const unsigned short* sp = (const unsigned short*)feat + base;
#pragma unroll
            for (int j = 0; j < 16; j++) tile[c][q * 16 + j] = bf2f(sp[j]);
        }
        __syncthreads();
        int n = tid >> 2;
        float* dp = featT + ((size_t)b * NN + n0 + n) * 64 + q * 16;
#pragma unroll
        for (int j = 0; j < 16; j++) dp[j] = tile[q * 16 + j][n];
    } else if (blk < 896) {
        int idx = (blk - 512) * 256 + tid;
        coordsC[idx] = fl ? ((const float*)coords)[idx]
                          : bf2f(((const unsigned short*)coords)[idx]);
    } else {
        int idx = (blk - 896) * 256 + tid;
        if (idx < 13056) {
            const void* src; int off;
            if (idx < 4288)       { src = W1;  off = idx; }
            else if (idx < 4352)  { src = b1;  off = idx - 4288; }
            else if (idx < 4416)  { src = g1;  off = idx - 4352; }
            else if (idx < 4480)  { src = be1; off = idx - 4416; }
            else if (idx < 12672) { src = W2;  off = idx - 4480; }
            else if (idx < 12800) { src = b2;  off = idx - 12672; }
            else if (idx < 12928) { src = g2;  off = idx - 12800; }
            else                  { src = be2; off = idx - 12928; }
            paramsC[idx] = fl ? ((const float*)src)[off]
                              : bf2f(((const unsigned short*)src)[off]);
        }
    }
}

// ====== shared LDS macros ======
#define W1Tm(j,c)     (((float*)SM)[(j)*64+(c)])
#define GBUFm(mi,k,c) (((float*)(SM+17152))[(((mi)*32+(k))*66)+(c)])
#define GCm(mi,j,k)   (((float*)(SM+50944))[(((mi)*3+(j))*32)+(k)])
#define NDm(mi,k)     (((int*)(SM+52480))[((mi)*32)+(k)])
#define W2Tm(j,c)     (((float*)SM)[(j)*128+(c)])
#define ACTm(mi,j,k)  (((float*)(SM+32768))[(((mi)*64+(j))*32)+(k)])

// ================= launch 2: FPS (blocks 0..7) + persistent workers =======
struct PW { double d; int p; int q; };
#define PSM_XS   ((float*)(SM))
#define PSM_YS   ((float*)(SM + 16384))
#define PSM_ZS   ((float*)(SM + 32768))
#define PSM_HIST ((int*)(SM + 49152))
#define PSM_PWB  ((PW*)(SM + 53248))
#define PSM_SF   ((int*)(SM + 53376))

#define RESCAN(G) { \
    double gd = 1.0e300; int ga = (G) * 8; \
    _Pragma("unroll") \
    for (int i = 0; i < 8; i++) { \
        int sl = (G) * 8 + i; \
        unsigned int bit = (sl < 32) ? (elo >> sl) : (ehi >> (sl - 32)); \
        double cd = (bit & 1u) ? 1.0e300 : d[sl]; \
        bool rep = cd < gd; \
        gd = rep ? cd : gd; ga = rep ? sl : ga; \
    } \
    g8[(G)] = gd; a8[(G)] = ga; }

__global__ __launch_bounds__(256) void k_fpsknn(
    const void* __restrict__ coords, const float* __restrict__ coordsC,
    float* __restrict__ centersF, int* __restrict__ nidx,
    const void* __restrict__ temb, const void* __restrict__ feat,
    const float* __restrict__ featT, const float* __restrict__ paramsC,
    float* __restrict__ stats1,
    void* __restrict__ d_out,
    int* __restrict__ qhead, int* __restrict__ progress)
{
    __shared__ __align__(16) char SM[55296];
    int tid = threadIdx.x;
    int blk = blockIdx.x;
    if (tid < 64) {
        int fl0 = detect_flag_wave((const unsigned short*)feat, tid);
        if (tid == 0) *PSM_SF = fl0;
    }
    __syncthreads();
    int fl = *PSM_SF;

    if (blk < 8) {
        // ---------- FPS in f64, 256 thr, DPP butterfly ----------
        int b = blk;
        if (fl) {
            const float* cb = (const float*)coords + (size_t)b * 3 * NN;
#pragma unroll
            for (int i = 0; i < 16; i++) {
                int p = tid + i * 256;
                PSM_XS[p] = cb[p]; PSM_YS[p] = cb[NN + p]; PSM_ZS[p] = cb[2 * NN + p];
            }
        } else {
            const unsigned short* cb = (const unsigned short*)coords + (size_t)b * 3 * NN;
#pragma unroll
            for (int i = 0; i < 16; i++) {
                int p = tid + i * 256;
                PSM_XS[p] = bf2f(cb[p]); PSM_YS[p] = bf2f(cb[NN + p]); PSM_ZS[p] = bf2f(cb[2 * NN + p]);
            }
        }
        if (tid == 0) PSM_HIST[0] = 0;
        __syncthreads();
        if (tid == 0) {
            *(float4*)(centersF + (size_t)b * MM * 4) =
                make_float4(PSM_XS[0], PSM_YS[0], PSM_ZS[0], 0.f);
            __hip_atomic_store(&progress[b * 16], 0, __ATOMIC_RELEASE, __HIP_MEMORY_SCOPE_AGENT);
        }
        int base = tid * 16;
        double px[16], py[16], pz[16], dist[16];
        double x0 = (double)PSM_XS[0], y0 = (double)PSM_YS[0], z0 = (double)PSM_ZS[0];
        double bd = -1.0; int bp = base;
#pragma unroll
        for (int j = 0; j < 16; j++) {
            px[j] = (double)PSM_XS[base + j]; py[j] = (double)PSM_YS[base + j]; pz[j] = (double)PSM_ZS[base + j];
            double dx = px[j] - x0, dy = py[j] - y0, dz = pz[j] - z0;
            dist[j] = fma(dz, dz, fma(dy, dy, dx * dx));
            bool rep = dist[j] > bd;
            bd = rep ? dist[j] : bd; bp = rep ? base + j : bp;
        }
        int lane = tid & 63, wid = tid >> 6;
#pragma unroll 1
        for (int s = 1; s < MM; s++) {
            redmax64(bd, bp);
            int par = s & 1;
            if (lane == 0) { PW w; w.d = bd; w.p = bp; w.q = 0; PSM_PWB[par * 4 + wid] = w; }
            __syncthreads();
            PW w0 = PSM_PWB[par * 4 + 0];
            double wd = w0.d; int wp = w0.p;
#pragma unroll
            for (int w = 1; w < 4; w++) {
                PW ww = PSM_PWB[par * 4 + w];
                bool rep = (ww.d > wd) || (ww.d == wd && ww.p < wp);
                wd = rep ? ww.d : wd; wp = rep ? ww.p : wp;
            }
            if (tid == 0) PSM_HIST[s] = wp;
            if ((s & 31) == 31 && s >= 63 && wid == ((s >> 5) & 3)) {
                int s0 = s - 63;
                if (lane < 32) {
                    int far = PSM_HIST[s0 + lane];
                    *(float4*)(centersF + ((size_t)b * MM + s0 + lane) * 4) =
                        make_float4(PSM_XS[far], PSM_YS[far], PSM_ZS[far], 0.f);
                }
                if (lane == 0)
                    __hip_atomic_store(&progress[b * 16], s0 + 31,
                                       __ATOMIC_RELEASE, __HIP_MEMORY_SCOPE_AGENT);
            }
            double fx = (double)PSM_XS[wp], fy = (double)PSM_YS[wp], fz = (double)PSM_ZS[wp];
            bd = -1.0; bp = base;
#pragma unroll
            for (int j = 0; j < 16; j++) {
                double dx = px[j] - fx, dy = py[j] - fy, dz = pz[j] - fz;
                double d = fma(dz, dz, fma(dy, dy, dx * dx));
                dist[j] = fmin(dist[j], d);
                bool rep = dist[j] > bd;
                bd = rep ? dist[j] : bd; bp = rep ? base + j : bp;
            }
        }
        __syncthreads();
        if (tid < 32) {
            int far = PSM_HIST[992 + tid];
            *(float4*)(centersF + ((size_t)b * MM + 992 + tid) * 4) =
                make_float4(PSM_XS[far], PSM_YS[far], PSM_ZS[far], 0.f);
        }
        if (tid == 0)
            __hip_atomic_store(&progress[b * 16], 1023,
                               __ATOMIC_RELEASE, __HIP_MEMORY_SCOPE_AGENT);
#pragma unroll
        for (int i = 0; i < 4; i++) {
            int m = tid + i * 256;
            int far = PSM_HIST[m];
            float X = PSM_XS[far], Y = PSM_YS[far], Z = PSM_ZS[far];
            if (fl) {
                float* o = (float*)d_out;
                o[OUT1_OFF + (size_t)(b * 3 + 0) * MM + m] = X;
                o[OUT1_OFF + (size_t)(b * 3 + 1) * MM + m] = Y;
                o[OUT1_OFF + (size_t)(b * 3 + 2) * MM + m] = Z;
            } else {
                unsigned short* o = (unsigned short*)d_out;
                o[OUT1_OFF + (size_t)(b * 3 + 0) * MM + m] = f2bf(X);
                o[OUT1_OFF + (size_t)(b * 3 + 1) * MM + m] = f2bf(Y);
                o[OUT1_OFF + (size_t)(b * 3 + 2) * MM + m] = f2bf(Z);
            }
        }
    } else {
        // ---------- persistent workers: kNN + gtemb + MLP1/GN1 stats ----------
        int lane = tid & 63, wid = tid >> 6;
        for (int t = tid; t < 64 * 67; t += 256) {
            int c = t / 67, j = t % 67;
            W1Tm(j, c) = paramsC[P_W1 + t];
        }
        __syncthreads();
        for (;;) {
            int id = 0;
            if (lane == 0) id = atomicAdd(qhead, 1);
            id = __shfl(id, 0, 64);
            if (id >= BB * MM) break;
            int b = id & 7, m = id >> 3;
            while (__hip_atomic_load(&progress[b * 16], __ATOMIC_RELAXED,
                                     __HIP_MEMORY_SCOPE_AGENT) < m)
                __builtin_amdgcn_s_sleep(64);
            (void)__hip_atomic_load(&progress[b * 16], __ATOMIC_ACQUIRE,
                                    __HIP_MEMORY_SCOPE_AGENT);
            int bm = b * MM + m;
            const float* cb = coordsC + (size_t)b * 3 * NN;
            float4 ctr = *(const float4*)(centersF + (size_t)bm * 4);
            double cx = (double)ctr.x, cy = (double)ctr.y, cz = (double)ctr.z;
            double cc = (cx * cx + cy * cy) + cz * cz;
            double d[64];
#pragma unroll 4
            for (int j = 0; j < 64; j++) {
                int p = j * 64 + lane;
                double x = (double)cb[p], y = (double)cb[NN + p], z = (double)cb[2 * NN + p];
                double pp = (x * x + y * y) + z * z;
                double dt = (cx * x + cy * y) + cz * z;
                d[j] = (cc + pp) - 2.0 * dt;
            }
            double g8[8]; int a8[8];
#pragma unroll
            for (int g = 0; g < 8; g++) {
                double gd = d[g * 8]; int ga = g * 8;
#pragma unroll
                for (int i = 1; i < 8; i++) {
                    int sl = g * 8 + i;
                    bool rep = d[sl] < gd;
                    gd = rep ? d[sl] : gd; ga = rep ? sl : ga;
                }
                g8[g] = gd; a8[g] = ga;
            }
            unsigned int elo = 0, ehi = 0;
            int res = 0;
#pragma unroll 1
            for (int it = 0; it < 32; it++) {
                double bd = g8[0]; int ba = a8[0];
#pragma unroll
                for (int g = 1; g < 8; g++) {
                    bool rep = g8[g] < bd;
                    bd = rep ? g8[g] : bd; ba = rep ? a8[g] : ba;
                }
                int bp = ba * 64 + lane;
                double wd = bd; int wp = bp;
#pragma unroll
                for (int s = 32; s >= 1; s >>= 1) {
                    double od = __shfl_xor(wd, s, 64);
                    int op = __shfl_xor(wp, s, 64);
                    bool rep = (od < wd) || (od == wd && op < wp);
                    wd = rep ? od : wd; wp = rep ? op : wp;
                }
                res = (lane == it) ? wp : res;
                if (bp == wp) {
                    int slot = ba;
                    if (slot < 32) elo |= (1u << slot); else ehi |= (1u << (slot - 32));
                    int g = slot >> 3;
                    switch (g) {
                        case 0: RESCAN(0) break;
                        case 1: RESCAN(1) break;
                        case 2: RESCAN(2) break;
                        case 3: RESCAN(3) break;
                        case 4: RESCAN(4) break;
                        case 5: RESCAN(5) break;
                        case 6: RESCAN(6) break;
                        case 7: RESCAN(7) break;
                    }
                }
            }
            if (lane < KK) nidx[(size_t)bm * KK + lane] = res;
            float best = -3.0e38f;
            if (fl) {
                const float* tb = (const float*)temb + ((size_t)b * 64 + lane) * NN;
#pragma unroll 4
                for (int k = 0; k < 32; k++) {
                    int nk = __shfl(res, k, 64);
                    best = fmaxf(best, tb[nk]);
                }
            } else {
                const unsigned short* tb = (const unsigned short*)temb + ((size_t)b * 64 + lane) * NN;
#pragma unroll 4
                for (int k = 0; k < 32; k++) {
                    int nk = __shfl(res, k, 64);
                    best = fmaxf(best, bf2f(tb[nk]));
                }
            }
            size_t off = (size_t)OUT2_OFF + ((size_t)(b * 64 + lane)) * MM + m;
            if (fl) ((float*)d_out)[off] = best;
            else    ((unsigned short*)d_out)[off] = f2bf(best);
            // ---- MLP1 for this center ----
            if (lane < 32) NDm(wid, lane) = res & (NN - 1);
            const float* fb = featT + (size_t)b * NN * 64;
#pragma unroll 4
            for (int q = 0; q < 32; q++) {
                int n = NDm(wid, q);
                GBUFm(wid, q, lane) = fb[(size_t)n * 64 + lane];
            }
            if (lane < 32) {
                int n = NDm(wid, lane);
                GCm(wid, 0, lane) = __fsub_rn(cb[n], ctr.x);
                GCm(wid, 1, lane) = __fsub_rn(cb[NN + n], ctr.y);
                GCm(wid, 2, lane) = __fsub_rn(cb[2 * NN + n], ctr.z);
            }
            int c0 = (lane >> 3) * 8;
            int k0 = (lane & 7) * 4;
            float acc[8][4];
#pragma unroll
            for (int i = 0; i < 8; i++)
#pragma unroll
                for (int kk = 0; kk < 4; kk++) acc[i][kk] = 0.f;
#pragma unroll
            for (int j = 0; j < 3; j++) {
                float4 a = *(const float4*)&GCm(wid, j, k0);
                float4 w0 = *(const float4*)&W1Tm(j, c0);
                float4 w1v = *(const float4*)&W1Tm(j, c0 + 4);
                float w[8] = {w0.x, w0.y, w0.z, w0.w, w1v.x, w1v.y, w1v.z, w1v.w};
#pragma unroll
                for (int i = 0; i < 8; i++) {
                    acc[i][0] = fmaf(w[i], a.x, acc[i][0]);
                    acc[i][1] = fmaf(w[i], a.y, acc[i][1]);
                    acc[i][2] = fmaf(w[i], a.z, acc[i][2]);
                    acc[i][3] = fmaf(w[i], a.w, acc[i][3]);
                }
            }
#pragma unroll 4
            for (int c = 0; c < 64; c++) {
                float f0 = GBUFm(wid, k0 + 0, c);
                float f1 = GBUFm(wid, k0 + 1, c);
                float f2 = GBUFm(wid, k0 + 2, c);
                float f3 = GBUFm(wid, k0 + 3, c);
                int j = 3 + c;
                float4 w0 = *(const float4*)&W1Tm(j, c0);
                float4 w1v = *(const float4*)&W1Tm(j, c0 + 4);
                float w[8] = {w0.x, w0.y, w0.z, w0.w, w1v.x, w1v.y, w1v.z, w1v.w};
#pragma unroll
                for (int i = 0; i < 8; i++) {
                    acc[i][0] = fmaf(w[i], f0, acc[i][0]);
                    acc[i][1] = fmaf(w[i], f1, acc[i][1]);
                    acc[i][2] = fmaf(w[i], f2, acc[i][2]);
                    acc[i][3] = fmaf(w[i], f3, acc[i][3]);
                }
            }
            float s = 0.f, s2 = 0.f;
#pragma unroll
            for (int i = 0; i < 8; i++) {
                float bb = paramsC[P_B1 + c0 + i];
#pragma unroll
                for (int kk = 0; kk < 4; kk++) {
                    float v = acc[i][kk] + bb;
                    s += v; s2 = fmaf(v, v, s2);
                }
            }
            s += __shfl_xor(s, 1, 64); s += __shfl_xor(s, 2, 64); s += __shfl_xor(s, 4, 64);
            s2 += __shfl_xor(s2, 1, 64); s2 += __shfl_xor(s2, 2, 64); s2 += __shfl_xor(s2, 4, 64);
            if ((lane & 7) == 0) {
                int g = lane >> 3;
                atomicAdd(&stats1[(b * 8 + g) * 2], s);
                atomicAdd(&stats1[(b * 8 + g) * 2 + 1], s2);
            }
        }
    }
}

// ================= fused MLP machinery (featT f32 gathers) =================
__device__ __forceinline__ void mlp1_compute(
    char* SM, int tid, int lane, int mi, int b, int bm,
    const float* __restrict__ featT, const float* __restrict__ coordsC,
    const float* __restrict__ centersF, const int* __restrict__ nidx,
    const float* __restrict__ P, float acc[8][4])
{
    for (int t = tid; t < 64 * 67; t += 256) {
        int c = t / 67, j = t % 67;
        W1Tm(j, c) = P[P_W1 + t];
    }
    if (lane < 32) NDm(mi, lane) = nidx[(size_t)bm * KK + lane] & (NN - 1);
    __syncthreads();
    const float* fb = featT + (size_t)b * NN * 64;
#pragma unroll 4
    for (int q = 0; q < 32; q++) {
        int n = NDm(mi, q);
        GBUFm(mi, q, lane) = fb[(size_t)n * 64 + lane];
    }
    float4 ctr = *(const float4*)(centersF + (size_t)bm * 4);
    const float* cb = coordsC + (size_t)b * 3 * NN;
    if (lane < 32) {
        int n = NDm(mi, lane);
        GCm(mi, 0, lane) = __fsub_rn(cb[n], ctr.x);
        GCm(mi, 1, lane) = __fsub_rn(cb[NN + n], ctr.y);
        GCm(mi, 2, lane) = __fsub_rn(cb[2 * NN + n], ctr.z);
    }
    __syncthreads();
    int c0 = (lane >> 3) * 8;
    int k0 = (lane & 7) * 4;
#pragma unroll
    for (int i = 0; i < 8; i++)
#pragma unroll
        for (int kk = 0; kk < 4; kk++) acc[i][kk] = 0.f;
#pragma unroll
    for (int j = 0; j < 3; j++) {
        float4 a = *(const float4*)&GCm(mi, j, k0);
        float4 w0 = *(const float4*)&W1Tm(j, c0);
        float4 w1v = *(const float4*)&W1Tm(j, c0 + 4);
        float w[8] = {w0.x, w0.y, w0.z, w0.w, w1v.x, w1v.y, w1v.z, w1v.w};
#pragma unroll
        for (int i = 0; i < 8; i++) {
            acc[i][0] = fmaf(w[i], a.x, acc[i][0]);
            acc[i][1] = fmaf(w[i], a.y, acc[i][1]);
            acc[i][2] = fmaf(w[i], a.z, acc[i][2]);
            acc[i][3] = fmaf(w[i], a.w, acc[i][3]);
        }
    }
#pragma unroll 4
    for (int c = 0; c < 64; c++) {
        float f0 = GBUFm(mi, k0 + 0, c);
        float f1 = GBUFm(mi, k0 + 1, c);
        float f2 = GBUFm(mi, k0 + 2, c);
        float f3 = GBUFm(mi, k0 + 3, c);
        int j = 3 + c;
        float4 w0 = *(const float4*)&W1Tm(j, c0);
        float4 w1v = *(const float4*)&W1Tm(j, c0 + 4);
        float w[8] = {w0.x, w0.y, w0.z, w0.w, w1v.x, w1v.y, w1v.z, w1v.w};
#pragma unroll
        for (int i = 0; i < 8; i++) {
            acc[i][0] = fmaf(w[i], f0, acc[i][0]);
            acc[i][1] = fmaf(w[i], f1, acc[i][1]);
            acc[i][2] = fmaf(w[i], f2, acc[i][2]);
            acc[i][3] = fmaf(w[i], f3, acc[i][3]);
        }
    }
}

__device__ __forceinline__ void mlp2_compute(
    char* SM, int tid, int lane, int mi, int b,
    const float acc1[8][4], const float* __restrict__ S1,
    const float* __restrict__ P, float acc2[16][4])
{
    __syncthreads();
    int c0 = (lane >> 3) * 8;
    int k0 = (lane & 7) * 4;
    int g = c0 >> 3;
    float S = S1[(b * 8 + g) * 2], Q = S1[(b * 8 + g) * 2 + 1];
    float mean = S * (1.0f / 262144.0f);
    float var = Q * (1.0f / 262144.0f) - mean * mean;
    float inv = rsqrtf(var + 1e-5f);
#pragma unroll
    for (int i = 0; i < 8; i++) {
        int c = c0 + i;
        float sc = P[P_G1 + c] * inv;
        float sh = P[P_BE1 + c] - mean * sc;
        float bb = P[P_B1 + c];
#pragma unroll
        for (int kk = 0; kk < 4; kk++)
            ACTm(mi, c, k0 + kk) = swishf(fmaf(acc1[i][kk] + bb, sc, sh));
    }
    for (int t = tid; t < 128 * 64; t += 256) {
        int c = t >> 6, j = t & 63;
        W2Tm(j, c) = P[P_W2 + t];
    }
    __syncthreads();
    int c02 = (lane >> 3) * 16;
#pragma unroll
    for (int i = 0; i < 16; i++)
#pragma unroll
        for (int kk = 0; kk < 4; kk++) acc2[i][kk] = 0.f;
#pragma unroll 4
    for (int j = 0; j < 64; j++) {
        float4 a = *(const float4*)&ACTm(mi, j, k0);
        float4 w0 = *(const float4*)&W2Tm(j, c02);
        float4 w1v = *(const float4*)&W2Tm(j, c02 + 4);
        float4 w2v = *(const float4*)&W2Tm(j, c02 + 8);
        float4 w3 = *(const float4*)&W2Tm(j, c02 + 12);
        float w[16] = {w0.x, w0.y, w0.z, w0.w, w1v.x, w1v.y, w1v.z, w1v.w,
                       w2v.x, w2v.y, w2v.z, w2v.w, w3.x, w3.y, w3.z, w3.w};
#pragma unroll
        for (int i = 0; i < 16; i++) {
            acc2[i][0] = fmaf(w[i], a.x, acc2[i][0]);
            acc2[i][1] = fmaf(w[i], a.y, acc2[i][1]);
            acc2[i][2] = fmaf(w[i], a.z, acc2[i][2]);
            acc2[i][3] = fmaf(w[i], a.w, acc2[i][3]);
        }
    }
}

// ---------------- MLP1(recompute)+MLP2 + GN2 stats via atomics
__global__ __launch_bounds__(256) void k_mlp2s(
    const float* __restrict__ featT, const float* __restrict__ coordsC,
    const float* __restrict__ centersF, const int* __restrict__ nidx,
    const float* __restrict__ P, const float* __restrict__ stats1,
    float* __restrict__ stats2)
{
    __shared__ __align__(16) char smem[65536];
    char* SM = smem;
    int tid = threadIdx.x, blk = blockIdx.x;
    int b = blk >> 8, m0 = (blk & 255) * 4;
    int mi = tid >> 6, lane = tid & 63;
    int bm = b * MM + m0 + mi;
    float acc1[8][4];
    mlp1_compute(SM, tid, lane, mi, b, bm, featT, coordsC, centersF, nidx, P, acc1);
    float acc2[16][4];
    mlp2_compute(SM, tid, lane, mi, b, acc1, stats1, P, acc2);
    int c02 = (lane >> 3) * 16;
    float s = 0.f, s2 = 0.f;
#pragma unroll
    for (int i = 0; i < 16; i++) {
        float bb = P[P_B2 + c02 + i];
#pragma unroll
        for (int kk = 0; kk < 4; kk++) {
            float v = acc2[i][kk] + bb;
            s += v; s2 = fmaf(v, v, s2);
        }
    }
    s += __shfl_xor(s, 1, 64); s += __shfl_xor(s, 2, 64); s += __shfl_xor(s, 4, 64);
    s2 += __shfl_xor(s2, 1, 64); s2 += __shfl_xor(s2, 2, 64); s2 += __shfl_xor(s2, 4, 64);
    __syncthreads();
    float* sred = (float*)SM;
    if ((lane & 7) == 0) {
        int g = lane >> 3;
        sred[(mi * 8 + g) * 2] = s;
        sred[(mi * 8 + g) * 2 + 1] = s2;
    }
    __syncthreads();
    if (tid < 16) {
        int g = tid >> 1, w = tid & 1;
        float t = sred[(0 * 8 + g) * 2 + w] + sred[(1 * 8 + g) * 2 + w]
                + sred[(2 * 8 + g) * 2 + w] + sred[(3 * 8 + g) * 2 + w];
        atomicAdd(&stats2[(b * 8 + g) * 2 + w], t);
    }
}

// ---------------- final: recompute, swish(GN2 inline), max over K -> out0
__global__ __launch_bounds__(256) void k_final(
    const float* __restrict__ featT, const float* __restrict__ coordsC,
    const float* __restrict__ centersF, const int* __restrict__ nidx,
    const float* __restrict__ P, const float* __restrict__ stats1,
    const float* __restrict__ stats2,
    void* __restrict__ d_out, const void* __restrict__ feat)
{
    __shared__ __align__(16) char smem[65536];
    char* SM = smem;
    int tid = threadIdx.x, blk = blockIdx.x;
    if (tid < 64) {
        int fl0 = detect_flag_wave((const unsigned short*)feat, tid);
        if (tid == 0) *(int*)(SM + 53248) = fl0;
    }
    __syncthreads();
    int fl = *(int*)(SM + 53248);
    int b = blk >> 8, m0 = (blk & 255) * 4;
    int mi = tid >> 6, lane = tid & 63;
    int bm = b * MM + m0 + mi;
    float acc1[8][4];
    mlp1_compute(SM, tid, lane, mi, b, bm, featT, coordsC, centersF, nidx, P, acc1);
    float acc2[16][4];
    mlp2_compute(SM, tid, lane, mi, b, acc1, stats1, P, acc2);
    int c02 = (lane >> 3) * 16;
    int g2 = c02 >> 4;
    float S = stats2[(b * 8 + g2) * 2], Q = stats2[(b * 8 + g2) * 2 + 1];
    float mean = S * (1.0f / 524288.0f);
    float var = Q * (1.0f / 524288.0f) - mean * mean;
    float inv = rsqrtf(var + 1e-5f);
    float mx[16];
#pragma unroll
    for (int i = 0; i < 16; i++) {
        int c = c02 + i;
        float sc = P[P_G2 + c] * inv;
        float sh = P[P_BE2 + c] - mean * sc;
        float bb = P[P_B2 + c];
        float v = -3.0e38f;
#pragma unroll
        for (int kk = 0; kk < 4; kk++)
            v = fmaxf(v, swishf(fmaf(acc2[i][kk] + bb, sc, sh)));
        v = fmaxf(v, __shfl_xor(v, 1, 64));
        v = fmaxf(v, __shfl_xor(v, 2, 64));
        v = fmaxf(v, __shfl_xor(v, 4, 64));
        mx[i] = v;
    }
    if ((lane & 7) == 0) {
        int m = m0 + mi;
#pragma unroll
        for (int i = 0; i < 16; i++) {
            size_t off = (size_t)(b * 128 + c02 + i) * MM + m;
            if (fl) ((float*)d_out)[off] = mx[i];
            else    ((unsigned short*)d_out)[off] = f2bf(mx[i]);
        }
    }
}

extern "C" void kernel_launch(void* const* d_in, const int* in_sizes, int n_in,
                              void* d_out, int out_size, void* d_ws, size_t ws_size,
                              hipStream_t stream) {
    (void)in_sizes; (void)n_in; (void)out_size; (void)ws_size;
    const void* feat = d_in[0];
    const void* coords = d_in[1];
    const void* temb = d_in[2];

    // workspace: ~10.0 MB
    char* ws = (char*)d_ws;
    int* qhead = (int*)ws;                                 // @0
    int* progress = (int*)(ws + 512);                      // 8 x 64B-strided ints
    float* stats1 = (float*)(ws + 1024);                   // 256 f32 (GN1)
    float* stats2 = (float*)(ws + 2048);                   // 256 f32 (GN2)
    float* coordsC = (float*)(ws + 3072);                  // 393,216
    float* paramsC = (float*)(ws + 396288);                // 52,224
    float* centersF = (float*)(ws + 448512);               // 131,072
    int* nidx = (int*)(ws + 579584);                       // 1,048,576
    float* featT = (float*)(ws + 1628160);                 // 8,388,608 -> 10,016,768

    k_cvt_all<<<947, 256, 0, stream>>>(feat, coords, featT, coordsC, paramsC,
                                       qhead, progress, stats1,
                                       d_in[3], d_in[4], d_in[5], d_in[6],
                                       d_in[7], d_in[8], d_in[9], d_in[10]);
    k_fpsknn<<<256, 256, 0, stream>>>(coords, coordsC, centersF, nidx, temb,
                                      feat, featT, paramsC, stats1, d_out,
                                      qhead, progress);
    k_mlp2s<<<2048, 256, 0, stream>>>(featT, coordsC, centersF, nidx, paramsC,
                                      stats1, stats2);
    k_final<<<2048, 256, 0, stream>>>(featT, coordsC, centersF, nidx, paramsC,
                                      stats1, stats2, d_out, feat);
}

// Round 14
// 1346.656 us; speedup vs baseline: 1.6714x; 1.1147x over previous
//
#include <hip/hip_runtime.h>
#include <stdint.h>

#define BB 8
#define NN 4096
#define MM 1024
#define KK 32

__device__ __forceinline__ float bf2f(unsigned short u) {
    union { unsigned int i; float f; } v; v.i = ((unsigned int)u) << 16; return v.f;
}
__device__ __forceinline__ unsigned short f2bf(float f) {
    union { float f; unsigned int i; } v; v.f = f;
    unsigned int x = v.i;
    x += 0x7fffu + ((x >> 16) & 1u);
    return (unsigned short)(x >> 16);
}
__device__ __forceinline__ float swishf(float y) {
    return __fdividef(y, 1.0f + __expf(-y));
}

// out element offsets (dtype-independent)
#define OUT1_OFF 1048576
#define OUT2_OFF 1073152

// params canonical f32 layout (floats)
#define P_W1 0
#define P_B1 4288
#define P_G1 4352
#define P_BE1 4416
#define P_W2 4480
#define P_B2 12672
#define P_G2 12800
#define P_BE2 12928

__device__ __forceinline__ int detect_flag_wave(const unsigned short* f, int lane) {
    unsigned short u = f[lane * 2];
    float x = fabsf(bf2f(u));
    bool ext = (u != 0) && (x > 100.0f || x < 1e-30f);
    unsigned long long m = __ballot(ext);
    return (__popcll(m) >= 16) ? 1 : 0;
}

// ---- DPP-accelerated 64-lane lex-max (d desc, idx asc) reduction ----
#define DPP_STAGE(CTRL) { \
    union { double d; unsigned int u[2]; } s_, r_; \
    s_.d = bd; \
    r_.u[0] = (unsigned)__builtin_amdgcn_update_dpp(0, (int)s_.u[0], CTRL, 0xF, 0xF, true); \
    r_.u[1] = (unsigned)__builtin_amdgcn_update_dpp(0, (int)s_.u[1], CTRL, 0xF, 0xF, true); \
    int op_ = __builtin_amdgcn_update_dpp(0, bp, CTRL, 0xF, 0xF, true); \
    double od_ = r_.d; \
    bool rep_ = (od_ > bd) || (od_ == bd && op_ < bp); \
    bd = rep_ ? od_ : bd; bp = rep_ ? op_ : bp; }

__device__ __forceinline__ void redmax64(double& bd, int& bp) {
    DPP_STAGE(0xB1)
    DPP_STAGE(0x4E)
    DPP_STAGE(0x141)
    DPP_STAGE(0x140)
#pragma unroll
    for (int m = 32; m >= 16; m >>= 1) {
        double od = __shfl_xor(bd, m, 64);
        int op = __shfl_xor(bp, m, 64);
        bool rep = (od > bd) || (od == bd && op < bp);
        bd = rep ? od : bd; bp = rep ? op : bp;
    }
}

// ================= launch 1: conversions + sync/stat init =================
__global__ __launch_bounds__(256) void k_cvt_all(
    const void* __restrict__ feat, const void* __restrict__ coords,
    float* __restrict__ featT, float* __restrict__ coordsC,
    float* __restrict__ paramsC,
    int* __restrict__ qhead, int* __restrict__ progress,
    float* __restrict__ stats1,
    const void* W1, const void* b1, const void* g1, const void* be1,
    const void* W2, const void* b2, const void* g2, const void* be2)
{
    __shared__ float tile[64][65];
    __shared__ int sflag;
    int tid = threadIdx.x, blk = blockIdx.x;
    if (tid < 64) {
        int fl0 = detect_flag_wave((const unsigned short*)feat, tid);
        if (tid == 0) sflag = fl0;
    }
    __syncthreads();
    int fl = sflag;
    if (blk == 0) {
        if (tid == 0) *qhead = 0;
        if (tid < 8) progress[tid * 16] = -1;
        stats1[tid] = 0.f;
        stats1[tid + 256] = 0.f;
    }
    if (blk < 512) {
        int i = blk;
        int b = i >> 6, n0 = (i & 63) * 64;
        int c = tid >> 2, q = tid & 3;
        size_t base = ((size_t)b * 64 + c) * NN + n0 + q * 16;
        if (fl) {
            const float* sp = (const float*)feat + base;
#pragma unroll
            for (int j = 0; j < 16; j++) tile[c][q * 16 + j] = sp[j];
        } else {
            const unsigned short* sp = (const unsigned short*)feat + base;
#pragma unroll
            for (int j = 0; j < 16; j++) tile[c][q * 16 + j] = bf2f(sp[j]);
        }
        __syncthreads();
        int n = tid >> 2;
        float* dp = featT + ((size_t)b * NN + n0 + n) * 64 + q * 16;
#pragma unroll
        for (int j = 0; j < 16; j++) dp[j] = tile[q * 16 + j][n];
    } else if (blk < 896) {
        int idx = (blk - 512) * 256 + tid;
        coordsC[idx] = fl ? ((const float*)coords)[idx]
                          : bf2f(((const unsigned short*)coords)[idx]);
    } else {
        int idx = (blk - 896) * 256 + tid;
        if (idx < 13056) {
            const void* src; int off;
            if (idx < 4288)       { src = W1;  off = idx; }
            else if (idx < 4352)  { src = b1;  off = idx - 4288; }
            else if (idx < 4416)  { src = g1;  off = idx - 4352; }
            else if (idx < 4480)  { src = be1; off = idx - 4416; }
            else if (idx < 12672) { src = W2;  off = idx - 4480; }
            else if (idx < 12800) { src = b2;  off = idx - 12672; }
            else if (idx < 12928) { src = g2;  off = idx - 12800; }
            else                  { src = be2; off = idx - 12928; }
            paramsC[idx] = fl ? ((const float*)src)[off]
                              : bf2f(((const unsigned short*)src)[off]);
        }
    }
}

// ====== shared LDS macros ======
#define W1Tm(j,c)     (((float*)SM)[(j)*64+(c)])
#define GBUFm(mi,k,c) (((float*)(SM+17152))[(((mi)*32+(k))*66)+(c)])
#define GCm(mi,j,k)   (((float*)(SM+50944))[(((mi)*3+(j))*32)+(k)])
#define NDm(mi,k)     (((int*)(SM+52480))[((mi)*32)+(k)])
#define W2Tm(j,c)     (((float*)SM)[(j)*128+(c)])
#define ACTm(mi,j,k)  (((float*)(SM+32768))[(((mi)*64+(j))*32)+(k)])

// ================= launch 2: FPS (blocks 0..7) + persistent workers =======
struct PW { double d; int p; int q; };
#define PSM_XS   ((float*)(SM))
#define PSM_YS   ((float*)(SM + 16384))
#define PSM_ZS   ((float*)(SM + 32768))
#define PSM_HIST ((int*)(SM + 49152))
#define PSM_PWB  ((PW*)(SM + 53248))
#define PSM_SF   ((int*)(SM + 53376))

#define RESCAN(G) { \
    double gd = 1.0e300; int ga = (G) * 8; \
    _Pragma("unroll") \
    for (int i = 0; i < 8; i++) { \
        int sl = (G) * 8 + i; \
        unsigned int bit = (sl < 32) ? (elo >> sl) : (ehi >> (sl - 32)); \
        double cd = (bit & 1u) ? 1.0e300 : d[sl]; \
        bool rep = cd < gd; \
        gd = rep ? cd : gd; ga = rep ? sl : ga; \
    } \
    g8[(G)] = gd; a8[(G)] = ga; }

__global__ __launch_bounds__(256) void k_fpsknn(
    const void* __restrict__ coords, const float* __restrict__ coordsC,
    float* __restrict__ centersF, int* __restrict__ nidx,
    const void* __restrict__ temb, const void* __restrict__ feat,
    const float* __restrict__ featT, const float* __restrict__ paramsC,
    float* __restrict__ stats1,
    void* __restrict__ d_out,
    int* __restrict__ qhead, int* __restrict__ progress,
    unsigned short* __restrict__ h1, int cache1)
{
    __shared__ __align__(16) char SM[55296];
    int tid = threadIdx.x;
    int blk = blockIdx.x;
    if (tid < 64) {
        int fl0 = detect_flag_wave((const unsigned short*)feat, tid);
        if (tid == 0) *PSM_SF = fl0;
    }
    __syncthreads();
    int fl = *PSM_SF;

    if (blk < 8) {
        // ---------- FPS in f64, 256 thr, DPP butterfly ----------
        int b = blk;
        if (fl) {
            const float* cb = (const float*)coords + (size_t)b * 3 * NN;
#pragma unroll
            for (int i = 0; i < 16; i++) {
                int p = tid + i * 256;
                PSM_XS[p] = cb[p]; PSM_YS[p] = cb[NN + p]; PSM_ZS[p] = cb[2 * NN + p];
            }
        } else {
            const unsigned short* cb = (const unsigned short*)coords + (size_t)b * 3 * NN;
#pragma unroll
            for (int i = 0; i < 16; i++) {
                int p = tid + i * 256;
                PSM_XS[p] = bf2f(cb[p]); PSM_YS[p] = bf2f(cb[NN + p]); PSM_ZS[p] = bf2f(cb[2 * NN + p]);
            }
        }
        if (tid == 0) PSM_HIST[0] = 0;
        __syncthreads();
        if (tid == 0) {
            *(float4*)(centersF + (size_t)b * MM * 4) =
                make_float4(PSM_XS[0], PSM_YS[0], PSM_ZS[0], 0.f);
            __hip_atomic_store(&progress[b * 16], 0, __ATOMIC_RELEASE, __HIP_MEMORY_SCOPE_AGENT);
        }
        int base = tid * 16;
        double px[16], py[16], pz[16], dist[16];
        double x0 = (double)PSM_XS[0], y0 = (double)PSM_YS[0], z0 = (double)PSM_ZS[0];
        double bd = -1.0; int bp = base;
#pragma unroll
        for (int j = 0; j < 16; j++) {
            px[j] = (double)PSM_XS[base + j]; py[j] = (double)PSM_YS[base + j]; pz[j] = (double)PSM_ZS[base + j];
            double dx = px[j] - x0, dy = py[j] - y0, dz = pz[j] - z0;
            dist[j] = fma(dz, dz, fma(dy, dy, dx * dx));
            bool rep = dist[j] > bd;
            bd = rep ? dist[j] : bd; bp = rep ? base + j : bp;
        }
        int lane = tid & 63, wid = tid >> 6;
#pragma unroll 1
        for (int s = 1; s < MM; s++) {
            redmax64(bd, bp);
            int par = s & 1;
            if (lane == 0) { PW w; w.d = bd; w.p = bp; w.q = 0; PSM_PWB[par * 4 + wid] = w; }
            __syncthreads();
            PW w0 = PSM_PWB[par * 4 + 0];
            double wd = w0.d; int wp = w0.p;
#pragma unroll
            for (int w = 1; w < 4; w++) {
                PW ww = PSM_PWB[par * 4 + w];
                bool rep = (ww.d > wd) || (ww.d == wd && ww.p < wp);
                wd = rep ? ww.d : wd; wp = rep ? ww.p : wp;
            }
            if (tid == 0) PSM_HIST[s] = wp;
            if ((s & 31) == 31 && s >= 63 && wid == ((s >> 5) & 3)) {
                int s0 = s - 63;
                if (lane < 32) {
                    int far = PSM_HIST[s0 + lane];
                    *(float4*)(centersF + ((size_t)b * MM + s0 + lane) * 4) =
                        make_float4(PSM_XS[far], PSM_YS[far], PSM_ZS[far], 0.f);
                }
                if (lane == 0)
                    __hip_atomic_store(&progress[b * 16], s0 + 31,
                                       __ATOMIC_RELEASE, __HIP_MEMORY_SCOPE_AGENT);
            }
            double fx = (double)PSM_XS[wp], fy = (double)PSM_YS[wp], fz = (double)PSM_ZS[wp];
            bd = -1.0; bp = base;
#pragma unroll
            for (int j = 0; j < 16; j++) {
                double dx = px[j] - fx, dy = py[j] - fy, dz = pz[j] - fz;
                double d = fma(dz, dz, fma(dy, dy, dx * dx));
                dist[j] = fmin(dist[j], d);
                bool rep = dist[j] > bd;
                bd = rep ? dist[j] : bd; bp = rep ? base + j : bp;
            }
        }
        __syncthreads();
        if (tid < 32) {
            int far = PSM_HIST[992 + tid];
            *(float4*)(centersF + ((size_t)b * MM + 992 + tid) * 4) =
                make_float4(PSM_XS[far], PSM_YS[far], PSM_ZS[far], 0.f);
        }
        if (tid == 0)
            __hip_atomic_store(&progress[b * 16], 1023,
                               __ATOMIC_RELEASE, __HIP_MEMORY_SCOPE_AGENT);
#pragma unroll
        for (int i = 0; i < 4; i++) {
            int m = tid + i * 256;
            int far = PSM_HIST[m];
            float X = PSM_XS[far], Y = PSM_YS[far], Z = PSM_ZS[far];
            if (fl) {
                float* o = (float*)d_out;
                o[OUT1_OFF + (size_t)(b * 3 + 0) * MM + m] = X;
                o[OUT1_OFF + (size_t)(b * 3 + 1) * MM + m] = Y;
                o[OUT1_OFF + (size_t)(b * 3 + 2) * MM + m] = Z;
            } else {
                unsigned short* o = (unsigned short*)d_out;
                o[OUT1_OFF + (size_t)(b * 3 + 0) * MM + m] = f2bf(X);
                o[OUT1_OFF + (size_t)(b * 3 + 1) * MM + m] = f2bf(Y);
                o[OUT1_OFF + (size_t)(b * 3 + 2) * MM + m] = f2bf(Z);
            }
        }
    } else {
        // ---------- persistent workers: kNN + gtemb + MLP1/GN1 stats ----------
        int lane = tid & 63, wid = tid >> 6;
        for (int t = tid; t < 64 * 67; t += 256) {
            int c = t / 67, j = t % 67;
            W1Tm(j, c) = paramsC[P_W1 + t];
        }
        __syncthreads();
        for (;;) {
            int id = 0;
            if (lane == 0) id = atomicAdd(qhead, 1);
            id = __shfl(id, 0, 64);
            if (id >= BB * MM) break;
            int b = id & 7, m = id >> 3;
            while (__hip_atomic_load(&progress[b * 16], __ATOMIC_RELAXED,
                                     __HIP_MEMORY_SCOPE_AGENT) < m)
                __builtin_amdgcn_s_sleep(64);
            (void)__hip_atomic_load(&progress[b * 16], __ATOMIC_ACQUIRE,
                                    __HIP_MEMORY_SCOPE_AGENT);
            int bm = b * MM + m;
            const float* cb = coordsC + (size_t)b * 3 * NN;
            float4 ctr = *(const float4*)(centersF + (size_t)bm * 4);
            double cx = (double)ctr.x, cy = (double)ctr.y, cz = (double)ctr.z;
            double cc = (cx * cx + cy * cy) + cz * cz;
            double d[64];
#pragma unroll 4
            for (int j = 0; j < 64; j++) {
                int p = j * 64 + lane;
                double x = (double)cb[p], y = (double)cb[NN + p], z = (double)cb[2 * NN + p];
                double pp = (x * x + y * y) + z * z;
                double dt = (cx * x + cy * y) + cz * z;
                d[j] = (cc + pp) - 2.0 * dt;
            }
            double g8[8]; int a8[8];
#pragma unroll
            for (int g = 0; g < 8; g++) {
                double gd = d[g * 8]; int ga = g * 8;
#pragma unroll
                for (int i = 1; i < 8; i++) {
                    int sl = g * 8 + i;
                    bool rep = d[sl] < gd;
                    gd = rep ? d[sl] : gd; ga = rep ? sl : ga;
                }
                g8[g] = gd; a8[g] = ga;
            }
            unsigned int elo = 0, ehi = 0;
            int res = 0;
#pragma unroll 1
            for (int it = 0; it < 32; it++) {
                double bd = g8[0]; int ba = a8[0];
#pragma unroll
                for (int g = 1; g < 8; g++) {
                    bool rep = g8[g] < bd;
                    bd = rep ? g8[g] : bd; ba = rep ? a8[g] : ba;
                }
                int bp = ba * 64 + lane;
                double wd = bd; int wp = bp;
#pragma unroll
                for (int s = 32; s >= 1; s >>= 1) {
                    double od = __shfl_xor(wd, s, 64);
                    int op = __shfl_xor(wp, s, 64);
                    bool rep = (od < wd) || (od == wd && op < wp);
                    wd = rep ? od : wd; wp = rep ? op : wp;
                }
                res = (lane == it) ? wp : res;
                if (bp == wp) {
                    int slot = ba;
                    if (slot < 32) elo |= (1u << slot); else ehi |= (1u << (slot - 32));
                    int g = slot >> 3;
                    switch (g) {
                        case 0: RESCAN(0) break;
                        case 1: RESCAN(1) break;
                        case 2: RESCAN(2) break;
                        case 3: RESCAN(3) break;
                        case 4: RESCAN(4) break;
                        case 5: RESCAN(5) break;
                        case 6: RESCAN(6) break;
                        case 7: RESCAN(7) break;
                    }
                }
            }
            if (lane < KK) nidx[(size_t)bm * KK + lane] = res;
            float best = -3.0e38f;
            if (fl) {
                const float* tb = (const float*)temb + ((size_t)b * 64 + lane) * NN;
#pragma unroll 4
                for (int k = 0; k < 32; k++) {
                    int nk = __shfl(res, k, 64);
                    best = fmaxf(best, tb[nk]);
                }
            } else {
                const unsigned short* tb = (const unsigned short*)temb + ((size_t)b * 64 + lane) * NN;
#pragma unroll 4
                for (int k = 0; k < 32; k++) {
                    int nk = __shfl(res, k, 64);
                    best = fmaxf(best, bf2f(tb[nk]));
                }
            }
            size_t off = (size_t)OUT2_OFF + ((size_t)(b * 64 + lane)) * MM + m;
            if (fl) ((float*)d_out)[off] = best;
            else    ((unsigned short*)d_out)[off] = f2bf(best);
            // ---- MLP1 for this center ----
            if (lane < 32) NDm(wid, lane) = res & (NN - 1);
            const float* fb = featT + (size_t)b * NN * 64;
#pragma unroll 4
            for (int q = 0; q < 32; q++) {
                int n = NDm(wid, q);
                GBUFm(wid, q, lane) = fb[(size_t)n * 64 + lane];
            }
            if (lane < 32) {
                int n = NDm(wid, lane);
                GCm(wid, 0, lane) = __fsub_rn(cb[n], ctr.x);
                GCm(wid, 1, lane) = __fsub_rn(cb[NN + n], ctr.y);
                GCm(wid, 2, lane) = __fsub_rn(cb[2 * NN + n], ctr.z);
            }
            int c0 = (lane >> 3) * 8;
            int k0 = (lane & 7) * 4;
            float acc[8][4];
#pragma unroll
            for (int i = 0; i < 8; i++)
#pragma unroll
                for (int kk = 0; kk < 4; kk++) acc[i][kk] = 0.f;
#pragma unroll
            for (int j = 0; j < 3; j++) {
                float4 a = *(const float4*)&GCm(wid, j, k0);
                float4 w0 = *(const float4*)&W1Tm(j, c0);
                float4 w1v = *(const float4*)&W1Tm(j, c0 + 4);
                float w[8] = {w0.x, w0.y, w0.z, w0.w, w1v.x, w1v.y, w1v.z, w1v.w};
#pragma unroll
                for (int i = 0; i < 8; i++) {
                    acc[i][0] = fmaf(w[i], a.x, acc[i][0]);
                    acc[i][1] = fmaf(w[i], a.y, acc[i][1]);
                    acc[i][2] = fmaf(w[i], a.z, acc[i][2]);
                    acc[i][3] = fmaf(w[i], a.w, acc[i][3]);
                }
            }
#pragma unroll 4
            for (int c = 0; c < 64; c++) {
                float f0 = GBUFm(wid, k0 + 0, c);
                float f1 = GBUFm(wid, k0 + 1, c);
                float f2 = GBUFm(wid, k0 + 2, c);
                float f3 = GBUFm(wid, k0 + 3, c);
                int j = 3 + c;
                float4 w0 = *(const float4*)&W1Tm(j, c0);
                float4 w1v = *(const float4*)&W1Tm(j, c0 + 4);
                float w[8] = {w0.x, w0.y, w0.z, w0.w, w1v.x, w1v.y, w1v.z, w1v.w};
#pragma unroll
                for (int i = 0; i < 8; i++) {
                    acc[i][0] = fmaf(w[i], f0, acc[i][0]);
                    acc[i][1] = fmaf(w[i], f1, acc[i][1]);
                    acc[i][2] = fmaf(w[i], f2, acc[i][2]);
                    acc[i][3] = fmaf(w[i], f3, acc[i][3]);
                }
            }
            float s = 0.f, s2 = 0.f;
#pragma unroll
            for (int i = 0; i < 8; i++) {
                float bb = paramsC[P_B1 + c0 + i];
                float v0 = acc[i][0] + bb, v1 = acc[i][1] + bb;
                float v2 = acc[i][2] + bb, v3 = acc[i][3] + bb;
                s += v0; s2 = fmaf(v0, v0, s2);
                s += v1; s2 = fmaf(v1, v1, s2);
                s += v2; s2 = fmaf(v2, v2, s2);
                s += v3; s2 = fmaf(v3, v3, s2);
                if (cache1) {
                    unsigned int p0 = (unsigned int)f2bf(v0) | ((unsigned int)f2bf(v1) << 16);
                    unsigned int p1 = (unsigned int)f2bf(v2) | ((unsigned int)f2bf(v3) << 16);
                    *(uint2*)(h1 + ((size_t)bm * 64 + c0 + i) * 32 + k0) = make_uint2(p0, p1);
                }
            }
            s += __shfl_xor(s, 1, 64); s += __shfl_xor(s, 2, 64); s += __shfl_xor(s, 4, 64);
            s2 += __shfl_xor(s2, 1, 64); s2 += __shfl_xor(s2, 2, 64); s2 += __shfl_xor(s2, 4, 64);
            if ((lane & 7) == 0) {
                int g = lane >> 3;
                atomicAdd(&stats1[(b * 8 + g) * 2], s);
                atomicAdd(&stats1[(b * 8 + g) * 2 + 1], s2);
            }
        }
    }
}

// ================= fused MLP machinery (featT f32 gathers) =================
__device__ __forceinline__ void mlp1_compute(
    char* SM, int tid, int lane, int mi, int b, int bm,
    const float* __restrict__ featT, const float* __restrict__ coordsC,
    const float* __restrict__ centersF, const int* __restrict__ nidx,
    const float* __restrict__ P, float acc[8][4])
{
    for (int t = tid; t < 64 * 67; t += 256) {
        int c = t / 67, j = t % 67;
        W1Tm(j, c) = P[P_W1 + t];
    }
    if (lane < 32) NDm(mi, lane) = nidx[(size_t)bm * KK + lane] & (NN - 1);
    __syncthreads();
    const float* fb = featT + (size_t)b * NN * 64;
#pragma unroll 4
    for (int q = 0; q < 32; q++) {
        int n = NDm(mi, q);
        GBUFm(mi, q, lane) = fb[(size_t)n * 64 + lane];
    }
    float4 ctr = *(const float4*)(centersF + (size_t)bm * 4);
    const float* cb = coordsC + (size_t)b * 3 * NN;
    if (lane < 32) {
        int n = NDm(mi, lane);
        GCm(mi, 0, lane) = __fsub_rn(cb[n], ctr.x);
        GCm(mi, 1, lane) = __fsub_rn(cb[NN + n], ctr.y);
        GCm(mi, 2, lane) = __fsub_rn(cb[2 * NN + n], ctr.z);
    }
    __syncthreads();
    int c0 = (lane >> 3) * 8;
    int k0 = (lane & 7) * 4;
#pragma unroll
    for (int i = 0; i < 8; i++)
#pragma unroll
        for (int kk = 0; kk < 4; kk++) acc[i][kk] = 0.f;
#pragma unroll
    for (int j = 0; j < 3; j++) {
        float4 a = *(const float4*)&GCm(mi, j, k0);
        float4 w0 = *(const float4*)&W1Tm(j, c0);
        float4 w1v = *(const float4*)&W1Tm(j, c0 + 4);
        float w[8] = {w0.x, w0.y, w0.z, w0.w, w1v.x, w1v.y, w1v.z, w1v.w};
#pragma unroll
        for (int i = 0; i < 8; i++) {
            acc[i][0] = fmaf(w[i], a.x, acc[i][0]);
            acc[i][1] = fmaf(w[i], a.y, acc[i][1]);
            acc[i][2] = fmaf(w[i], a.z, acc[i][2]);
            acc[i][3] = fmaf(w[i], a.w, acc[i][3]);
        }
    }
#pragma unroll 4
    for (int c = 0; c < 64; c++) {
        float f0 = GBUFm(mi, k0 + 0, c);
        float f1 = GBUFm(mi, k0 + 1, c);
        float f2 = GBUFm(mi, k0 + 2, c);
        float f3 = GBUFm(mi, k0 + 3, c);
        int j = 3 + c;
        float4 w0 = *(const float4*)&W1Tm(j, c0);
        float4 w1v = *(const float4*)&W1Tm(j, c0 + 4);
        float w[8] = {w0.x, w0.y, w0.z, w0.w, w1v.x, w1v.y, w1v.z, w1v.w};
#pragma unroll
        for (int i = 0; i < 8; i++) {
            acc[i][0] = fmaf(w[i], f0, acc[i][0]);
            acc[i][1] = fmaf(w[i], f1, acc[i][1]);
            acc[i][2] = fmaf(w[i], f2, acc[i][2]);
            acc[i][3] = fmaf(w[i], f3, acc[i][3]);
        }
    }
}

// v1 = h1 values (bias included). Produces v2 = acc2 + b2 (bias included).
__device__ __forceinline__ void mlp2_compute(
    char* SM, int tid, int lane, int mi, int b,
    const float v1[8][4], const float* __restrict__ S1,
    const float* __restrict__ P, float v2[16][4])
{
    __syncthreads();
    int c0 = (lane >> 3) * 8;
    int k0 = (lane & 7) * 4;
    int g = c0 >> 3;
    float S = S1[(b * 8 + g) * 2], Q = S1[(b * 8 + g) * 2 + 1];
    float mean = S * (1.0f / 262144.0f);
    float var = Q * (1.0f / 262144.0f) - mean * mean;
    float inv = rsqrtf(var + 1e-5f);
#pragma unroll
    for (int i = 0; i < 8; i++) {
        int c = c0 + i;
        float sc = P[P_G1 + c] * inv;
        float sh = P[P_BE1 + c] - mean * sc;
#pragma unroll
        for (int kk = 0; kk < 4; kk++)
            ACTm(mi, c, k0 + kk) = swishf(fmaf(v1[i][kk], sc, sh));
    }
    for (int t = tid; t < 128 * 64; t += 256) {
        int c = t >> 6, j = t & 63;
        W2Tm(j, c) = P[P_W2 + t];
    }
    __syncthreads();
    int c02 = (lane >> 3) * 16;
    float acc2[16][4];
#pragma unroll
    for (int i = 0; i < 16; i++)
#pragma unroll
        for (int kk = 0; kk < 4; kk++) acc2[i][kk] = 0.f;
#pragma unroll 4
    for (int j = 0; j < 64; j++) {
        float4 a = *(const float4*)&ACTm(mi, j, k0);
        float4 w0 = *(const float4*)&W2Tm(j, c02);
        float4 w1v = *(const float4*)&W2Tm(j, c02 + 4);
        float4 w2v = *(const float4*)&W2Tm(j, c02 + 8);
        float4 w3 = *(const float4*)&W2Tm(j, c02 + 12);
        float w[16] = {w0.x, w0.y, w0.z, w0.w, w1v.x, w1v.y, w1v.z, w1v.w,
                       w2v.x, w2v.y, w2v.z, w2v.w, w3.x, w3.y, w3.z, w3.w};
#pragma unroll
        for (int i = 0; i < 16; i++) {
            acc2[i][0] = fmaf(w[i], a.x, acc2[i][0]);
            acc2[i][1] = fmaf(w[i], a.y, acc2[i][1]);
            acc2[i][2] = fmaf(w[i], a.z, acc2[i][2]);
            acc2[i][3] = fmaf(w[i], a.w, acc2[i][3]);
        }
    }
#pragma unroll
    for (int i = 0; i < 16; i++) {
        float bb = P[P_B2 + c02 + i];
#pragma unroll
        for (int kk = 0; kk < 4; kk++) v2[i][kk] = acc2[i][kk] + bb;
    }
}

// load/compute v1 (bias-included h1 values)
__device__ __forceinline__ void get_v1(
    char* SM, int tid, int lane, int mi, int b, int bm,
    const float* featT, const float* coordsC, const float* centersF,
    const int* nidx, const float* P,
    const unsigned short* h1, int cache1, float v1[8][4])
{
    int c0 = (lane >> 3) * 8;
    int k0 = (lane & 7) * 4;
    if (cache1) {
#pragma unroll
        for (int i = 0; i < 8; i++) {
            uint2 u = *(const uint2*)(h1 + ((size_t)bm * 64 + c0 + i) * 32 + k0);
            v1[i][0] = bf2f((unsigned short)(u.x & 0xffffu));
            v1[i][1] = bf2f((unsigned short)(u.x >> 16));
            v1[i][2] = bf2f((unsigned short)(u.y & 0xffffu));
            v1[i][3] = bf2f((unsigned short)(u.y >> 16));
        }
    } else {
        float acc1[8][4];
        mlp1_compute(SM, tid, lane, mi, b, bm, featT, coordsC, centersF, nidx, P, acc1);
#pragma unroll
        for (int i = 0; i < 8; i++) {
            float bb = P[P_B1 + c0 + i];
#pragma unroll
            for (int kk = 0; kk < 4; kk++) v1[i][kk] = acc1[i][kk] + bb;
        }
    }
}

// ---------------- MLP2 + GN2 stats (optionally cache h2)
__global__ __launch_bounds__(256) void k_mlp2s(
    const float* __restrict__ featT, const float* __restrict__ coordsC,
    const float* __restrict__ centersF, const int* __restrict__ nidx,
    const float* __restrict__ P, const float* __restrict__ stats1,
    float* __restrict__ stats2,
    const unsigned short* __restrict__ h1, unsigned short* __restrict__ h2,
    int cache1, int cache2)
{
    __shared__ __align__(16) char smem[65536];
    char* SM = smem;
    int tid = threadIdx.x, blk = blockIdx.x;
    int b = blk >> 8, m0 = (blk & 255) * 4;
    int mi = tid >> 6, lane = tid & 63;
    int bm = b * MM + m0 + mi;
    float v1[8][4];
    get_v1(SM, tid, lane, mi, b, bm, featT, coordsC, centersF, nidx, P, h1, cache1, v1);
    float v2[16][4];
    mlp2_compute(SM, tid, lane, mi, b, v1, stats1, P, v2);
    int c02 = (lane >> 3) * 16;
    int k0 = (lane & 7) * 4;
    float s = 0.f, s2 = 0.f;
#pragma unroll
    for (int i = 0; i < 16; i++) {
#pragma unroll
        for (int kk = 0; kk < 4; kk++) {
            float v = v2[i][kk];
            s += v; s2 = fmaf(v, v, s2);
        }
        if (cache2) {
            unsigned int p0 = (unsigned int)f2bf(v2[i][0]) | ((unsigned int)f2bf(v2[i][1]) << 16);
            unsigned int p1 = (unsigned int)f2bf(v2[i][2]) | ((unsigned int)f2bf(v2[i][3]) << 16);
            *(uint2*)(h2 + ((size_t)bm * 128 + c02 + i) * 32 + k0) = make_uint2(p0, p1);
        }
    }
    s += __shfl_xor(s, 1, 64); s += __shfl_xor(s, 2, 64); s += __shfl_xor(s, 4, 64);
    s2 += __shfl_xor(s2, 1, 64); s2 += __shfl_xor(s2, 2, 64); s2 += __shfl_xor(s2, 4, 64);
    __syncthreads();
    float* sred = (float*)SM;
    if ((lane & 7) == 0) {
        int g = lane >> 3;
        sred[(mi * 8 + g) * 2] = s;
        sred[(mi * 8 + g) * 2 + 1] = s2;
    }
    __syncthreads();
    if (tid < 16) {
        int g = tid >> 1, w = tid & 1;
        float t = sred[(0 * 8 + g) * 2 + w] + sred[(1 * 8 + g) * 2 + w]
                + sred[(2 * 8 + g) * 2 + w] + sred[(3 * 8 + g) * 2 + w];
        atomicAdd(&stats2[(b * 8 + g) * 2 + w], t);
    }
}

// ---------------- final: GN2 + swish + max over K -> out0
__global__ __launch_bounds__(256) void k_final(
    const float* __restrict__ featT, const float* __restrict__ coordsC,
    const float* __restrict__ centersF, const int* __restrict__ nidx,
    const float* __restrict__ P, const float* __restrict__ stats1,
    const float* __restrict__ stats2,
    void* __restrict__ d_out, const void* __restrict__ feat,
    const unsigned short* __restrict__ h1, const unsigned short* __restrict__ h2,
    int cache1, int cache2)
{
    __shared__ __align__(16) char smem[65536];
    char* SM = smem;
    int tid = threadIdx.x, blk = blockIdx.x;
    if (tid < 64) {
        int fl0 = detect_flag_wave((const unsigned short*)feat, tid);
        if (tid == 0) *(int*)(SM + 53248) = fl0;
    }
    __syncthreads();
    int fl = *(int*)(SM + 53248);
    int b = blk >> 8, m0 = (blk & 255) * 4;
    int mi = tid >> 6, lane = tid & 63;
    int bm = b * MM + m0 + mi;
    int c02 = (lane >> 3) * 16;
    int k0 = (lane & 7) * 4;
    float v2[16][4];
    if (cache2) {
#pragma unroll
        for (int i = 0; i < 16; i++) {
            uint2 u = *(const uint2*)(h2 + ((size_t)bm * 128 + c02 + i) * 32 + k0);
            v2[i][0] = bf2f((unsigned short)(u.x & 0xffffu));
            v2[i][1] = bf2f((unsigned short)(u.x >> 16));
            v2[i][2] = bf2f((unsigned short)(u.y & 0xffffu));
            v2[i][3] = bf2f((unsigned short)(u.y >> 16));
        }
    } else {
        float v1[8][4];
        get_v1(SM, tid, lane, mi, b, bm, featT, coordsC, centersF, nidx, P, h1, cache1, v1);
        mlp2_compute(SM, tid, lane, mi, b, v1, stats1, P, v2);
    }
    int g2 = c02 >> 4;
    float S = stats2[(b * 8 + g2) * 2], Q = stats2[(b * 8 + g2) * 2 + 1];
    float mean = S * (1.0f / 524288.0f);
    float var = Q * (1.0f / 524288.0f) - mean * mean;
    float inv = rsqrtf(var + 1e-5f);
    float mx[16];
#pragma unroll
    for (int i = 0; i < 16; i++) {
        int c = c02 + i;
        float sc = P[P_G2 + c] * inv;
        float sh = P[P_BE2 + c] - mean * sc;
        float v = -3.0e38f;
#pragma unroll
        for (int kk = 0; kk < 4; kk++)
            v = fmaxf(v, swishf(fmaf(v2[i][kk], sc, sh)));
        v = fmaxf(v, __shfl_xor(v, 1, 64));
        v = fmaxf(v, __shfl_xor(v, 2, 64));
        v = fmaxf(v, __shfl_xor(v, 4, 64));
        mx[i] = v;
    }
    if ((lane & 7) == 0) {
        int m = m0 + mi;
#pragma unroll
        for (int i = 0; i < 16; i++) {
            size_t off = (size_t)(b * 128 + c02 + i) * MM + m;
            if (fl) ((float*)d_out)[off] = mx[i];
            else    ((unsigned short*)d_out)[off] = f2bf(mx[i]);
        }
    }
}

extern "C" void kernel_launch(void* const* d_in, const int* in_sizes, int n_in,
                              void* d_out, int out_size, void* d_ws, size_t ws_size,
                              hipStream_t stream) {
    (void)in_sizes; (void)n_in; (void)out_size;
    const void* feat = d_in[0];
    const void* coords = d_in[1];
    const void* temb = d_in[2];

    // base workspace: 10,016,768 B (proven safe). Optional caches gated on
    // ws_size: h1 bf16 (32 MB) and h2 bf16 (64 MB).
    char* ws = (char*)d_ws;
    int* qhead = (int*)ws;                                 // @0
    int* progress = (int*)(ws + 512);                      // 8 x 64B-strided ints
    float* stats1 = (float*)(ws + 1024);                   // 256 f32 (GN1)
    float* stats2 = (float*)(ws + 2048);                   // 256 f32 (GN2)
    float* coordsC = (float*)(ws + 3072);                  // 393,216
    float* paramsC = (float*)(ws + 396288);                // 52,224
    float* centersF = (float*)(ws + 448512);               // 131,072
    int* nidx = (int*)(ws + 579584);                       // 1,048,576
    float* featT = (float*)(ws + 1628160);                 // 8,388,608 -> 10,016,768
    unsigned short* h1 = (unsigned short*)(ws + 10016768); // 33,554,432 -> 43,571,200
    unsigned short* h2 = (unsigned short*)(ws + 43571200); // 67,108,864 -> 110,680,064
    int cache1 = (ws_size >= 43571200u) ? 1 : 0;
    int cache2 = (ws_size >= 110680064u) ? 1 : 0;

    k_cvt_all<<<947, 256, 0, stream>>>(feat, coords, featT, coordsC, paramsC,
                                       qhead, progress, stats1,
                                       d_in[3], d_in[4], d_in[5], d_in[6],
                                       d_in[7], d_in[8], d_in[9], d_in[10]);
    k_fpsknn<<<256, 256, 0, stream>>>(coords, coordsC, centersF, nidx, temb,
                                      feat, featT, paramsC, stats1, d_out,
                                      qhead, progress, h1, cache1);
    k_mlp2s<<<2048, 256, 0, stream>>>(featT, coordsC, centersF, nidx, paramsC,
                                      stats1, stats2, h1, h2, cache1, cache2);
    k_final<<<2048, 256, 0, stream>>>(featT, coordsC, centersF, nidx, paramsC,
                                      stats1, stats2, d_out, feat, h1, h2,
                                      cache1, cache2);
}

// Round 15
// 1332.756 us; speedup vs baseline: 1.6888x; 1.0104x over previous
//
#include <hip/hip_runtime.h>
#include <stdint.h>

#define BB 8
#define NN 4096
#define MM 1024
#define KK 32

__device__ __forceinline__ float bf2f(unsigned short u) {
    union { unsigned int i; float f; } v; v.i = ((unsigned int)u) << 16; return v.f;
}
__device__ __forceinline__ unsigned short f2bf(float f) {
    union { float f; unsigned int i; } v; v.f = f;
    unsigned int x = v.i;
    x += 0x7fffu + ((x >> 16) & 1u);
    return (unsigned short)(x >> 16);
}
__device__ __forceinline__ float swishf(float y) {
    return __fdividef(y, 1.0f + __expf(-y));
}

// out element offsets (dtype-independent)
#define OUT1_OFF 1048576
#define OUT2_OFF 1073152

// params canonical f32 layout (floats)
#define P_W1 0
#define P_B1 4288
#define P_G1 4352
#define P_BE1 4416
#define P_W2 4480
#define P_B2 12672
#define P_G2 12800
#define P_BE2 12928

__device__ __forceinline__ int detect_flag_wave(const unsigned short* f, int lane) {
    unsigned short u = f[lane * 2];
    float x = fabsf(bf2f(u));
    bool ext = (u != 0) && (x > 100.0f || x < 1e-30f);
    unsigned long long m = __ballot(ext);
    return (__popcll(m) >= 16) ? 1 : 0;
}

// ---- DPP-accelerated 64-lane lex-max (d desc, idx asc) reduction ----
#define DPP_STAGE(CTRL) { \
    union { double d; unsigned int u[2]; } s_, r_; \
    s_.d = bd; \
    r_.u[0] = (unsigned)__builtin_amdgcn_update_dpp(0, (int)s_.u[0], CTRL, 0xF, 0xF, true); \
    r_.u[1] = (unsigned)__builtin_amdgcn_update_dpp(0, (int)s_.u[1], CTRL, 0xF, 0xF, true); \
    int op_ = __builtin_amdgcn_update_dpp(0, bp, CTRL, 0xF, 0xF, true); \
    double od_ = r_.d; \
    bool rep_ = (od_ > bd) || (od_ == bd && op_ < bp); \
    bd = rep_ ? od_ : bd; bp = rep_ ? op_ : bp; }

__device__ __forceinline__ void redmax64(double& bd, int& bp) {
    DPP_STAGE(0xB1)
    DPP_STAGE(0x4E)
    DPP_STAGE(0x141)
    DPP_STAGE(0x140)
#pragma unroll
    for (int m = 32; m >= 16; m >>= 1) {
        double od = __shfl_xor(bd, m, 64);
        int op = __shfl_xor(bp, m, 64);
        bool rep = (od > bd) || (od == bd && op < bp);
        bd = rep ? od : bd; bp = rep ? op : bp;
    }
}

// ================= launch 1: coords/params cvt + sync/stat init ===========
// (featT transpose moved into worker prologue of k_fpsknn, overlapped w/ FPS)
__global__ __launch_bounds__(256) void k_cvt_all(
    const void* __restrict__ feat, const void* __restrict__ coords,
    float* __restrict__ coordsC, float* __restrict__ paramsC,
    int* __restrict__ qhead, int* __restrict__ progress,
    float* __restrict__ stats1, int* __restrict__ cvt_done,
    const void* W1, const void* b1, const void* g1, const void* be1,
    const void* W2, const void* b2, const void* g2, const void* be2)
{
    __shared__ int sflag;
    int tid = threadIdx.x, blk = blockIdx.x;
    if (tid < 64) {
        int fl0 = detect_flag_wave((const unsigned short*)feat, tid);
        if (tid == 0) sflag = fl0;
    }
    __syncthreads();
    int fl = sflag;
    if (blk == 0) {
        if (tid == 0) { *qhead = 0; *cvt_done = 0; }
        if (tid < 8) progress[tid * 16] = -1;
        stats1[tid] = 0.f;          // stats1 (256 f32)
        stats1[tid + 256] = 0.f;    // stats2 (contiguous after)
    }
    if (blk < 384) {
        int idx = blk * 256 + tid;
        coordsC[idx] = fl ? ((const float*)coords)[idx]
                          : bf2f(((const unsigned short*)coords)[idx]);
    } else {
        int idx = (blk - 384) * 256 + tid;
        if (idx < 13056) {
            const void* src; int off;
            if (idx < 4288)       { src = W1;  off = idx; }
            else if (idx < 4352)  { src = b1;  off = idx - 4288; }
            else if (idx < 4416)  { src = g1;  off = idx - 4352; }
            else if (idx < 4480)  { src = be1; off = idx - 4416; }
            else if (idx < 12672) { src = W2;  off = idx - 4480; }
            else if (idx < 12800) { src = b2;  off = idx - 12672; }
            else if (idx < 12928) { src = g2;  off = idx - 12800; }
            else                  { src = be2; off = idx - 12928; }
            paramsC[idx] = fl ? ((const float*)src)[off]
                              : bf2f(((const unsigned short*)src)[off]);
        }
    }
}

// ====== shared LDS macros ======
#define W1Tm(j,c)     (((float*)SM)[(j)*64+(c)])
#define GBUFm(mi,k,c) (((float*)(SM+17152))[(((mi)*32+(k))*66)+(c)])
#define GCm(mi,j,k)   (((float*)(SM+50944))[(((mi)*3+(j))*32)+(k)])
#define NDm(mi,k)     (((int*)(SM+52480))[((mi)*32)+(k)])
#define W2Tm(j,c)     (((float*)SM)[(j)*128+(c)])
#define ACTm(mi,j,k)  (((float*)(SM+32768))[(((mi)*64+(j))*32)+(k)])

// ================= launch 2: FPS (blocks 0..7) + persistent workers =======
struct PW { double d; int p; int q; };
#define PSM_XS   ((float*)(SM))
#define PSM_YS   ((float*)(SM + 16384))
#define PSM_ZS   ((float*)(SM + 32768))
#define PSM_HIST ((int*)(SM + 49152))
#define PSM_PWB  ((PW*)(SM + 53248))
#define PSM_SF   ((int*)(SM + 53376))

#define RESCAN(G) { \
    double gd = 1.0e300; int ga = (G) * 8; \
    _Pragma("unroll") \
    for (int i = 0; i < 8; i++) { \
        int sl = (G) * 8 + i; \
        unsigned int bit = (sl < 32) ? (elo >> sl) : (ehi >> (sl - 32)); \
        double cd = (bit & 1u) ? 1.0e300 : d[sl]; \
        bool rep = cd < gd; \
        gd = rep ? cd : gd; ga = rep ? sl : ga; \
    } \
    g8[(G)] = gd; a8[(G)] = ga; }

__global__ __launch_bounds__(256) void k_fpsknn(
    const void* __restrict__ coords, const float* __restrict__ coordsC,
    float* __restrict__ centersF, int* __restrict__ nidx,
    const void* __restrict__ temb, const void* __restrict__ feat,
    float* __restrict__ featT, const float* __restrict__ paramsC,
    float* __restrict__ stats1,
    void* __restrict__ d_out,
    int* __restrict__ qhead, int* __restrict__ progress,
    int* __restrict__ cvt_done,
    unsigned short* __restrict__ h1, int cache1)
{
    __shared__ __align__(16) char SM[55296];
    int tid = threadIdx.x;
    int blk = blockIdx.x;
    if (tid < 64) {
        int fl0 = detect_flag_wave((const unsigned short*)feat, tid);
        if (tid == 0) *PSM_SF = fl0;
    }
    __syncthreads();
    int fl = *PSM_SF;

    if (blk < 8) {
        // ---------- FPS in f64, 256 thr, DPP butterfly ----------
        int b = blk;
        if (fl) {
            const float* cb = (const float*)coords + (size_t)b * 3 * NN;
#pragma unroll
            for (int i = 0; i < 16; i++) {
                int p = tid + i * 256;
                PSM_XS[p] = cb[p]; PSM_YS[p] = cb[NN + p]; PSM_ZS[p] = cb[2 * NN + p];
            }
        } else {
            const unsigned short* cb = (const unsigned short*)coords + (size_t)b * 3 * NN;
#pragma unroll
            for (int i = 0; i < 16; i++) {
                int p = tid + i * 256;
                PSM_XS[p] = bf2f(cb[p]); PSM_YS[p] = bf2f(cb[NN + p]); PSM_ZS[p] = bf2f(cb[2 * NN + p]);
            }
        }
        if (tid == 0) PSM_HIST[0] = 0;
        __syncthreads();
        if (tid == 0) {
            *(float4*)(centersF + (size_t)b * MM * 4) =
                make_float4(PSM_XS[0], PSM_YS[0], PSM_ZS[0], 0.f);
            __hip_atomic_store(&progress[b * 16], 0, __ATOMIC_RELEASE, __HIP_MEMORY_SCOPE_AGENT);
        }
        int base = tid * 16;
        double px[16], py[16], pz[16], dist[16];
        double x0 = (double)PSM_XS[0], y0 = (double)PSM_YS[0], z0 = (double)PSM_ZS[0];
        double bd = -1.0; int bp = base;
#pragma unroll
        for (int j = 0; j < 16; j++) {
            px[j] = (double)PSM_XS[base + j]; py[j] = (double)PSM_YS[base + j]; pz[j] = (double)PSM_ZS[base + j];
            double dx = px[j] - x0, dy = py[j] - y0, dz = pz[j] - z0;
            dist[j] = fma(dz, dz, fma(dy, dy, dx * dx));
            bool rep = dist[j] > bd;
            bd = rep ? dist[j] : bd; bp = rep ? base + j : bp;
        }
        int lane = tid & 63, wid = tid >> 6;
#pragma unroll 1
        for (int s = 1; s < MM; s++) {
            redmax64(bd, bp);
            int par = s & 1;
            if (lane == 0) { PW w; w.d = bd; w.p = bp; w.q = 0; PSM_PWB[par * 4 + wid] = w; }
            __syncthreads();
            PW w0 = PSM_PWB[par * 4 + 0];
            double wd = w0.d; int wp = w0.p;
#pragma unroll
            for (int w = 1; w < 4; w++) {
                PW ww = PSM_PWB[par * 4 + w];
                bool rep = (ww.d > wd) || (ww.d == wd && ww.p < wp);
                wd = rep ? ww.d : wd; wp = rep ? ww.p : wp;
            }
            if (tid == 0) PSM_HIST[s] = wp;
            if ((s & 31) == 31 && s >= 63 && wid == ((s >> 5) & 3)) {
                int s0 = s - 63;
                if (lane < 32) {
                    int far = PSM_HIST[s0 + lane];
                    *(float4*)(centersF + ((size_t)b * MM + s0 + lane) * 4) =
                        make_float4(PSM_XS[far], PSM_YS[far], PSM_ZS[far], 0.f);
                }
                if (lane == 0)
                    __hip_atomic_store(&progress[b * 16], s0 + 31,
                                       __ATOMIC_RELEASE, __HIP_MEMORY_SCOPE_AGENT);
            }
            double fx = (double)PSM_XS[wp], fy = (double)PSM_YS[wp], fz = (double)PSM_ZS[wp];
            bd = -1.0; bp = base;
#pragma unroll
            for (int j = 0; j < 16; j++) {
                double dx = px[j] - fx, dy = py[j] - fy, dz = pz[j] - fz;
                double d = fma(dz, dz, fma(dy, dy, dx * dx));
                dist[j] = fmin(dist[j], d);
                bool rep = dist[j] > bd;
                bd = rep ? dist[j] : bd; bp = rep ? base + j : bp;
            }
        }
        __syncthreads();
        if (tid < 32) {
            int far = PSM_HIST[992 + tid];
            *(float4*)(centersF + ((size_t)b * MM + 992 + tid) * 4) =
                make_float4(PSM_XS[far], PSM_YS[far], PSM_ZS[far], 0.f);
        }
        if (tid == 0)
            __hip_atomic_store(&progress[b * 16], 1023,
                               __ATOMIC_RELEASE, __HIP_MEMORY_SCOPE_AGENT);
#pragma unroll
        for (int i = 0; i < 4; i++) {
            int m = tid + i * 256;
            int far = PSM_HIST[m];
            float X = PSM_XS[far], Y = PSM_YS[far], Z = PSM_ZS[far];
            if (fl) {
                float* o = (float*)d_out;
                o[OUT1_OFF + (size_t)(b * 3 + 0) * MM + m] = X;
                o[OUT1_OFF + (size_t)(b * 3 + 1) * MM + m] = Y;
                o[OUT1_OFF + (size_t)(b * 3 + 2) * MM + m] = Z;
            } else {
                unsigned short* o = (unsigned short*)d_out;
                o[OUT1_OFF + (size_t)(b * 3 + 0) * MM + m] = f2bf(X);
                o[OUT1_OFF + (size_t)(b * 3 + 1) * MM + m] = f2bf(Y);
                o[OUT1_OFF + (size_t)(b * 3 + 2) * MM + m] = f2bf(Z);
            }
        }
    } else {
        // ---------- workers: featT prologue, then kNN+gtemb+MLP1 tasks -----
        int lane = tid & 63, wid = tid >> 6;
        // featT transpose share (overlapped with FPS warmup)
        {
            float (*tile)[65] = (float(*)[65])SM;
            for (int t = blk - 8; t < 512; t += 248) {
                int b = t >> 6, n0 = (t & 63) * 64;
                int c = tid >> 2, q = tid & 3;
                size_t base = ((size_t)b * 64 + c) * NN + n0 + q * 16;
                __syncthreads();
                if (fl) {
                    const float* sp = (const float*)feat + base;
#pragma unroll
                    for (int j = 0; j < 16; j++) tile[c][q * 16 + j] = sp[j];
                } else {
                    const unsigned short* sp = (const unsigned short*)feat + base;
#pragma unroll
                    for (int j = 0; j < 16; j++) tile[c][q * 16 + j] = bf2f(sp[j]);
                }
                __syncthreads();
                int n = tid >> 2;
                float* dp = featT + ((size_t)b * NN + n0 + n) * 64 + q * 16;
#pragma unroll
                for (int j = 0; j < 16; j++) dp[j] = tile[q * 16 + j][n];
            }
            __syncthreads();
            if (tid == 0) {
                __hip_atomic_fetch_add(cvt_done, 1, __ATOMIC_ACQ_REL, __HIP_MEMORY_SCOPE_AGENT);
                while (__hip_atomic_load(cvt_done, __ATOMIC_RELAXED,
                                         __HIP_MEMORY_SCOPE_AGENT) < 248)
                    __builtin_amdgcn_s_sleep(16);
                (void)__hip_atomic_load(cvt_done, __ATOMIC_ACQUIRE, __HIP_MEMORY_SCOPE_AGENT);
            }
            __syncthreads();
        }
        // stage W1 once per block
        for (int t = tid; t < 64 * 67; t += 256) {
            int c = t / 67, j = t % 67;
            W1Tm(j, c) = paramsC[P_W1 + t];
        }
        __syncthreads();
        for (;;) {
            int id = 0;
            if (lane == 0) id = atomicAdd(qhead, 1);
            id = __shfl(id, 0, 64);
            if (id >= BB * MM) break;
            int b = id & 7, m = id >> 3;
            while (__hip_atomic_load(&progress[b * 16], __ATOMIC_RELAXED,
                                     __HIP_MEMORY_SCOPE_AGENT) < m)
                __builtin_amdgcn_s_sleep(64);
            (void)__hip_atomic_load(&progress[b * 16], __ATOMIC_ACQUIRE,
                                    __HIP_MEMORY_SCOPE_AGENT);
            int bm = b * MM + m;
            const float* cb = coordsC + (size_t)b * 3 * NN;
            float4 ctr = *(const float4*)(centersF + (size_t)bm * 4);
            double cx = (double)ctr.x, cy = (double)ctr.y, cz = (double)ctr.z;
            double cc = (cx * cx + cy * cy) + cz * cz;
            double d[64];
#pragma unroll 4
            for (int j = 0; j < 64; j++) {
                int p = j * 64 + lane;
                double x = (double)cb[p], y = (double)cb[NN + p], z = (double)cb[2 * NN + p];
                double pp = (x * x + y * y) + z * z;
                double dt = (cx * x + cy * y) + cz * z;
                d[j] = (cc + pp) - 2.0 * dt;
            }
            double g8[8]; int a8[8];
#pragma unroll
            for (int g = 0; g < 8; g++) {
                double gd = d[g * 8]; int ga = g * 8;
#pragma unroll
                for (int i = 1; i < 8; i++) {
                    int sl = g * 8 + i;
                    bool rep = d[sl] < gd;
                    gd = rep ? d[sl] : gd; ga = rep ? sl : ga;
                }
                g8[g] = gd; a8[g] = ga;
            }
            unsigned int elo = 0, ehi = 0;
            int res = 0;
#pragma unroll 1
            for (int it = 0; it < 32; it++) {
                double bd = g8[0]; int ba = a8[0];
#pragma unroll
                for (int g = 1; g < 8; g++) {
                    bool rep = g8[g] < bd;
                    bd = rep ? g8[g] : bd; ba = rep ? a8[g] : ba;
                }
                int bp = ba * 64 + lane;
                double wd = bd; int wp = bp;
#pragma unroll
                for (int s = 32; s >= 1; s >>= 1) {
                    double od = __shfl_xor(wd, s, 64);
                    int op = __shfl_xor(wp, s, 64);
                    bool rep = (od < wd) || (od == wd && op < wp);
                    wd = rep ? od : wd; wp = rep ? op : wp;
                }
                res = (lane == it) ? wp : res;
                if (bp == wp) {
                    int slot = ba;
                    if (slot < 32) elo |= (1u << slot); else ehi |= (1u << (slot - 32));
                    int g = slot >> 3;
                    switch (g) {
                        case 0: RESCAN(0) break;
                        case 1: RESCAN(1) break;
                        case 2: RESCAN(2) break;
                        case 3: RESCAN(3) break;
                        case 4: RESCAN(4) break;
                        case 5: RESCAN(5) break;
                        case 6: RESCAN(6) break;
                        case 7: RESCAN(7) break;
                    }
                }
            }
            if (lane < KK) nidx[(size_t)bm * KK + lane] = res;
            float best = -3.0e38f;
            if (fl) {
                const float* tb = (const float*)temb + ((size_t)b * 64 + lane) * NN;
#pragma unroll 4
                for (int k = 0; k < 32; k++) {
                    int nk = __shfl(res, k, 64);
                    best = fmaxf(best, tb[nk]);
                }
            } else {
                const unsigned short* tb = (const unsigned short*)temb + ((size_t)b * 64 + lane) * NN;
#pragma unroll 4
                for (int k = 0; k < 32; k++) {
                    int nk = __shfl(res, k, 64);
                    best = fmaxf(best, bf2f(tb[nk]));
                }
            }
            size_t off = (size_t)OUT2_OFF + ((size_t)(b * 64 + lane)) * MM + m;
            if (fl) ((float*)d_out)[off] = best;
            else    ((unsigned short*)d_out)[off] = f2bf(best);
            // ---- MLP1 for this center ----
            if (lane < 32) NDm(wid, lane) = res & (NN - 1);
            const float* fb = featT + (size_t)b * NN * 64;
#pragma unroll 4
            for (int q = 0; q < 32; q++) {
                int n = NDm(wid, q);
                GBUFm(wid, q, lane) = fb[(size_t)n * 64 + lane];
            }
            if (lane < 32) {
                int n = NDm(wid, lane);
                GCm(wid, 0, lane) = __fsub_rn(cb[n], ctr.x);
                GCm(wid, 1, lane) = __fsub_rn(cb[NN + n], ctr.y);
                GCm(wid, 2, lane) = __fsub_rn(cb[2 * NN + n], ctr.z);
            }
            int c0 = (lane >> 3) * 8;
            int k0 = (lane & 7) * 4;
            float acc[8][4];
#pragma unroll
            for (int i = 0; i < 8; i++)
#pragma unroll
                for (int kk = 0; kk < 4; kk++) acc[i][kk] = 0.f;
#pragma unroll
            for (int j = 0; j < 3; j++) {
                float4 a = *(const float4*)&GCm(wid, j, k0);
                float4 w0 = *(const float4*)&W1Tm(j, c0);
                float4 w1v = *(const float4*)&W1Tm(j, c0 + 4);
                float w[8] = {w0.x, w0.y, w0.z, w0.w, w1v.x, w1v.y, w1v.z, w1v.w};
#pragma unroll
                for (int i = 0; i < 8; i++) {
                    acc[i][0] = fmaf(w[i], a.x, acc[i][0]);
                    acc[i][1] = fmaf(w[i], a.y, acc[i][1]);
                    acc[i][2] = fmaf(w[i], a.z, acc[i][2]);
                    acc[i][3] = fmaf(w[i], a.w, acc[i][3]);
                }
            }
#pragma unroll 4
            for (int c = 0; c < 64; c++) {
                float f0 = GBUFm(wid, k0 + 0, c);
                float f1 = GBUFm(wid, k0 + 1, c);
                float f2 = GBUFm(wid, k0 + 2, c);
                float f3 = GBUFm(wid, k0 + 3, c);
                int j = 3 + c;
                float4 w0 = *(const float4*)&W1Tm(j, c0);
                float4 w1v = *(const float4*)&W1Tm(j, c0 + 4);
                float w[8] = {w0.x, w0.y, w0.z, w0.w, w1v.x, w1v.y, w1v.z, w1v.w};
#pragma unroll
                for (int i = 0; i < 8; i++) {
                    acc[i][0] = fmaf(w[i], f0, acc[i][0]);
                    acc[i][1] = fmaf(w[i], f1, acc[i][1]);
                    acc[i][2] = fmaf(w[i], f2, acc[i][2]);
                    acc[i][3] = fmaf(w[i], f3, acc[i][3]);
                }
            }
            float s = 0.f, s2 = 0.f;
#pragma unroll
            for (int i = 0; i < 8; i++) {
                float bb = paramsC[P_B1 + c0 + i];
                float v0 = acc[i][0] + bb, v1 = acc[i][1] + bb;
                float v2 = acc[i][2] + bb, v3 = acc[i][3] + bb;
                s += v0; s2 = fmaf(v0, v0, s2);
                s += v1; s2 = fmaf(v1, v1, s2);
                s += v2; s2 = fmaf(v2, v2, s2);
                s += v3; s2 = fmaf(v3, v3, s2);
                if (cache1) {
                    unsigned int p0 = (unsigned int)f2bf(v0) | ((unsigned int)f2bf(v1) << 16);
                    unsigned int p1 = (unsigned int)f2bf(v2) | ((unsigned int)f2bf(v3) << 16);
                    *(uint2*)(h1 + ((size_t)bm * 64 + c0 + i) * 32 + k0) = make_uint2(p0, p1);
                }
            }
            s += __shfl_xor(s, 1, 64); s += __shfl_xor(s, 2, 64); s += __shfl_xor(s, 4, 64);
            s2 += __shfl_xor(s2, 1, 64); s2 += __shfl_xor(s2, 2, 64); s2 += __shfl_xor(s2, 4, 64);
            if ((lane & 7) == 0) {
                int g = lane >> 3;
                atomicAdd(&stats1[(b * 8 + g) * 2], s);
                atomicAdd(&stats1[(b * 8 + g) * 2 + 1], s2);
            }
        }
    }
}

// ================= fused MLP machinery (featT f32 gathers) =================
__device__ __forceinline__ void mlp1_compute(
    char* SM, int tid, int lane, int mi, int b, int bm,
    const float* __restrict__ featT, const float* __restrict__ coordsC,
    const float* __restrict__ centersF, const int* __restrict__ nidx,
    const float* __restrict__ P, float acc[8][4])
{
    for (int t = tid; t < 64 * 67; t += 256) {
        int c = t / 67, j = t % 67;
        W1Tm(j, c) = P[P_W1 + t];
    }
    if (lane < 32) NDm(mi, lane) = nidx[(size_t)bm * KK + lane] & (NN - 1);
    __syncthreads();
    const float* fb = featT + (size_t)b * NN * 64;
#pragma unroll 4
    for (int q = 0; q < 32; q++) {
        int n = NDm(mi, q);
        GBUFm(mi, q, lane) = fb[(size_t)n * 64 + lane];
    }
    float4 ctr = *(const float4*)(centersF + (size_t)bm * 4);
    const float* cb = coordsC + (size_t)b * 3 * NN;
    if (lane < 32) {
        int n = NDm(mi, lane);
        GCm(mi, 0, lane) = __fsub_rn(cb[n], ctr.x);
        GCm(mi, 1, lane) = __fsub_rn(cb[NN + n], ctr.y);
        GCm(mi, 2, lane) = __fsub_rn(cb[2 * NN + n], ctr.z);
    }
    __syncthreads();
    int c0 = (lane >> 3) * 8;
    int k0 = (lane & 7) * 4;
#pragma unroll
    for (int i = 0; i < 8; i++)
#pragma unroll
        for (int kk = 0; kk < 4; kk++) acc[i][kk] = 0.f;
#pragma unroll
    for (int j = 0; j < 3; j++) {
        float4 a = *(const float4*)&GCm(mi, j, k0);
        float4 w0 = *(const float4*)&W1Tm(j, c0);
        float4 w1v = *(const float4*)&W1Tm(j, c0 + 4);
        float w[8] = {w0.x, w0.y, w0.z, w0.w, w1v.x, w1v.y, w1v.z, w1v.w};
#pragma unroll
        for (int i = 0; i < 8; i++) {
            acc[i][0] = fmaf(w[i], a.x, acc[i][0]);
            acc[i][1] = fmaf(w[i], a.y, acc[i][1]);
            acc[i][2] = fmaf(w[i], a.z, acc[i][2]);
            acc[i][3] = fmaf(w[i], a.w, acc[i][3]);
        }
    }
#pragma unroll 4
    for (int c = 0; c < 64; c++) {
        float f0 = GBUFm(mi, k0 + 0, c);
        float f1 = GBUFm(mi, k0 + 1, c);
        float f2 = GBUFm(mi, k0 + 2, c);
        float f3 = GBUFm(mi, k0 + 3, c);
        int j = 3 + c;
        float4 w0 = *(const float4*)&W1Tm(j, c0);
        float4 w1v = *(const float4*)&W1Tm(j, c0 + 4);
        float w[8] = {w0.x, w0.y, w0.z, w0.w, w1v.x, w1v.y, w1v.z, w1v.w};
#pragma unroll
        for (int i = 0; i < 8; i++) {
            acc[i][0] = fmaf(w[i], f0, acc[i][0]);
            acc[i][1] = fmaf(w[i], f1, acc[i][1]);
            acc[i][2] = fmaf(w[i], f2, acc[i][2]);
            acc[i][3] = fmaf(w[i], f3, acc[i][3]);
        }
    }
}

__device__ __forceinline__ void mlp2_compute(
    char* SM, int tid, int lane, int mi, int b,
    const float v1[8][4], const float* __restrict__ S1,
    const float* __restrict__ P, float v2[16][4])
{
    __syncthreads();
    int c0 = (lane >> 3) * 8;
    int k0 = (lane & 7) * 4;
    int g = c0 >> 3;
    float S = S1[(b * 8 + g) * 2], Q = S1[(b * 8 + g) * 2 + 1];
    float mean = S * (1.0f / 262144.0f);
    float var = Q * (1.0f / 262144.0f) - mean * mean;
    float inv = rsqrtf(var + 1e-5f);
#pragma unroll
    for (int i = 0; i < 8; i++) {
        int c = c0 + i;
        float sc = P[P_G1 + c] * inv;
        float sh = P[P_BE1 + c] - mean * sc;
#pragma unroll
        for (int kk = 0; kk < 4; kk++)
            ACTm(mi, c, k0 + kk) = swishf(fmaf(v1[i][kk], sc, sh));
    }
    for (int t = tid; t < 128 * 64; t += 256) {
        int c = t >> 6, j = t & 63;
        W2Tm(j, c) = P[P_W2 + t];
    }
    __syncthreads();
    int c02 = (lane >> 3) * 16;
    float acc2[16][4];
#pragma unroll
    for (int i = 0; i < 16; i++)
#pragma unroll
        for (int kk = 0; kk < 4; kk++) acc2[i][kk] = 0.f;
#pragma unroll 4
    for (int j = 0; j < 64; j++) {
        float4 a = *(const float4*)&ACTm(mi, j, k0);
        float4 w0 = *(const float4*)&W2Tm(j, c02);
        float4 w1v = *(const float4*)&W2Tm(j, c02 + 4);
        float4 w2v = *(const float4*)&W2Tm(j, c02 + 8);
        float4 w3 = *(const float4*)&W2Tm(j, c02 + 12);
        float w[16] = {w0.x, w0.y, w0.z, w0.w, w1v.x, w1v.y, w1v.z, w1v.w,
                       w2v.x, w2v.y, w2v.z, w2v.w, w3.x, w3.y, w3.z, w3.w};
#pragma unroll
        for (int i = 0; i < 16; i++) {
            acc2[i][0] = fmaf(w[i], a.x, acc2[i][0]);
            acc2[i][1] = fmaf(w[i], a.y, acc2[i][1]);
            acc2[i][2] = fmaf(w[i], a.z, acc2[i][2]);
            acc2[i][3] = fmaf(w[i], a.w, acc2[i][3]);
        }
    }
#pragma unroll
    for (int i = 0; i < 16; i++) {
        float bb = P[P_B2 + c02 + i];
#pragma unroll
        for (int kk = 0; kk < 4; kk++) v2[i][kk] = acc2[i][kk] + bb;
    }
}

__device__ __forceinline__ void get_v1(
    char* SM, int tid, int lane, int mi, int b, int bm,
    const float* featT, const float* coordsC, const float* centersF,
    const int* nidx, const float* P,
    const unsigned short* h1, int cache1, float v1[8][4])
{
    int c0 = (lane >> 3) * 8;
    int k0 = (lane & 7) * 4;
    if (cache1) {
#pragma unroll
        for (int i = 0; i < 8; i++) {
            uint2 u = *(const uint2*)(h1 + ((size_t)bm * 64 + c0 + i) * 32 + k0);
            v1[i][0] = bf2f((unsigned short)(u.x & 0xffffu));
            v1[i][1] = bf2f((unsigned short)(u.x >> 16));
            v1[i][2] = bf2f((unsigned short)(u.y & 0xffffu));
            v1[i][3] = bf2f((unsigned short)(u.y >> 16));
        }
    } else {
        float acc1[8][4];
        mlp1_compute(SM, tid, lane, mi, b, bm, featT, coordsC, centersF, nidx, P, acc1);
#pragma unroll
        for (int i = 0; i < 8; i++) {
            float bb = P[P_B1 + c0 + i];
#pragma unroll
            for (int kk = 0; kk < 4; kk++) v1[i][kk] = acc1[i][kk] + bb;
        }
    }
}

// ---------------- MLP2 + GN2 stats + optional vmin/vmax store
__global__ __launch_bounds__(256) void k_mlp2s(
    const float* __restrict__ featT, const float* __restrict__ coordsC,
    const float* __restrict__ centersF, const int* __restrict__ nidx,
    const float* __restrict__ P, const float* __restrict__ stats1,
    float* __restrict__ stats2,
    const unsigned short* __restrict__ h1, int cache1,
    unsigned short* __restrict__ vmaxA, unsigned short* __restrict__ vminA,
    int have_vmm)
{
    __shared__ __align__(16) char smem[65536];
    char* SM = smem;
    int tid = threadIdx.x, blk = blockIdx.x;
    int b = blk >> 8, m0 = (blk & 255) * 4;
    int mi = tid >> 6, lane = tid & 63;
    int bm = b * MM + m0 + mi;
    float v1[8][4];
    get_v1(SM, tid, lane, mi, b, bm, featT, coordsC, centersF, nidx, P, h1, cache1, v1);
    float v2[16][4];
    mlp2_compute(SM, tid, lane, mi, b, v1, stats1, P, v2);
    int c02 = (lane >> 3) * 16;
    float s = 0.f, s2 = 0.f;
#pragma unroll
    for (int i = 0; i < 16; i++) {
#pragma unroll
        for (int kk = 0; kk < 4; kk++) {
            float v = v2[i][kk];
            s += v; s2 = fmaf(v, v, s2);
        }
    }
    if (have_vmm) {
        int m = m0 + mi;
#pragma unroll
        for (int i = 0; i < 16; i++) {
            float va = fmaxf(fmaxf(v2[i][0], v2[i][1]), fmaxf(v2[i][2], v2[i][3]));
            float vb = fminf(fminf(v2[i][0], v2[i][1]), fminf(v2[i][2], v2[i][3]));
            va = fmaxf(va, __shfl_xor(va, 1, 64)); vb = fminf(vb, __shfl_xor(vb, 1, 64));
            va = fmaxf(va, __shfl_xor(va, 2, 64)); vb = fminf(vb, __shfl_xor(vb, 2, 64));
            va = fmaxf(va, __shfl_xor(va, 4, 64)); vb = fminf(vb, __shfl_xor(vb, 4, 64));
            if ((lane & 7) == 0) {
                size_t o = ((size_t)(b * 128 + c02 + i)) * MM + m;
                vmaxA[o] = f2bf(va);
                vminA[o] = f2bf(vb);
            }
        }
    }
    s += __shfl_xor(s, 1, 64); s += __shfl_xor(s, 2, 64); s += __shfl_xor(s, 4, 64);
    s2 += __shfl_xor(s2, 1, 64); s2 += __shfl_xor(s2, 2, 64); s2 += __shfl_xor(s2, 4, 64);
    __syncthreads();
    float* sred = (float*)SM;
    if ((lane & 7) == 0) {
        int g = lane >> 3;
        sred[(mi * 8 + g) * 2] = s;
        sred[(mi * 8 + g) * 2 + 1] = s2;
    }
    __syncthreads();
    if (tid < 16) {
        int g = tid >> 1, w = tid & 1;
        float t = sred[(0 * 8 + g) * 2 + w] + sred[(1 * 8 + g) * 2 + w]
                + sred[(2 * 8 + g) * 2 + w] + sred[(3 * 8 + g) * 2 + w];
        atomicAdd(&stats2[(b * 8 + g) * 2 + w], t);
    }
}

// ---------------- fast final: elementwise from vmin/vmax (swish unimodal)
__global__ __launch_bounds__(256) void k_final_fast(
    const unsigned short* __restrict__ vmaxA, const unsigned short* __restrict__ vminA,
    const float* __restrict__ P, const float* __restrict__ stats2,
    void* __restrict__ d_out, const void* __restrict__ feat)
{
    int tid = threadIdx.x;
    int idx = blockIdx.x * 256 + tid;
    int fl = detect_flag_wave((const unsigned short*)feat, tid & 63);
    int c = (idx >> 10) & 127;
    int b = idx >> 17;
    int g = c >> 4;
    float S = stats2[(b * 8 + g) * 2], Q = stats2[(b * 8 + g) * 2 + 1];
    float mean = S * (1.0f / 524288.0f);
    float var = Q * (1.0f / 524288.0f) - mean * mean;
    float inv = rsqrtf(var + 1e-5f);
    float sc = P[P_G2 + c] * inv;
    float sh = P[P_BE2 + c] - mean * sc;
    float va = bf2f(vmaxA[idx]);
    float vb = bf2f(vminA[idx]);
    float r = fmaxf(swishf(fmaf(va, sc, sh)), swishf(fmaf(vb, sc, sh)));
    if (fl) ((float*)d_out)[idx] = r;
    else    ((unsigned short*)d_out)[idx] = f2bf(r);
}

// ---------------- slow final (fallback, recompute path)
__global__ __launch_bounds__(256) void k_final_slow(
    const float* __restrict__ featT, const float* __restrict__ coordsC,
    const float* __restrict__ centersF, const int* __restrict__ nidx,
    const float* __restrict__ P, const float* __restrict__ stats1,
    const float* __restrict__ stats2,
    void* __restrict__ d_out, const void* __restrict__ feat,
    const unsigned short* __restrict__ h1, int cache1)
{
    __shared__ __align__(16) char smem[65536];
    char* SM = smem;
    int tid = threadIdx.x, blk = blockIdx.x;
    if (tid < 64) {
        int fl0 = detect_flag_wave((const unsigned short*)feat, tid);
        if (tid == 0) *(int*)(SM + 53248) = fl0;
    }
    __syncthreads();
    int fl = *(int*)(SM + 53248);
    int b = blk >> 8, m0 = (blk & 255) * 4;
    int mi = tid >> 6, lane = tid & 63;
    int bm = b * MM + m0 + mi;
    float v1[8][4];
    get_v1(SM, tid, lane, mi, b, bm, featT, coordsC, centersF, nidx, P, h1, cache1, v1);
    float v2[16][4];
    mlp2_compute(SM, tid, lane, mi, b, v1, stats1, P, v2);
    int c02 = (lane >> 3) * 16;
    int g2 = c02 >> 4;
    float S = stats2[(b * 8 + g2) * 2], Q = stats2[(b * 8 + g2) * 2 + 1];
    float mean = S * (1.0f / 524288.0f);
    float var = Q * (1.0f / 524288.0f) - mean * mean;
    float inv = rsqrtf(var + 1e-5f);
    float mx[16];
#pragma unroll
    for (int i = 0; i < 16; i++) {
        int c = c02 + i;
        float sc = P[P_G2 + c] * inv;
        float sh = P[P_BE2 + c] - mean * sc;
        float v = -3.0e38f;
#pragma unroll
        for (int kk = 0; kk < 4; kk++)
            v = fmaxf(v, swishf(fmaf(v2[i][kk], sc, sh)));
        v = fmaxf(v, __shfl_xor(v, 1, 64));
        v = fmaxf(v, __shfl_xor(v, 2, 64));
        v = fmaxf(v, __shfl_xor(v, 4, 64));
        mx[i] = v;
    }
    if ((lane & 7) == 0) {
        int m = m0 + mi;
#pragma unroll
        for (int i = 0; i < 16; i++) {
            size_t off = (size_t)(b * 128 + c02 + i) * MM + m;
            if (fl) ((float*)d_out)[off] = mx[i];
            else    ((unsigned short*)d_out)[off] = f2bf(mx[i]);
        }
    }
}

extern "C" void kernel_launch(void* const* d_in, const int* in_sizes, int n_in,
                              void* d_out, int out_size, void* d_ws, size_t ws_size,
                              hipStream_t stream) {
    (void)in_sizes; (void)n_in; (void)out_size;
    const void* feat = d_in[0];
    const void* coords = d_in[1];
    const void* temb = d_in[2];

    // base ws 10,016,832 B; gated: h1 (32 MB) @10,016,832; vmax/vmin (4 MB)
    char* ws = (char*)d_ws;
    int* qhead = (int*)ws;                                  // @0
    int* progress = (int*)(ws + 512);                       // 8 x 64B lines
    float* stats1 = (float*)(ws + 1024);                    // 256 f32
    float* stats2 = (float*)(ws + 2048);                    // 256 f32
    int* cvt_done = (int*)(ws + 3072);                      // 64 B
    float* coordsC = (float*)(ws + 3136);                   // 393,216
    float* paramsC = (float*)(ws + 396352);                 // 52,224
    float* centersF = (float*)(ws + 448576);                // 131,072
    int* nidx = (int*)(ws + 579648);                        // 1,048,576
    float* featT = (float*)(ws + 1628224);                  // 8,388,608 -> 10,016,832
    unsigned short* h1 = (unsigned short*)(ws + 10016832);  // 33,554,432 -> 43,571,264
    unsigned short* vmaxA = (unsigned short*)(ws + 43571264); // 2,097,152
    unsigned short* vminA = (unsigned short*)(ws + 45668416); // 2,097,152 -> 47,765,568
    int cache1 = (ws_size >= 43571264u) ? 1 : 0;
    int have_vmm = (ws_size >= 47765568u) ? 1 : 0;

    k_cvt_all<<<435, 256, 0, stream>>>(feat, coords, coordsC, paramsC,
                                       qhead, progress, stats1, cvt_done,
                                       d_in[3], d_in[4], d_in[5], d_in[6],
                                       d_in[7], d_in[8], d_in[9], d_in[10]);
    k_fpsknn<<<256, 256, 0, stream>>>(coords, coordsC, centersF, nidx, temb,
                                      feat, featT, paramsC, stats1, d_out,
                                      qhead, progress, cvt_done, h1, cache1);
    k_mlp2s<<<2048, 256, 0, stream>>>(featT, coordsC, centersF, nidx, paramsC,
                                      stats1, stats2, h1, cache1,
                                      vmaxA, vminA, have_vmm);
    if (have_vmm) {
        k_final_fast<<<4096, 256, 0, stream>>>(vmaxA, vminA, paramsC, stats2,
                                               d_out, feat);
    } else {
        k_final_slow<<<2048, 256, 0, stream>>>(featT, coordsC, centersF, nidx,
                                               paramsC, stats1, stats2, d_out,
                                               feat, h1, cache1);
    }
}